// Round 9
// baseline (960.827 us; speedup 1.0000x reference)
//
#include <hip/hip_runtime.h>
#include <math.h>

// ---------------------------------------------------------------------------
// WaveletNet forward. conv_mfma6: 128x128x64 double-buffered (1 barrier/iter),
// split-K=2, 256 threads, 2 blocks/CU (cross-block overlap is the latency
// hiding mechanism - R4/R5/R7 ablations). GN-apply fused into consumers
// (wt_nhwc_gn / conv3x3_iwt / concat_iwt_nhwc). Decoder concat+iwt writes
// padded NHWC f16 directly (no t2 round-trip); ic4 split-K reduce folded into
// the iw4 concat. conv_mfma3: 128x64x64 dbuf. GN via block-partials. N=16.
// ---------------------------------------------------------------------------

#define NB 16  // batch

typedef _Float16 f16;
typedef _Float16 f16x8 __attribute__((ext_vector_type(8)));
typedef _Float16 f16x4 __attribute__((ext_vector_type(4)));
typedef float f32x4 __attribute__((ext_vector_type(4)));
typedef float f32x2 __attribute__((ext_vector_type(2)));
typedef unsigned int u32;

#define LLDS16(gp, lp)                                                          \
  __builtin_amdgcn_global_load_lds((const __attribute__((address_space(1))) u32*)(const void*)(gp), \
                                   (__attribute__((address_space(3))) u32*)(void*)(lp), 16, 0, 0)

// ---------------- weight standardization ----------------
__device__ __forceinline__ void ws_reduce(const float* wp, int fan, float* red,
                                          float& mean, float& inv) {
  float s = 0.f, s2 = 0.f;
  for (int i = threadIdx.x; i < fan; i += 256) { float v = wp[i]; s += v; s2 += v * v; }
  red[threadIdx.x] = s; red[256 + threadIdx.x] = s2;
  __syncthreads();
  for (int st = 128; st > 0; st >>= 1) {
    if (threadIdx.x < st) {
      red[threadIdx.x] += red[threadIdx.x + st];
      red[256 + threadIdx.x] += red[256 + threadIdx.x + st];
    }
    __syncthreads();
  }
  float sum = red[0], sumsq = red[256];
  mean = sum / (float)fan;
  float var = (sumsq - sum * mean) / (float)(fan - 1);
  if (var < 0.f) var = 0.f;
  inv = 1.0f / (sqrtf(var) + 1e-5f);
}

__global__ void ws_all_kernel(const float* w0, float* o0, const float* w1, float* o1,
                              const float* w2, float* o2, const float* w3, float* o3) {
  __shared__ float red[512];
  int b = blockIdx.x;
  const float* w; float* o; int fan, oi;
  if (b < 16)      { w = w0; o = o0; fan = 108; oi = b; }
  else if (b < 28) { w = w1; o = o1; fan = 144; oi = b - 16; }
  else if (b < 44) { w = w2; o = o2; fan = 288; oi = b - 28; }
  else             { w = w3; o = o3; fan = 3;   oi = b - 44; }
  const float* wp = w + (size_t)oi * fan;
  float mean, inv; ws_reduce(wp, fan, red, mean, inv);
  for (int i = threadIdx.x; i < fan; i += 256)
    o[(size_t)oi * fan + i] = (wp[i] - mean) * inv;
}

__global__ void ws_f16_all_kernel(const float* w0, f16* o0, const float* w1, f16* o1,
                                  const float* w2, f16* o2, const float* w3, f16* o3,
                                  const float* w4, f16* o4) {
  __shared__ float red[512];
  int b = blockIdx.x;
  const float* w; f16* o; int fan, Cin, Cout, oi;
  if (b < 64)        { w = w0; o = o0; fan = 576;  Cin = 64;   Cout = 64;   oi = b; }
  else if (b < 320)  { w = w1; o = o1; fan = 2304; Cin = 256;  Cout = 256;  oi = b - 64; }
  else if (b < 1344) { w = w2; o = o2; fan = 9216; Cin = 1024; Cout = 1024; oi = b - 320; }
  else if (b < 1408) { w = w3; o = o3; fan = 1152; Cin = 128;  Cout = 64;   oi = b - 1344; }
  else               { w = w4; o = o4; fan = 4608; Cin = 512;  Cout = 256;  oi = b - 1408; }
  const float* wp = w + (size_t)oi * fan;
  float mean, inv; ws_reduce(wp, fan, red, mean, inv);
  for (int i = threadIdx.x; i < fan; i += 256) {
    int ci = i / 9, tap = i - ci * 9;
    o[((size_t)tap * Cout + oi) * Cin + ci] = (f16)((wp[i] - mean) * inv);
  }
}

// ---------------- halo zero ----------------
__device__ __forceinline__ void halo_write(f16* buf, int C, int H, int W, int t) {
  int c8s = C >> 3;
  int c8 = t % c8s; int q = t / c8s;
  int P = 2 * (W + 2) + 2 * H;
  int b = q % P; int n = q / P;
  int y, x;
  if (b < W + 2) { y = 0; x = b; }
  else if (b < 2 * (W + 2)) { y = H + 1; x = b - (W + 2); }
  else { int bb = b - 2 * (W + 2); y = 1 + (bb >> 1); x = (bb & 1) ? (W + 1) : 0; }
  size_t a = (((size_t)n * (H + 2) + y) * (W + 2) + x) * C + c8 * 8;
  *(f16x8*)(buf + a) = (f16x8){0, 0, 0, 0, 0, 0, 0, 0};
}

__global__ void halo2_kernel(f16* b0, int c0, int h0, int w0, int n0,
                             f16* b1, int c1, int h1, int w1, int total) {
  int idx = blockIdx.x * 256 + threadIdx.x;
  if (idx >= total) return;
  if (idx < n0) halo_write(b0, c0, h0, w0, idx);
  else halo_write(b1, c1, h1, w1, idx - n0);
}

__global__ void zero_halo_kernel(f16* __restrict__ buf, int C, int H, int W, int total8) {
  int idx = blockIdx.x * 256 + threadIdx.x;
  if (idx >= total8) return;
  halo_write(buf, C, H, W, idx);
}

// ---------------- Haar forward (NCHW fp32) ----------------
__global__ void wt_kernel(const float* __restrict__ in, float* __restrict__ out,
                          int C, int Ho, int Wo, int total) {
  int idx = blockIdx.x * 256 + threadIdx.x;
  if (idx >= total) return;
  int w = idx % Wo; int t = idx / Wo;
  int h = t % Ho; t /= Ho;
  int c = t % C; int n = t / C;
  int Wi = 2 * Wo;
  const float* ip = in + (((size_t)n * C + c) * (2 * Ho) + 2 * h) * Wi + 2 * w;
  float a = ip[0], b = ip[1], cc = ip[Wi], d = ip[Wi + 1];
  size_t cs = (size_t)Ho * Wo;
  float* op = out + (((size_t)n * 4 * C + 4 * c) * Ho + h) * Wo + w;
  op[0]      = 0.25f * (a + b + cc + d);
  op[cs]     = 0.25f * (a + b - cc - d) + 0.5f;
  op[2 * cs] = 0.25f * (a - b + cc - d) + 0.5f;
  op[3 * cs] = 0.25f * (a - b - cc + d) + 0.5f;
}

// ---------------- fused GN-apply + Haar + NCHW->padded NHWC f16 -------------
__global__ __launch_bounds__(256) void wt_nhwc_gn_kernel(
    const float* __restrict__ in, const float* __restrict__ gnp,
    const float* __restrict__ gamma, const float* __restrict__ beta,
    int G, int Sg, int len,
    f16* __restrict__ out, float* __restrict__ out32, float* __restrict__ gnwb,
    int C, int Ho, int Wo) {
  __shared__ f16 sm[32][264];
  __shared__ float scs[8], shs[8];
  int HWo = Ho * Wo;
  int p0 = blockIdx.x * 256, c0 = blockIdx.y * 8, n = blockIdx.z;
  int t = threadIdx.x;
  if (t < 8) {
    int c = c0 + t;
    int g = c / (C / G);
    const float* pp = gnp + (size_t)((n * G + g) * Sg) * 2;
    float s = 0.f, s2 = 0.f;
    for (int i = 0; i < Sg; ++i) { s += pp[2 * i]; s2 += pp[2 * i + 1]; }
    float mean = s / (float)len;
    float var = s2 / (float)len - mean * mean;
    if (var < 0.f) var = 0.f;
    float inv = rsqrtf(var + 1e-5f);
    float ga = gamma[c];
    scs[t] = inv * ga;
    shs[t] = beta[c] - mean * inv * ga;
  }
  __syncthreads();
  int p = p0 + t; int h = p / Wo; int ww = p - h * Wo;
  int Wi = 2 * Wo;
  int C4 = 4 * C;
#pragma unroll
  for (int r = 0; r < 8; ++r) {
    size_t ioff = (((size_t)n * C + c0 + r) * (2 * Ho) + 2 * h) * Wi + 2 * ww;
    const float* ip = in + ioff;
    f32x2 u0 = *(const f32x2*)ip;
    f32x2 u1 = *(const f32x2*)(ip + Wi);
    float sc = scs[r], sh = shs[r];
    float a = u0.x * sc + sh, b = u0.y * sc + sh;
    float cc = u1.x * sc + sh, d = u1.y * sc + sh;
    if (gnwb) {
      float* wp = gnwb + ioff;
      *(f32x2*)wp = (f32x2){a, b};
      *(f32x2*)(wp + Wi) = (f32x2){cc, d};
    }
    float v0 = 0.25f * (a + b + cc + d);
    float v1 = 0.25f * (a + b - cc - d) + 0.5f;
    float v2 = 0.25f * (a - b + cc - d) + 0.5f;
    float v3 = 0.25f * (a - b - cc + d) + 0.5f;
    sm[4 * r][t]     = (f16)v0;
    sm[4 * r + 1][t] = (f16)v1;
    sm[4 * r + 2][t] = (f16)v2;
    sm[4 * r + 3][t] = (f16)v3;
    if (out32) {
      float* op = out32 + (((size_t)n * C4 + 4 * (c0 + r)) * Ho + h) * Wo + ww;
      size_t cs = (size_t)HWo;
      op[0] = v0; op[cs] = v1; op[2 * cs] = v2; op[3 * cs] = v3;
    }
  }
  __syncthreads();
#pragma unroll
  for (int i = 0; i < 4; ++i) {
    int c = t + i * 256;
    int pl = c >> 2, cio = (c & 3) * 8;
    f16x8 v;
#pragma unroll
    for (int u = 0; u < 8; ++u) v[u] = sm[cio + u][pl];
    int pp = p0 + pl; int y = pp / Wo; int x = pp - y * Wo;
    *(f16x8*)(out + (((size_t)n * (Ho + 2) + y + 1) * (Wo + 2) + x + 1) * C4 + c0 * 4 + cio) = v;
  }
}

// ---------------- fused concat + iwt (NCHW fp32 out; iw2 site) -------------
__global__ void concat_iwt_kernel(const float* __restrict__ skip, const float* __restrict__ v,
                                  float* __restrict__ out, const float* __restrict__ gnp,
                                  const float* __restrict__ gamma, const float* __restrict__ beta,
                                  int G, int Sg, int len, int C, int Hh, int Wh,
                                  int totalA, int total) {
  int idx = blockIdx.x * 256 + threadIdx.x;
  if (idx >= total) return;
  int W = 2 * Wh, H = 2 * Hh; int HWs = H * W;
  if (idx < totalA) {
    int p = idx % HWs; int t = idx / HWs; int c = t % C; int n = t / C;
    out[((size_t)n * 2 * C + c) * HWs + p] = skip[idx];
    return;
  }
  int i2 = idx - totalA;
  int w = i2 % Wh; int t = i2 / Wh; int h = t % Hh; t /= Hh;
  int c = t % C; int n = t / C;
  size_t cs = (size_t)Hh * Wh;
  const float* vp = v + (((size_t)n * 4 * C + 4 * c) * Hh + h) * Wh + w;
  float v0 = vp[0], v1 = vp[cs], v2 = vp[2 * cs], v3 = vp[3 * cs];
  if (gnp) {
    int cpg = (4 * C) / G;
    int g = (4 * c) / cpg;
    const float* pp = gnp + (size_t)((n * G + g) * Sg) * 2;
    float s = 0.f, s2 = 0.f;
    for (int i = 0; i < Sg; ++i) { s += pp[2 * i]; s2 += pp[2 * i + 1]; }
    float mean = s / (float)len;
    float var = s2 / (float)len - mean * mean;
    if (var < 0.f) var = 0.f;
    float inv = rsqrtf(var + 1e-5f);
    v0 = (v0 - mean) * inv * gamma[4 * c]     + beta[4 * c];
    v1 = (v1 - mean) * inv * gamma[4 * c + 1] + beta[4 * c + 1];
    v2 = (v2 - mean) * inv * gamma[4 * c + 2] + beta[4 * c + 2];
    v3 = (v3 - mean) * inv * gamma[4 * c + 3] + beta[4 * c + 3];
  }
  v1 = 2.f * v1 - 1.f; v2 = 2.f * v2 - 1.f; v3 = 2.f * v3 - 1.f;
  float* op = out + (((size_t)n * 2 * C + C + c) * H + 2 * h) * (size_t)W + 2 * w;
  op[0]     = v0 + 0.5f * ( v1 + v2 + v3);
  op[1]     = v0 + 0.5f * ( v1 - v2 - v3);
  op[W]     = v0 + 0.5f * (-v1 + v2 - v3);
  op[W + 1] = v0 + 0.5f * (-v1 - v2 + v3);
}

// ---- fused concat + iwt -> padded NHWC f16 (iw4/iw3 sites) ----------------
// Block: 32 output channels x 256 output pixels; LDS transpose write.
// v-source: either fp32 NCHW v32, or split-K part pair (+bias,+add,+lrelu).
// Optional inline GN on v channels (from gnp partials).
__global__ __launch_bounds__(256) void concat_iwt_nhwc_kernel(
    const float* __restrict__ skip, const float* __restrict__ v32,
    const f16* __restrict__ part, const float* __restrict__ bias,
    const float* __restrict__ add,
    const float* __restrict__ gnp, const float* __restrict__ gamma,
    const float* __restrict__ beta, int G, int Sg, int len,
    f16* __restrict__ out, int C, int Hh, int Wh) {
  __shared__ f16 sm[32][264];
  __shared__ float scs[128], shs[128];
  const int W = 2 * Wh, H = 2 * Hh;
  const int HWo = H * W, HWh = Hh * Wh;
  const int C2 = 2 * C;
  const int p0 = blockIdx.x * 256, c0 = blockIdx.y * 32, n = blockIdx.z;
  const int t = threadIdx.x;
  const bool isV = (c0 >= C);
  if (isV && gnp) {
    if (t < 128) {
      int ch = 4 * (c0 - C) + t;
      int cpg = (4 * C) / G;
      int g = ch / cpg;
      const float* pp = gnp + (size_t)((n * G + g) * Sg) * 2;
      float s = 0.f, s2 = 0.f;
      for (int i = 0; i < Sg; ++i) { s += pp[2 * i]; s2 += pp[2 * i + 1]; }
      float mean = s / (float)len;
      float var = s2 / (float)len - mean * mean;
      if (var < 0.f) var = 0.f;
      float inv = rsqrtf(var + 1e-5f);
      float ga = gamma[ch];
      scs[t] = inv * ga;
      shs[t] = beta[ch] - mean * inv * ga;
    }
    __syncthreads();
  }
  int p = p0 + t; int y = p / W; int x = p - y * W;
  if (!isV) {
    const float* sp = skip + ((size_t)n * C + c0) * HWo + p;
#pragma unroll 8
    for (int r = 0; r < 32; ++r) sm[r][t] = (f16)sp[(size_t)r * HWo];
  } else {
    int hh = y >> 1, sy = y & 1, w2 = x >> 1, sx = x & 1;
    int q = hh * Wh + w2;
    int Cv = 4 * C;
    size_t sstr = (size_t)NB * Cv * HWh;
    int cb4 = 4 * (c0 - C);
    for (int r = 0; r < 32; ++r) {
      float vv[4];
#pragma unroll
      for (int k = 0; k < 4; ++k) {
        int cv = cb4 + 4 * r + k;
        size_t off = ((size_t)n * Cv + cv) * HWh + q;
        float val;
        if (part) {
          val = (float)part[off] + (float)part[sstr + off] + bias[cv];
          if (add) val += add[off];
          val = val > 0.f ? val : 0.2f * val;
        } else {
          val = v32[off];
        }
        if (gnp) val = val * scs[4 * r + k] + shs[4 * r + k];
        vv[k] = val;
      }
      float v1 = 2.f * vv[1] - 1.f, v2 = 2.f * vv[2] - 1.f, v3 = 2.f * vv[3] - 1.f;
      float a1 = sy ? -v1 : v1;
      float a2 = sx ? -v2 : v2;
      float a3 = (sy ^ sx) ? -v3 : v3;
      sm[r][t] = (f16)(vv[0] + 0.5f * (a1 + a2 + a3));
    }
  }
  __syncthreads();
#pragma unroll
  for (int i = 0; i < 4; ++i) {
    int c = t + i * 256;
    int pl = c >> 2, cio = (c & 3) * 8;
    f16x8 ov;
#pragma unroll
    for (int u = 0; u < 8; ++u) ov[u] = sm[cio + u][pl];
    int pp = p0 + pl; int yy = pp / W; int xx = pp - yy * W;
    *(f16x8*)(out + (((size_t)n * (H + 2) + yy + 1) * (W + 2) + xx + 1) * C2 + c0 + cio) = ov;
  }
}

// ---------------- GN-apply (partial-based) + NCHW->padded NHWC f16 ----------
__global__ __launch_bounds__(256) void gn_nhwc_kernel(
    const float* __restrict__ in, const float* __restrict__ gnp,
    const float* __restrict__ gamma, const float* __restrict__ beta,
    f16* __restrict__ out, int C, int H, int W, int G, int Sg, int len) {
  __shared__ f16 sm[32][264];
  int HW = H * W;
  int p0 = blockIdx.x * 256, c0 = blockIdx.y * 32, n = blockIdx.z;
  int t = threadIdx.x;
  int cpg = C / G;
  const float* ip = in + ((size_t)n * C + c0) * HW + p0;
#pragma unroll 8
  for (int r = 0; r < 32; ++r) {
    int c = c0 + r; int g = c / cpg;
    const float* pp = gnp + (size_t)((n * G + g) * Sg) * 2;
    float s = 0.f, s2 = 0.f;
    for (int i = 0; i < Sg; ++i) { s += pp[2 * i]; s2 += pp[2 * i + 1]; }
    float mean = s / (float)len;
    float var = s2 / (float)len - mean * mean;
    if (var < 0.f) var = 0.f;
    float inv = rsqrtf(var + 1e-5f);
    float ga = gamma[c], be = beta[c];
    sm[r][t] = (f16)((ip[(size_t)r * HW + t] - mean) * inv * ga + be);
  }
  __syncthreads();
#pragma unroll
  for (int i = 0; i < 4; ++i) {
    int c = t + i * 256;
    int pl = c >> 2, cio = (c & 3) * 8;
    f16x8 v;
#pragma unroll
    for (int u = 0; u < 8; ++u) v[u] = sm[cio + u][pl];
    int p = p0 + pl; int y = p / W; int x = p - y * W;
    *(f16x8*)(out + (((size_t)n * (H + 2) + y + 1) * (W + 2) + x + 1) * C + c0 + cio) = v;
  }
}

// ---------------- conv_mfma6: 128x128x64, dbuf, 1 barrier/iter, split-K -----
__global__ __launch_bounds__(256) void conv_mfma6_kernel(
    const f16* __restrict__ A, const f16* __restrict__ Wp,
    f16* __restrict__ part, int Cin, int H, int W, int Cout, int HW) {
  constexpr int CH = 128 * 64;  // f16 per buffer
  __shared__ f16 Asm[2 * CH];   // 32 KB
  __shared__ f16 Bsm[2 * CH];   // 32 KB

  const int tid = threadIdx.x;
  const int w = tid >> 6, lane = tid & 63;
  const int m0 = blockIdx.x * 128;
  const int co0 = blockIdx.y * 128;
  const int Wp2 = W + 2;

  const f16* gA[4]; const f16* gB[4];
  int lOff[4];
#pragma unroll
  for (int e = 0; e < 4; ++e) {
    int c = e * 256 + tid;
    int r = c >> 3, j = c & 7;
    int jx = j ^ (r & 7);
    int m = m0 + r; int n = m / HW; int p = m - n * HW;
    int y = p / W; int x = p - y * W;
    gA[e] = A + (((size_t)n * (H + 2) + y + 1) * Wp2 + (x + 1)) * Cin + jx * 8;
    gB[e] = Wp + (size_t)(co0 + r) * Cin + jx * 8;
    lOff[e] = (e * 256 + w * 64) * 8;  // wave-uniform
  }

  const int wm = w & 1, wn = w >> 1;
  const int lr = lane & 15, quad = lane >> 4;
  int aoffs[4][2], boffs[4][2];
#pragma unroll
  for (int i = 0; i < 4; ++i)
#pragma unroll
    for (int kk = 0; kk < 2; ++kk) {
      int r = wm * 64 + i * 16 + lr;
      int cidx = kk * 4 + quad;
      aoffs[i][kk] = (r * 8 + (cidx ^ (r & 7))) * 8;
      int rb = wn * 64 + i * 16 + lr;
      boffs[i][kk] = (rb * 8 + (cidx ^ (rb & 7))) * 8;
    }

  f32x4 acc[4][4];
#pragma unroll
  for (int i = 0; i < 4; ++i)
#pragma unroll
    for (int j = 0; j < 4; ++j) acc[i][j] = (f32x4){0.f, 0.f, 0.f, 0.f};

  const int kpt = Cin >> 6;
  const int nit = (9 * kpt) / gridDim.z;
  const int it0 = blockIdx.z * nit;
  const size_t bstride = (size_t)Cout * Cin;

  auto stageAB = [&](int it, int sel) {
    int tap = it / kpt, kk = it - tap * kpt;
    int dy = tap / 3 - 1, dx = tap % 3 - 1;
    long offA = ((long)dy * Wp2 + dx) * Cin + (kk << 6);
    long offB = (long)tap * bstride + (kk << 6);
    f16* ab = Asm + sel * CH;
    f16* bb = Bsm + sel * CH;
#pragma unroll
    for (int e = 0; e < 4; ++e) {
      LLDS16(gA[e] + offA, ab + lOff[e]);
      LLDS16(gB[e] + offB, bb + lOff[e]);
    }
  };

  stageAB(it0, 0);
  int sel = 0;
  for (int ii = 0; ii < nit; ++ii) {
    __syncthreads();  // drains prefetch (vmcnt) + prior reads (lgkm)
    if (ii + 1 < nit) stageAB(it0 + ii + 1, sel ^ 1);  // overlaps compute below
    const f16* ab = Asm + sel * CH;
    const f16* bb = Bsm + sel * CH;
    f16x8 af[4][2], bf[4][2];
#pragma unroll
    for (int i = 0; i < 4; ++i)
#pragma unroll
      for (int kk = 0; kk < 2; ++kk) {
        af[i][kk] = *(const f16x8*)&ab[aoffs[i][kk]];
        bf[i][kk] = *(const f16x8*)&bb[boffs[i][kk]];
      }
#pragma unroll
    for (int kk = 0; kk < 2; ++kk)
#pragma unroll
      for (int i = 0; i < 4; ++i)
#pragma unroll
        for (int j = 0; j < 4; ++j)
          acc[i][j] = __builtin_amdgcn_mfma_f32_16x16x32_f16(af[i][kk], bf[j][kk], acc[i][j], 0, 0, 0);
    sel ^= 1;
  }

  const size_t pbase = (size_t)blockIdx.z * NB * Cout * HW;
#pragma unroll
  for (int i = 0; i < 4; ++i) {
    int mg = m0 + wm * 64 + i * 16 + quad * 4;
    int n = mg / HW, p = mg - n * HW;
#pragma unroll
    for (int j = 0; j < 4; ++j) {
      int co = co0 + wn * 64 + j * 16 + lr;
      f32x4 v = acc[i][j];
      f16x4 h;
#pragma unroll
      for (int r = 0; r < 4; ++r) h[r] = (f16)v[r];
      *(f16x4*)&part[pbase + ((size_t)n * Cout + co) * HW + p] = h;
    }
  }
}

// ---------------- reduce S partials + bias (+add)(+lrelu) + GN partials -----
__global__ __launch_bounds__(256) void reduceS_kernel(
    const f16* __restrict__ part, const float* __restrict__ bias,
    const float* __restrict__ add, float* __restrict__ out,
    int Cout, int HW, int S, int do_lrelu, int total4,
    float* __restrict__ gnp, int G, int Sg) {
  __shared__ float red[512];
  int idx = blockIdx.x * 256 + threadIdx.x;
  if (idx >= total4) return;
  size_t sstride = (size_t)NB * Cout * HW;
  int hw4 = HW >> 2;
  int p4 = idx % hw4; int t = idx / hw4;
  int c = t % Cout;
  size_t eoff = (size_t)t * HW + p4 * 4;
  float b = bias[c];
  f32x4 o = {b, b, b, b};
  for (int s = 0; s < S; ++s) {
    f16x4 a = *(const f16x4*)(part + s * sstride + eoff);
#pragma unroll
    for (int r = 0; r < 4; ++r) o[r] += (float)a[r];
  }
  if (add) {
    f32x4 av = *(const f32x4*)(add + eoff);
#pragma unroll
    for (int r = 0; r < 4; ++r) o[r] += av[r];
  }
  if (do_lrelu)
#pragma unroll
    for (int r = 0; r < 4; ++r) o[r] = o[r] > 0.f ? o[r] : 0.2f * o[r];
  *(f32x4*)(out + eoff) = o;
  if (gnp) {
    float ls = o[0] + o[1] + o[2] + o[3];
    float ls2 = o[0]*o[0] + o[1]*o[1] + o[2]*o[2] + o[3]*o[3];
    red[threadIdx.x] = ls; red[256 + threadIdx.x] = ls2;
    __syncthreads();
    for (int st = 128; st > 0; st >>= 1) {
      if (threadIdx.x < st) {
        red[threadIdx.x] += red[threadIdx.x + st];
        red[256 + threadIdx.x] += red[256 + threadIdx.x + st];
      }
      __syncthreads();
    }
    if (threadIdx.x == 0) {
      int flat0 = blockIdx.x * 1024;
      int chw = Cout * HW;
      int n = flat0 / chw;
      int rem = flat0 - n * chw;
      int L = (Cout / G) * HW;
      int g = rem / L;
      int s = (rem - g * L) >> 10;
      gnp[((n * G + g) * Sg + s) * 2] = red[0];
      gnp[((n * G + g) * Sg + s) * 2 + 1] = red[256];
    }
  }
}

// ---------------- conv_mfma3: 128x64x64, dbuf, 1 barrier/iter (Cout=64) -----
__global__ __launch_bounds__(256) void conv_mfma3_kernel(
    const f16* __restrict__ A, const f16* __restrict__ Wp,
    const float* __restrict__ bias, float* __restrict__ out,
    int Cin, int H, int W, int Cout, int HW, int do_lrelu) {
  constexpr int CHA = 128 * 64;  // f16 per A buffer
  constexpr int CHB = 64 * 64;   // f16 per B buffer
  __shared__ f16 Asm[2 * CHA];   // 32 KB
  __shared__ f16 Bsm[2 * CHB];   // 16 KB

  const int tid = threadIdx.x;
  const int w = tid >> 6, lane = tid & 63;
  const int m0 = blockIdx.x * 128;
  const int co0 = blockIdx.y * 64;
  const int Wp2 = W + 2;

  const f16* gA[4];
  int lAoff[4];
#pragma unroll
  for (int e = 0; e < 4; ++e) {
    int c = e * 256 + tid;
    int r = c >> 3, j = c & 7;
    int jx = j ^ (r & 7);
    int m = m0 + r; int n = m / HW; int p = m - n * HW;
    int y = p / W; int x = p - y * W;
    gA[e] = A + (((size_t)n * (H + 2) + y + 1) * Wp2 + (x + 1)) * Cin + jx * 8;
    lAoff[e] = (e * 256 + w * 64) * 8;
  }
  const f16* gB[2];
  int lBoff[2];
#pragma unroll
  for (int e = 0; e < 2; ++e) {
    int c = e * 256 + tid;
    int r = c >> 3, j = c & 7;
    int jx = j ^ (r & 7);
    gB[e] = Wp + (size_t)(co0 + r) * Cin + jx * 8;
    lBoff[e] = (e * 256 + w * 64) * 8;
  }

  const int wm = w & 1, wn = w >> 1;
  const int lr = lane & 15, quad = lane >> 4;
  int aoffs[4][2], boffs[2][2];
#pragma unroll
  for (int i = 0; i < 4; ++i)
#pragma unroll
    for (int kk = 0; kk < 2; ++kk) {
      int r = wm * 64 + i * 16 + lr;
      int cidx = kk * 4 + quad;
      aoffs[i][kk] = (r * 8 + (cidx ^ (r & 7))) * 8;
    }
#pragma unroll
  for (int jn = 0; jn < 2; ++jn)
#pragma unroll
    for (int kk = 0; kk < 2; ++kk) {
      int rb = wn * 32 + jn * 16 + lr;
      int cidx = kk * 4 + quad;
      boffs[jn][kk] = (rb * 8 + (cidx ^ (rb & 7))) * 8;
    }

  f32x4 acc[4][2];
#pragma unroll
  for (int i = 0; i < 4; ++i)
#pragma unroll
    for (int jn = 0; jn < 2; ++jn) acc[i][jn] = (f32x4){0.f, 0.f, 0.f, 0.f};

  const int kpt = Cin >> 6;
  const int nit = 9 * kpt;
  const size_t bstride = (size_t)Cout * Cin;

  auto stageAB = [&](int it, int sel) {
    int tap = it / kpt, kk = it - tap * kpt;
    int dy = tap / 3 - 1, dx = tap % 3 - 1;
    long offA = ((long)dy * Wp2 + dx) * Cin + (kk << 6);
    long offB = (long)tap * bstride + (kk << 6);
    f16* ab = Asm + sel * CHA;
    f16* bb = Bsm + sel * CHB;
#pragma unroll
    for (int e = 0; e < 4; ++e) LLDS16(gA[e] + offA, ab + lAoff[e]);
#pragma unroll
    for (int e = 0; e < 2; ++e) LLDS16(gB[e] + offB, bb + lBoff[e]);
  };

  stageAB(0, 0);
  int sel = 0;
  for (int ii = 0; ii < nit; ++ii) {
    __syncthreads();
    if (ii + 1 < nit) stageAB(ii + 1, sel ^ 1);
    const f16* ab = Asm + sel * CHA;
    const f16* bb = Bsm + sel * CHB;
    f16x8 af[4][2], bf[2][2];
#pragma unroll
    for (int i = 0; i < 4; ++i)
#pragma unroll
      for (int kk = 0; kk < 2; ++kk) af[i][kk] = *(const f16x8*)&ab[aoffs[i][kk]];
#pragma unroll
    for (int jn = 0; jn < 2; ++jn)
#pragma unroll
      for (int kk = 0; kk < 2; ++kk) bf[jn][kk] = *(const f16x8*)&bb[boffs[jn][kk]];
#pragma unroll
    for (int kk = 0; kk < 2; ++kk)
#pragma unroll
      for (int i = 0; i < 4; ++i)
#pragma unroll
        for (int jn = 0; jn < 2; ++jn)
          acc[i][jn] = __builtin_amdgcn_mfma_f32_16x16x32_f16(af[i][kk], bf[jn][kk], acc[i][jn], 0, 0, 0);
    sel ^= 1;
  }

#pragma unroll
  for (int i = 0; i < 4; ++i) {
    int mg = m0 + wm * 64 + i * 16 + quad * 4;
    int n = mg / HW, p = mg - n * HW;
#pragma unroll
    for (int jn = 0; jn < 2; ++jn) {
      int co = co0 + wn * 32 + jn * 16 + lr;
      float b = bias[co];
      f32x4 v = acc[i][jn];
#pragma unroll
      for (int r = 0; r < 4; ++r) {
        float u = v[r] + b;
        v[r] = (do_lrelu && u < 0.f) ? 0.2f * u : u;
      }
      *(f32x4*)&out[((size_t)n * Cout + co) * HW + p] = v;
    }
  }
}

// ---------------- direct 3x3 conv, CO per thread, optional gn1 partials -----
template <int CO, int CIC>
__global__ __launch_bounds__(256) void conv3x3_kernel(
    const float* __restrict__ in, const float* __restrict__ wgt,
    const float* __restrict__ bias, float* __restrict__ out,
    int Cin, int H, int W, int Cout, int do_lrelu, float* __restrict__ gnp) {
  __shared__ float sm[CIC][18][18];
  int tiles_x = W >> 4;
  int bt = blockIdx.x;
  int tx0 = (bt % tiles_x) << 4;
  int ty0 = (bt / tiles_x) << 4;
  int co0 = blockIdx.y * CO;
  int n = blockIdx.z;
  int tid = threadIdx.x;
  int lx = tid & 15, ly = tid >> 4;

  float acc[CO];
#pragma unroll
  for (int i = 0; i < CO; i++) acc[i] = 0.f;

  const float* inb = in + (size_t)n * Cin * H * W;

  for (int ci0 = 0; ci0 < Cin; ci0 += CIC) {
    __syncthreads();
    for (int idx = tid; idx < CIC * 324; idx += 256) {
      int ci = idx / 324;
      int r = idx - ci * 324;
      int gy = r / 18, gx = r - gy * 18;
      int iy = ty0 + gy - 1, ix = tx0 + gx - 1;
      float v = 0.f;
      if ((unsigned)iy < (unsigned)H && (unsigned)ix < (unsigned)W)
        v = inb[((size_t)(ci0 + ci)) * H * W + (size_t)iy * W + ix];
      sm[ci][gy][gx] = v;
    }
    __syncthreads();
#pragma unroll
    for (int ci = 0; ci < CIC; ci++) {
      float x00 = sm[ci][ly][lx],     x01 = sm[ci][ly][lx + 1],     x02 = sm[ci][ly][lx + 2];
      float x10 = sm[ci][ly + 1][lx], x11 = sm[ci][ly + 1][lx + 1], x12 = sm[ci][ly + 1][lx + 2];
      float x20 = sm[ci][ly + 2][lx], x21 = sm[ci][ly + 2][lx + 1], x22 = sm[ci][ly + 2][lx + 2];
      const float* wp = wgt + ((size_t)co0 * Cin + (ci0 + ci)) * 9;
#pragma unroll
      for (int co = 0; co < CO; co++) {
        const float* wc = wp + (size_t)co * Cin * 9;
        float a = acc[co];
        a = fmaf(wc[0], x00, a); a = fmaf(wc[1], x01, a); a = fmaf(wc[2], x02, a);
        a = fmaf(wc[3], x10, a); a = fmaf(wc[4], x11, a); a = fmaf(wc[5], x12, a);
        a = fmaf(wc[6], x20, a); a = fmaf(wc[7], x21, a); a = fmaf(wc[8], x22, a);
        acc[co] = a;
      }
    }
  }

  float vout[CO];
#pragma unroll
  for (int co = 0; co < CO; co++) {
    float v = acc[co] + bias[co0 + co];
    if (do_lrelu) v = v > 0.f ? v : 0.2f * v;
    vout[co] = v;
  }

  if (gnp) {
    float p0 = 0.f, q0 = 0.f, p1 = 0.f, q1 = 0.f;
#pragma unroll
    for (int co = 0; co < 8; ++co) { p0 += vout[co]; q0 += vout[co] * vout[co]; }
#pragma unroll
    for (int co = 8; co < CO; ++co) { p1 += vout[co]; q1 += vout[co] * vout[co]; }
    float* red = &sm[0][0][0];
    __syncthreads();
    red[tid] = p0; red[256 + tid] = q0; red[512 + tid] = p1; red[768 + tid] = q1;
    __syncthreads();
    for (int st = 128; st > 0; st >>= 1) {
      if (tid < st) {
        red[tid] += red[tid + st]; red[256 + tid] += red[256 + tid + st];
        red[512 + tid] += red[512 + tid + st]; red[768 + tid] += red[768 + tid + st];
      }
      __syncthreads();
    }
    if (tid == 0) {
      int S = gridDim.x;
      gnp[((n * 2 + 0) * S + blockIdx.x) * 2]     = red[0];
      gnp[((n * 2 + 0) * S + blockIdx.x) * 2 + 1] = red[256];
      gnp[((n * 2 + 1) * S + blockIdx.x) * 2]     = red[512];
      gnp[((n * 2 + 1) * S + blockIdx.x) * 2 + 1] = red[768];
    }
  }

  int oy = ty0 + ly, ox = tx0 + lx;
#pragma unroll
  for (int co = 0; co < CO; co++)
    out[(((size_t)n * Cout + co0 + co) * H + oy) * W + ox] = vout[co];
}

// ---- fused inline-GN(input) + conv3x3(lrelu) + iwt + final 1x1 ws-conv -----
template <int CO, int CIC>
__global__ __launch_bounds__(256) void conv3x3_iwt_kernel(
    const float* __restrict__ in, const float* __restrict__ wgt,
    const float* __restrict__ bias, const float* __restrict__ fw,
    const float* __restrict__ gnp, const float* __restrict__ gamma,
    const float* __restrict__ beta, int G, int Sg, int len,
    float* __restrict__ out, int Cin, int H, int W) {
  __shared__ float sm[CIC][18][18];
  __shared__ float csc[16], csh[16];
  int tiles_x = W >> 4;
  int bt = blockIdx.x;
  int tx0 = (bt % tiles_x) << 4;
  int ty0 = (bt / tiles_x) << 4;
  int n = blockIdx.z;
  int tid = threadIdx.x;
  int lx = tid & 15, ly = tid >> 4;

  if (tid < Cin) {
    int g = tid / (Cin / G);
    const float* pp = gnp + (size_t)((n * G + g) * Sg) * 2;
    float s = 0.f, s2 = 0.f;
    for (int i = 0; i < Sg; ++i) { s += pp[2 * i]; s2 += pp[2 * i + 1]; }
    float mean = s / (float)len;
    float var = s2 / (float)len - mean * mean;
    if (var < 0.f) var = 0.f;
    float inv = rsqrtf(var + 1e-5f);
    float ga = gamma[tid];
    csc[tid] = inv * ga;
    csh[tid] = beta[tid] - mean * inv * ga;
  }
  __syncthreads();

  float acc[CO];
#pragma unroll
  for (int i = 0; i < CO; i++) acc[i] = 0.f;

  const float* inb = in + (size_t)n * Cin * H * W;

  for (int ci0 = 0; ci0 < Cin; ci0 += CIC) {
    __syncthreads();
    for (int idx = tid; idx < CIC * 324; idx += 256) {
      int ci = idx / 324;
      int r = idx - ci * 324;
      int gy = r / 18, gx = r - gy * 18;
      int iy = ty0 + gy - 1, ix = tx0 + gx - 1;
      float v = 0.f;
      if ((unsigned)iy < (unsigned)H && (unsigned)ix < (unsigned)W)
        v = inb[((size_t)(ci0 + ci)) * H * W + (size_t)iy * W + ix] * csc[ci0 + ci] + csh[ci0 + ci];
      sm[ci][gy][gx] = v;
    }
    __syncthreads();
#pragma unroll
    for (int ci = 0; ci < CIC; ci++) {
      float x00 = sm[ci][ly][lx],     x01 = sm[ci][ly][lx + 1],     x02 = sm[ci][ly][lx + 2];
      float x10 = sm[ci][ly + 1][lx], x11 = sm[ci][ly + 1][lx + 1], x12 = sm[ci][ly + 1][lx + 2];
      float x20 = sm[ci][ly + 2][lx], x21 = sm[ci][ly + 2][lx + 1], x22 = sm[ci][ly + 2][lx + 2];
      const float* wp = wgt + (size_t)(ci0 + ci) * 9;
#pragma unroll
      for (int co = 0; co < CO; co++) {
        const float* wc = wp + (size_t)co * Cin * 9;
        float a = acc[co];
        a = fmaf(wc[0], x00, a); a = fmaf(wc[1], x01, a); a = fmaf(wc[2], x02, a);
        a = fmaf(wc[3], x10, a); a = fmaf(wc[4], x11, a); a = fmaf(wc[5], x12, a);
        a = fmaf(wc[6], x20, a); a = fmaf(wc[7], x21, a); a = fmaf(wc[8], x22, a);
        acc[co] = a;
      }
    }
  }

  float vout[CO];
#pragma unroll
  for (int co = 0; co < CO; co++) {
    float v = acc[co] + bias[co];
    vout[co] = v > 0.f ? v : 0.2f * v;
  }

  float y0[3], y1[3], y2[3], y3[3];
#pragma unroll
  for (int c = 0; c < 3; ++c) {
    float v0 = vout[4 * c];
    float v1 = 2.f * vout[4 * c + 1] - 1.f;
    float v2 = 2.f * vout[4 * c + 2] - 1.f;
    float v3 = 2.f * vout[4 * c + 3] - 1.f;
    y0[c] = v0 + 0.5f * ( v1 + v2 + v3);
    y1[c] = v0 + 0.5f * ( v1 - v2 - v3);
    y2[c] = v0 + 0.5f * (-v1 + v2 - v3);
    y3[c] = v0 + 0.5f * (-v1 - v2 + v3);
  }
  float w0 = fw[0], w1 = fw[1], w2 = fw[2], w3 = fw[3], w4 = fw[4], w5 = fw[5];
  int oy = ty0 + ly, ox = tx0 + lx;
  int OW = 2 * W;
  size_t ocs = (size_t)(2 * H) * OW;
  float* o0 = out + (size_t)n * 2 * ocs + (size_t)(2 * oy) * OW + 2 * ox;
  o0[0]      = w0 * y0[0] + w1 * y0[1] + w2 * y0[2];
  o0[1]      = w0 * y1[0] + w1 * y1[1] + w2 * y1[2];
  o0[OW]     = w0 * y2[0] + w1 * y2[1] + w2 * y2[2];
  o0[OW + 1] = w0 * y3[0] + w1 * y3[1] + w2 * y3[2];
  float* o1 = o0 + ocs;
  o1[0]      = w3 * y0[0] + w4 * y0[1] + w5 * y0[2];
  o1[1]      = w3 * y1[0] + w4 * y1[1] + w5 * y1[2];
  o1[OW]     = w3 * y2[0] + w4 * y2[1] + w5 * y2[2];
  o1[OW + 1] = w3 * y3[0] + w4 * y3[1] + w5 * y3[2];
}

// ---------------- group norm: stats (partials) ----------------
__global__ __launch_bounds__(256) void gn_stats_kernel(const float* __restrict__ x,
                                                       float* __restrict__ part,
                                                       int C, int HW, int G, int SPLIT) {
  __shared__ float red[512];
  int gs = blockIdx.x;
  int g = gs / SPLIT, s = gs - g * SPLIT;
  int n = blockIdx.y;
  int cpg = C / G;
  int len = cpg * HW;
  int chunk = len / SPLIT;
  size_t base = ((size_t)n * C + (size_t)g * cpg) * HW + (size_t)s * chunk;
  const f32x4* xp = (const f32x4*)(x + base);
  int chunk4 = chunk >> 2;
  float sm = 0.f, s2 = 0.f;
  for (int i = threadIdx.x; i < chunk4; i += 256) {
    f32x4 v = xp[i];
    sm += v.x + v.y + v.z + v.w;
    s2 += v.x * v.x + v.y * v.y + v.z * v.z + v.w * v.w;
  }
  red[threadIdx.x] = sm; red[256 + threadIdx.x] = s2;
  __syncthreads();
  for (int st = 128; st > 0; st >>= 1) {
    if (threadIdx.x < st) {
      red[threadIdx.x] += red[threadIdx.x + st];
      red[256 + threadIdx.x] += red[256 + threadIdx.x + st];
    }
    __syncthreads();
  }
  if (threadIdx.x == 0) {
    int o = ((n * G + g) * SPLIT + s) * 2;
    part[o] = red[0]; part[o + 1] = red[256];
  }
}

// ---------------------------------------------------------------------------

extern "C" void kernel_launch(void* const* d_in, const int* in_sizes, int n_in,
                              void* d_out, int out_size, void* d_ws, size_t ws_size,
                              hipStream_t stream) {
  const float* x        = (const float*)d_in[0];
  const float* conv1_w  = (const float*)d_in[1];
  const float* conv1_b  = (const float*)d_in[2];
  const float* conv2_w  = (const float*)d_in[3];
  const float* conv2_b  = (const float*)d_in[4];
  const float* conv3_w  = (const float*)d_in[5];
  const float* conv3_b  = (const float*)d_in[6];
  const float* conv4_w  = (const float*)d_in[7];
  const float* conv4_b  = (const float*)d_in[8];
  const float* convd1_w = (const float*)d_in[9];
  const float* convd1_b = (const float*)d_in[10];
  const float* convd2_w = (const float*)d_in[11];
  const float* convd2_b = (const float*)d_in[12];
  const float* convd3_w = (const float*)d_in[13];
  const float* convd3_b = (const float*)d_in[14];
  const float* convd4_w = (const float*)d_in[15];
  const float* convd4_b = (const float*)d_in[16];
  const float* final_w  = (const float*)d_in[17];
  const float* gn1_w = (const float*)d_in[18];
  const float* gn1_b = (const float*)d_in[19];
  const float* gn2_w = (const float*)d_in[20];
  const float* gn2_b = (const float*)d_in[21];
  const float* gn3_w = (const float*)d_in[22];
  const float* gn3_b = (const float*)d_in[23];
  const float* gn4_w = (const float*)d_in[24];
  const float* gn4_b = (const float*)d_in[25];

  char* base = (char*)d_ws;
  size_t off = 0;
  auto allocB = [&](size_t bytes) { size_t o = off; off = (off + bytes + 255) & ~(size_t)255; return o; };

  size_t o_sw1  = allocB(16 * 108 * 4);
  size_t o_swd1 = allocB(12 * 144 * 4);
  size_t o_swd2 = allocB(16 * 288 * 4);
  size_t o_swf  = allocB(6 * 4);
  size_t o_pw2  = allocB((size_t)9 * 64 * 64 * 2);
  size_t o_pw3  = allocB((size_t)9 * 256 * 256 * 2);
  size_t o_pw4  = allocB((size_t)9 * 1024 * 1024 * 2);
  size_t o_pwd3 = allocB((size_t)9 * 64 * 128 * 2);
  size_t o_pwd4 = allocB((size_t)9 * 256 * 512 * 2);
  size_t o_R1   = allocB((size_t)NB * 66 * 66 * 128 * 2);  // part | ah64 | ah128
  size_t o_R2   = allocB((size_t)NB * 34 * 34 * 512 * 2);  // ah256 | ah1k | ah512
  size_t o_gnp  = allocB(16384 * 4);                        // gn block partials
  size_t o_c1 = allocB((size_t)NB * 16 * 128 * 128 * 4);
  size_t o_c2 = allocB((size_t)NB * 64 * 64 * 64 * 4);
  size_t o_c3 = allocB((size_t)NB * 256 * 32 * 32 * 4);
  size_t o_w4 = allocB((size_t)NB * 1024 * 16 * 16 * 4);
  size_t o_t1 = allocB((size_t)NB * 1024 * 16 * 16 * 4);
  size_t o_t2 = allocB((size_t)NB * 512 * 32 * 32 * 4);

  if (off > ws_size) return;

  float* c1 = (float*)(base + o_c1);
  float* c2 = (float*)(base + o_c2);
  float* c3 = (float*)(base + o_c3);
  float* w4 = (float*)(base + o_w4);
  float* t1 = (float*)(base + o_t1);
  float* t2 = (float*)(base + o_t2);
  f16* part  = (f16*)(base + o_R1);
  f16* ah64  = (f16*)(base + o_R1);
  f16* ah128 = (f16*)(base + o_R1);
  f16* ah256 = (f16*)(base + o_R2);
  f16* ah1k  = (f16*)(base + o_R2);
  f16* ah512 = (f16*)(base + o_R2);
  f16* pw2 = (f16*)(base + o_pw2);
  f16* pw3 = (f16*)(base + o_pw3);
  f16* pw4 = (f16*)(base + o_pw4);
  f16* pwd3 = (f16*)(base + o_pwd3);
  f16* pwd4 = (f16*)(base + o_pwd4);
  float* gnp = (float*)(base + o_gnp);

  // ---- upfront ----
  {
    int n0 = NB * (2 * 66 + 2 * 64) * (64 / 8);
    int n1 = NB * (2 * 34 + 2 * 32) * (256 / 8);
    int tot = n0 + n1;
    halo2_kernel<<<(tot + 255) / 256, 256, 0, stream>>>(ah64, 64, 64, 64, n0,
                                                        ah256, 256, 32, 32, tot);
  }
  ws_all_kernel<<<46, 256, 0, stream>>>(conv1_w, (float*)(base + o_sw1),
                                        convd1_w, (float*)(base + o_swd1),
                                        convd2_w, (float*)(base + o_swd2),
                                        final_w, (float*)(base + o_swf));
  ws_f16_all_kernel<<<1664, 256, 0, stream>>>(conv2_w, pw2, conv3_w, pw3, conv4_w, pw4,
                                              convd3_w, pwd3, convd4_w, pwd4);

  auto zero_halo = [&](f16* ah, int C, int H, int W) {
    int total8 = NB * (2 * (W + 2) + 2 * H) * (C / 8);
    zero_halo_kernel<<<(total8 + 255) / 256, 256, 0, stream>>>(ah, C, H, W, total8);
  };
  // fused GN + Haar + NHWC pack (+writeback of normalized input, +optional Haar fp32)
  auto wt_nhwc_gn = [&](const float* in, f16* ah, float* haar32, float* wb,
                        const float* gg, const float* gb, int G, int Sg,
                        int C, int Ho, int Wo) {
    int len = (C / G) * (4 * Ho * Wo);
    dim3 g((Ho * Wo) / 256, C / 8, NB);
    wt_nhwc_gn_kernel<<<g, 256, 0, stream>>>(in, gnp, gg, gb, G, Sg, len,
                                             ah, haar32, wb, C, Ho, Wo);
  };
  auto cm6conv = [&](const f16* a, const f16* wt, int Cin, int Hs, int Ws, int Cout) {
    dim3 g((NB * Hs * Ws) / 128, Cout / 128, 2);
    conv_mfma6_kernel<<<g, 256, 0, stream>>>(a, wt, part, Cin, Hs, Ws, Cout, Hs * Ws);
  };
  auto cm6 = [&](const f16* a, const f16* wt, const float* b, float* dest, const float* add,
                 int Cin, int Hs, int Ws, int Cout, int lr, int G, int Sg) {
    cm6conv(a, wt, Cin, Hs, Ws, Cout);
    int total4 = (NB * Cout * Hs * Ws) >> 2;
    reduceS_kernel<<<(total4 + 255) / 256, 256, 0, stream>>>(
        part, b, add, dest, Cout, Hs * Ws, 2, lr, total4, G ? gnp : nullptr, G, Sg);
  };
  auto cm3 = [&](const f16* a, const f16* wt, const float* b, float* o,
                 int Cin, int Hs, int Ws, int Cout, int lr) {
    dim3 g((NB * Hs * Ws) / 128, Cout / 64);
    conv_mfma3_kernel<<<g, 256, 0, stream>>>(a, wt, b, o, Cin, Hs, Ws, Cout, Hs * Ws, lr);
  };
  auto stats = [&](const float* xb, int C, int HW, int G, int SPLIT) {
    dim3 gsd(G * SPLIT, NB);
    gn_stats_kernel<<<gsd, 256, 0, stream>>>(xb, gnp, C, HW, G, SPLIT);
  };

  // ==== encoder ====
  {
    int total = NB * 3 * 128 * 128;
    wt_kernel<<<(total + 255) / 256, 256, 0, stream>>>(x, t1, 3, 128, 128, total);  // w1
  }
  {
    dim3 g(64, 1, NB);
    conv3x3_kernel<16, 4><<<g, 256, 0, stream>>>(t1, (float*)(base + o_sw1), conv1_b,
                                                 c1, 12, 128, 128, 16, 1, gnp);
  }
  // gn1(c1) fused into wt_nhwc_gn (writeback -> c1 for skip use); w2 -> ah64
  wt_nhwc_gn(c1, ah64, nullptr, c1, gn1_w, gn1_b, 2, 64, 16, 64, 64);

  cm3(ah64, pw2, conv2_b, c2, 64, 64, 64, 64, 1);                   // c2
  stats(c2, 64, 4096, 8, 16);
  // gn2(c2) fused; w3 -> ah256
  wt_nhwc_gn(c2, ah256, nullptr, c2, gn2_w, gn2_b, 8, 16, 64, 32, 32);

  cm6(ah256, pw3, conv3_b, c3, nullptr, 256, 32, 32, 256, 1, 32, 8);  // c3 (+partials)
  zero_halo(ah1k, 1024, 16, 16);
  // gn3(c3) fused; w4 -> ah1k + fp32 Haar copy (residual) + writeback -> c3
  wt_nhwc_gn(c3, ah1k, w4, c3, gn3_w, gn3_b, 32, 8, 256, 16, 16);

  cm6(ah1k, pw4, conv4_b, t1, nullptr, 1024, 16, 16, 1024, 1, 128, 2);  // c4 -> t1
  {
    dim3 g(1, 32, NB);
    gn_nhwc_kernel<<<g, 256, 0, stream>>>(t1, gnp, gn4_w, gn4_b, ah1k, 1024, 16, 16,
                                          128, 2, 2048);
  }
  cm6(ah1k, pw4, conv4_b, t2, nullptr, 1024, 16, 16, 1024, 1, 128, 2);  // c5 -> t2
  {
    dim3 g(1, 32, NB);
    gn_nhwc_kernel<<<g, 256, 0, stream>>>(t2, gnp, gn4_w, gn4_b, ah1k, 1024, 16, 16,
                                          128, 2, 2048);
  }
  // c6 partials only (split-K reduce folded into the iw4 concat below)
  cm6conv(ah1k, pw4, 1024, 16, 16, 1024);

  // ==== decoder ====
  // iw4 = concat(c3, iwt(lrelu(part0+part1+bias+w4))) -> ah512 (NHWC f16, no GN)
  zero_halo(ah512, 512, 32, 32);
  {
    dim3 g(4, 16, NB);  // 1024 px / 256, 512 ch / 32
    concat_iwt_nhwc_kernel<<<g, 256, 0, stream>>>(
        c3, nullptr, part, conv4_b, w4,
        nullptr, nullptr, nullptr, 0, 0, 0, ah512, 256, 16, 16);
  }
  cm6(ah512, pwd4, convd4_b, t1, nullptr, 512, 32, 32, 256, 1, 32, 8);  // ic3 (+partials)
  // iw3 = concat(c2, iwt(gn3(ic3))) -> ah128 (NHWC f16, gn3 inline)
  zero_halo(ah128, 128, 64, 64);
  {
    dim3 g(16, 4, NB);  // 4096 px / 256, 128 ch / 32
    concat_iwt_nhwc_kernel<<<g, 256, 0, stream>>>(
        c2, t1, nullptr, nullptr, nullptr,
        gnp, gn3_w, gn3_b, 32, 8, 8192, ah128, 64, 32, 32);
  }
  cm3(ah128, pwd3, convd3_b, t1, 128, 64, 64, 64, 1);               // ic2 -> t1
  stats(t1, 64, 4096, 8, 16);
  // iw2 -> t2 (NCHW fp32; consumed by direct conv) with gn2 inline
  {
    int totalA = NB * 16 * 4 * 64 * 64;
    int total = totalA + NB * 16 * 64 * 64;
    int len = (64 / 8) * 64 * 64;
    concat_iwt_kernel<<<(total + 255) / 256, 256, 0, stream>>>(
        c1, t1, t2, gnp, gn2_w, gn2_b, 8, 16, len, 16, 64, 64, totalA, total);
  }
  {
    dim3 g(64, 1, NB);
    conv3x3_kernel<16, 4><<<g, 256, 0, stream>>>(t2, (float*)(base + o_swd2), convd2_b,
                                                 t1, 32, 128, 128, 16, 1, gnp);
  }
  // gn1(ic1) fused into conv3x3_iwt's input read; final conv + iwt + 1x1
  {
    dim3 g(64, 1, NB);
    conv3x3_iwt_kernel<12, 4><<<g, 256, 0, stream>>>(
        t1, (float*)(base + o_swd1), convd1_b, (float*)(base + o_swf),
        gnp, gn1_w, gn1_b, 2, 64, 8 * 128 * 128, (float*)d_out, 16, 128, 128);
  }
}

// Round 10
// 892.171 us; speedup vs baseline: 1.0770x; 1.0770x over previous
//
#include <hip/hip_runtime.h>
#include <math.h>

// ---------------------------------------------------------------------------
// WaveletNet forward. conv_mfma6: 128x128x64 double-buffered (1 barrier/iter),
// split-K=2, 256 threads, 2 blocks/CU (cross-block overlap is the latency
// hiding mechanism - R4/R5/R7 ablations). GN-apply fused into consumers
// (wt_nhwc_gn / conv3x3_iwt). ic4 split-K reduce folded into the iw4 concat
// (NCHW concat keeps coalesced pattern - R9 lesson: NHWC-direct concat's
// per-thread gather loses more than the traffic it saves).
// conv_mfma3: 128x64x64 dbuf. GN via block-partials. N=16 fixed.
// ---------------------------------------------------------------------------

#define NB 16  // batch

typedef _Float16 f16;
typedef _Float16 f16x8 __attribute__((ext_vector_type(8)));
typedef _Float16 f16x4 __attribute__((ext_vector_type(4)));
typedef float f32x4 __attribute__((ext_vector_type(4)));
typedef float f32x2 __attribute__((ext_vector_type(2)));
typedef unsigned int u32;

#define LLDS16(gp, lp)                                                          \
  __builtin_amdgcn_global_load_lds((const __attribute__((address_space(1))) u32*)(const void*)(gp), \
                                   (__attribute__((address_space(3))) u32*)(void*)(lp), 16, 0, 0)

// ---------------- weight standardization ----------------
__device__ __forceinline__ void ws_reduce(const float* wp, int fan, float* red,
                                          float& mean, float& inv) {
  float s = 0.f, s2 = 0.f;
  for (int i = threadIdx.x; i < fan; i += 256) { float v = wp[i]; s += v; s2 += v * v; }
  red[threadIdx.x] = s; red[256 + threadIdx.x] = s2;
  __syncthreads();
  for (int st = 128; st > 0; st >>= 1) {
    if (threadIdx.x < st) {
      red[threadIdx.x] += red[threadIdx.x + st];
      red[256 + threadIdx.x] += red[256 + threadIdx.x + st];
    }
    __syncthreads();
  }
  float sum = red[0], sumsq = red[256];
  mean = sum / (float)fan;
  float var = (sumsq - sum * mean) / (float)(fan - 1);
  if (var < 0.f) var = 0.f;
  inv = 1.0f / (sqrtf(var) + 1e-5f);
}

__global__ void ws_all_kernel(const float* w0, float* o0, const float* w1, float* o1,
                              const float* w2, float* o2, const float* w3, float* o3) {
  __shared__ float red[512];
  int b = blockIdx.x;
  const float* w; float* o; int fan, oi;
  if (b < 16)      { w = w0; o = o0; fan = 108; oi = b; }
  else if (b < 28) { w = w1; o = o1; fan = 144; oi = b - 16; }
  else if (b < 44) { w = w2; o = o2; fan = 288; oi = b - 28; }
  else             { w = w3; o = o3; fan = 3;   oi = b - 44; }
  const float* wp = w + (size_t)oi * fan;
  float mean, inv; ws_reduce(wp, fan, red, mean, inv);
  for (int i = threadIdx.x; i < fan; i += 256)
    o[(size_t)oi * fan + i] = (wp[i] - mean) * inv;
}

__global__ void ws_f16_all_kernel(const float* w0, f16* o0, const float* w1, f16* o1,
                                  const float* w2, f16* o2, const float* w3, f16* o3,
                                  const float* w4, f16* o4) {
  __shared__ float red[512];
  int b = blockIdx.x;
  const float* w; f16* o; int fan, Cin, Cout, oi;
  if (b < 64)        { w = w0; o = o0; fan = 576;  Cin = 64;   Cout = 64;   oi = b; }
  else if (b < 320)  { w = w1; o = o1; fan = 2304; Cin = 256;  Cout = 256;  oi = b - 64; }
  else if (b < 1344) { w = w2; o = o2; fan = 9216; Cin = 1024; Cout = 1024; oi = b - 320; }
  else if (b < 1408) { w = w3; o = o3; fan = 1152; Cin = 128;  Cout = 64;   oi = b - 1344; }
  else               { w = w4; o = o4; fan = 4608; Cin = 512;  Cout = 256;  oi = b - 1408; }
  const float* wp = w + (size_t)oi * fan;
  float mean, inv; ws_reduce(wp, fan, red, mean, inv);
  for (int i = threadIdx.x; i < fan; i += 256) {
    int ci = i / 9, tap = i - ci * 9;
    o[((size_t)tap * Cout + oi) * Cin + ci] = (f16)((wp[i] - mean) * inv);
  }
}

// ---------------- halo zero ----------------
__device__ __forceinline__ void halo_write(f16* buf, int C, int H, int W, int t) {
  int c8s = C >> 3;
  int c8 = t % c8s; int q = t / c8s;
  int P = 2 * (W + 2) + 2 * H;
  int b = q % P; int n = q / P;
  int y, x;
  if (b < W + 2) { y = 0; x = b; }
  else if (b < 2 * (W + 2)) { y = H + 1; x = b - (W + 2); }
  else { int bb = b - 2 * (W + 2); y = 1 + (bb >> 1); x = (bb & 1) ? (W + 1) : 0; }
  size_t a = (((size_t)n * (H + 2) + y) * (W + 2) + x) * C + c8 * 8;
  *(f16x8*)(buf + a) = (f16x8){0, 0, 0, 0, 0, 0, 0, 0};
}

__global__ void halo2_kernel(f16* b0, int c0, int h0, int w0, int n0,
                             f16* b1, int c1, int h1, int w1, int total) {
  int idx = blockIdx.x * 256 + threadIdx.x;
  if (idx >= total) return;
  if (idx < n0) halo_write(b0, c0, h0, w0, idx);
  else halo_write(b1, c1, h1, w1, idx - n0);
}

__global__ void zero_halo_kernel(f16* __restrict__ buf, int C, int H, int W, int total8) {
  int idx = blockIdx.x * 256 + threadIdx.x;
  if (idx >= total8) return;
  halo_write(buf, C, H, W, idx);
}

// ---------------- Haar forward (NCHW fp32) ----------------
__global__ void wt_kernel(const float* __restrict__ in, float* __restrict__ out,
                          int C, int Ho, int Wo, int total) {
  int idx = blockIdx.x * 256 + threadIdx.x;
  if (idx >= total) return;
  int w = idx % Wo; int t = idx / Wo;
  int h = t % Ho; t /= Ho;
  int c = t % C; int n = t / C;
  int Wi = 2 * Wo;
  const float* ip = in + (((size_t)n * C + c) * (2 * Ho) + 2 * h) * Wi + 2 * w;
  float a = ip[0], b = ip[1], cc = ip[Wi], d = ip[Wi + 1];
  size_t cs = (size_t)Ho * Wo;
  float* op = out + (((size_t)n * 4 * C + 4 * c) * Ho + h) * Wo + w;
  op[0]      = 0.25f * (a + b + cc + d);
  op[cs]     = 0.25f * (a + b - cc - d) + 0.5f;
  op[2 * cs] = 0.25f * (a - b + cc - d) + 0.5f;
  op[3 * cs] = 0.25f * (a - b - cc + d) + 0.5f;
}

// ---------------- fused GN-apply + Haar + NCHW->padded NHWC f16 -------------
__global__ __launch_bounds__(256) void wt_nhwc_gn_kernel(
    const float* __restrict__ in, const float* __restrict__ gnp,
    const float* __restrict__ gamma, const float* __restrict__ beta,
    int G, int Sg, int len,
    f16* __restrict__ out, float* __restrict__ out32, float* __restrict__ gnwb,
    int C, int Ho, int Wo) {
  __shared__ f16 sm[32][264];
  __shared__ float scs[8], shs[8];
  int HWo = Ho * Wo;
  int p0 = blockIdx.x * 256, c0 = blockIdx.y * 8, n = blockIdx.z;
  int t = threadIdx.x;
  if (t < 8) {
    int c = c0 + t;
    int g = c / (C / G);
    const float* pp = gnp + (size_t)((n * G + g) * Sg) * 2;
    float s = 0.f, s2 = 0.f;
    for (int i = 0; i < Sg; ++i) { s += pp[2 * i]; s2 += pp[2 * i + 1]; }
    float mean = s / (float)len;
    float var = s2 / (float)len - mean * mean;
    if (var < 0.f) var = 0.f;
    float inv = rsqrtf(var + 1e-5f);
    float ga = gamma[c];
    scs[t] = inv * ga;
    shs[t] = beta[c] - mean * inv * ga;
  }
  __syncthreads();
  int p = p0 + t; int h = p / Wo; int ww = p - h * Wo;
  int Wi = 2 * Wo;
  int C4 = 4 * C;
#pragma unroll
  for (int r = 0; r < 8; ++r) {
    size_t ioff = (((size_t)n * C + c0 + r) * (2 * Ho) + 2 * h) * Wi + 2 * ww;
    const float* ip = in + ioff;
    f32x2 u0 = *(const f32x2*)ip;
    f32x2 u1 = *(const f32x2*)(ip + Wi);
    float sc = scs[r], sh = shs[r];
    float a = u0.x * sc + sh, b = u0.y * sc + sh;
    float cc = u1.x * sc + sh, d = u1.y * sc + sh;
    if (gnwb) {
      float* wp = gnwb + ioff;
      *(f32x2*)wp = (f32x2){a, b};
      *(f32x2*)(wp + Wi) = (f32x2){cc, d};
    }
    float v0 = 0.25f * (a + b + cc + d);
    float v1 = 0.25f * (a + b - cc - d) + 0.5f;
    float v2 = 0.25f * (a - b + cc - d) + 0.5f;
    float v3 = 0.25f * (a - b - cc + d) + 0.5f;
    sm[4 * r][t]     = (f16)v0;
    sm[4 * r + 1][t] = (f16)v1;
    sm[4 * r + 2][t] = (f16)v2;
    sm[4 * r + 3][t] = (f16)v3;
    if (out32) {
      float* op = out32 + (((size_t)n * C4 + 4 * (c0 + r)) * Ho + h) * Wo + ww;
      size_t cs = (size_t)HWo;
      op[0] = v0; op[cs] = v1; op[2 * cs] = v2; op[3 * cs] = v3;
    }
  }
  __syncthreads();
#pragma unroll
  for (int i = 0; i < 4; ++i) {
    int c = t + i * 256;
    int pl = c >> 2, cio = (c & 3) * 8;
    f16x8 v;
#pragma unroll
    for (int u = 0; u < 8; ++u) v[u] = sm[cio + u][pl];
    int pp = p0 + pl; int y = pp / Wo; int x = pp - y * Wo;
    *(f16x8*)(out + (((size_t)n * (Ho + 2) + y + 1) * (Wo + 2) + x + 1) * C4 + c0 * 4 + cio) = v;
  }
}

// ---------------- fused concat + iwt (+optional inline GN / part-reduce) ----
// v-source: fp32 NCHW v, OR split-K f16 part pair (+bias,+add fp32,+lrelu).
__global__ void concat_iwt_kernel(const float* __restrict__ skip, const float* __restrict__ v,
                                  const f16* __restrict__ part, const float* __restrict__ bias,
                                  const float* __restrict__ add,
                                  float* __restrict__ out, const float* __restrict__ gnp,
                                  const float* __restrict__ gamma, const float* __restrict__ beta,
                                  int G, int Sg, int len, int C, int Hh, int Wh,
                                  int totalA, int total) {
  int idx = blockIdx.x * 256 + threadIdx.x;
  if (idx >= total) return;
  int W = 2 * Wh, H = 2 * Hh; int HWs = H * W;
  if (idx < totalA) {
    int p = idx % HWs; int t = idx / HWs; int c = t % C; int n = t / C;
    out[((size_t)n * 2 * C + c) * HWs + p] = skip[idx];
    return;
  }
  int i2 = idx - totalA;
  int w = i2 % Wh; int t = i2 / Wh; int h = t % Hh; t /= Hh;
  int c = t % C; int n = t / C;
  size_t cs = (size_t)Hh * Wh;
  float v0, v1, v2, v3;
  if (part) {
    size_t base_off = (((size_t)n * 4 * C + 4 * c) * Hh + h) * Wh + w;
    size_t sstr = (size_t)NB * 4 * C * cs;
    float vv[4];
#pragma unroll
    for (int k = 0; k < 4; ++k) {
      size_t off = base_off + (size_t)k * cs;
      float val = (float)part[off] + (float)part[sstr + off] + bias[4 * c + k];
      if (add) val += add[off];
      vv[k] = val > 0.f ? val : 0.2f * val;
    }
    v0 = vv[0]; v1 = vv[1]; v2 = vv[2]; v3 = vv[3];
  } else {
    const float* vp = v + (((size_t)n * 4 * C + 4 * c) * Hh + h) * Wh + w;
    v0 = vp[0]; v1 = vp[cs]; v2 = vp[2 * cs]; v3 = vp[3 * cs];
  }
  if (gnp) {
    int cpg = (4 * C) / G;
    int g = (4 * c) / cpg;
    const float* pp = gnp + (size_t)((n * G + g) * Sg) * 2;
    float s = 0.f, s2 = 0.f;
    for (int i = 0; i < Sg; ++i) { s += pp[2 * i]; s2 += pp[2 * i + 1]; }
    float mean = s / (float)len;
    float var = s2 / (float)len - mean * mean;
    if (var < 0.f) var = 0.f;
    float inv = rsqrtf(var + 1e-5f);
    v0 = (v0 - mean) * inv * gamma[4 * c]     + beta[4 * c];
    v1 = (v1 - mean) * inv * gamma[4 * c + 1] + beta[4 * c + 1];
    v2 = (v2 - mean) * inv * gamma[4 * c + 2] + beta[4 * c + 2];
    v3 = (v3 - mean) * inv * gamma[4 * c + 3] + beta[4 * c + 3];
  }
  v1 = 2.f * v1 - 1.f; v2 = 2.f * v2 - 1.f; v3 = 2.f * v3 - 1.f;
  float* op = out + (((size_t)n * 2 * C + C + c) * H + 2 * h) * (size_t)W + 2 * w;
  op[0]     = v0 + 0.5f * ( v1 + v2 + v3);
  op[1]     = v0 + 0.5f * ( v1 - v2 - v3);
  op[W]     = v0 + 0.5f * (-v1 + v2 - v3);
  op[W + 1] = v0 + 0.5f * (-v1 - v2 + v3);
}

// ---------------- NCHW fp32 -> padded NHWC f16 (LDS transpose) --------------
__global__ __launch_bounds__(256) void to_nhwc_pad_kernel(const float* __restrict__ in,
                                                          f16* __restrict__ out,
                                                          int C, int H, int W) {
  __shared__ f16 sm[32][264];
  int HW = H * W;
  int p0 = blockIdx.x * 256, c0 = blockIdx.y * 32, n = blockIdx.z;
  int t = threadIdx.x;
  const float* ip = in + ((size_t)n * C + c0) * HW + p0;
#pragma unroll 8
  for (int r = 0; r < 32; ++r) sm[r][t] = (f16)ip[(size_t)r * HW + t];
  __syncthreads();
#pragma unroll
  for (int i = 0; i < 4; ++i) {
    int c = t + i * 256;
    int pl = c >> 2, cio = (c & 3) * 8;
    f16x8 v;
#pragma unroll
    for (int u = 0; u < 8; ++u) v[u] = sm[cio + u][pl];
    int p = p0 + pl; int y = p / W; int x = p - y * W;
    *(f16x8*)(out + (((size_t)n * (H + 2) + y + 1) * (W + 2) + x + 1) * C + c0 + cio) = v;
  }
}

// ---------------- GN-apply (partial-based) + NCHW->padded NHWC f16 ----------
__global__ __launch_bounds__(256) void gn_nhwc_kernel(
    const float* __restrict__ in, const float* __restrict__ gnp,
    const float* __restrict__ gamma, const float* __restrict__ beta,
    f16* __restrict__ out, int C, int H, int W, int G, int Sg, int len) {
  __shared__ f16 sm[32][264];
  int HW = H * W;
  int p0 = blockIdx.x * 256, c0 = blockIdx.y * 32, n = blockIdx.z;
  int t = threadIdx.x;
  int cpg = C / G;
  const float* ip = in + ((size_t)n * C + c0) * HW + p0;
#pragma unroll 8
  for (int r = 0; r < 32; ++r) {
    int c = c0 + r; int g = c / cpg;
    const float* pp = gnp + (size_t)((n * G + g) * Sg) * 2;
    float s = 0.f, s2 = 0.f;
    for (int i = 0; i < Sg; ++i) { s += pp[2 * i]; s2 += pp[2 * i + 1]; }
    float mean = s / (float)len;
    float var = s2 / (float)len - mean * mean;
    if (var < 0.f) var = 0.f;
    float inv = rsqrtf(var + 1e-5f);
    float ga = gamma[c], be = beta[c];
    sm[r][t] = (f16)((ip[(size_t)r * HW + t] - mean) * inv * ga + be);
  }
  __syncthreads();
#pragma unroll
  for (int i = 0; i < 4; ++i) {
    int c = t + i * 256;
    int pl = c >> 2, cio = (c & 3) * 8;
    f16x8 v;
#pragma unroll
    for (int u = 0; u < 8; ++u) v[u] = sm[cio + u][pl];
    int p = p0 + pl; int y = p / W; int x = p - y * W;
    *(f16x8*)(out + (((size_t)n * (H + 2) + y + 1) * (W + 2) + x + 1) * C + c0 + cio) = v;
  }
}

// ---------------- conv_mfma6: 128x128x64, dbuf, 1 barrier/iter, split-K -----
__global__ __launch_bounds__(256) void conv_mfma6_kernel(
    const f16* __restrict__ A, const f16* __restrict__ Wp,
    f16* __restrict__ part, int Cin, int H, int W, int Cout, int HW) {
  constexpr int CH = 128 * 64;  // f16 per buffer
  __shared__ f16 Asm[2 * CH];   // 32 KB
  __shared__ f16 Bsm[2 * CH];   // 32 KB

  const int tid = threadIdx.x;
  const int w = tid >> 6, lane = tid & 63;
  const int m0 = blockIdx.x * 128;
  const int co0 = blockIdx.y * 128;
  const int Wp2 = W + 2;

  const f16* gA[4]; const f16* gB[4];
  int lOff[4];
#pragma unroll
  for (int e = 0; e < 4; ++e) {
    int c = e * 256 + tid;
    int r = c >> 3, j = c & 7;
    int jx = j ^ (r & 7);
    int m = m0 + r; int n = m / HW; int p = m - n * HW;
    int y = p / W; int x = p - y * W;
    gA[e] = A + (((size_t)n * (H + 2) + y + 1) * Wp2 + (x + 1)) * Cin + jx * 8;
    gB[e] = Wp + (size_t)(co0 + r) * Cin + jx * 8;
    lOff[e] = (e * 256 + w * 64) * 8;  // wave-uniform
  }

  const int wm = w & 1, wn = w >> 1;
  const int lr = lane & 15, quad = lane >> 4;
  int aoffs[4][2], boffs[4][2];
#pragma unroll
  for (int i = 0; i < 4; ++i)
#pragma unroll
    for (int kk = 0; kk < 2; ++kk) {
      int r = wm * 64 + i * 16 + lr;
      int cidx = kk * 4 + quad;
      aoffs[i][kk] = (r * 8 + (cidx ^ (r & 7))) * 8;
      int rb = wn * 64 + i * 16 + lr;
      boffs[i][kk] = (rb * 8 + (cidx ^ (rb & 7))) * 8;
    }

  f32x4 acc[4][4];
#pragma unroll
  for (int i = 0; i < 4; ++i)
#pragma unroll
    for (int j = 0; j < 4; ++j) acc[i][j] = (f32x4){0.f, 0.f, 0.f, 0.f};

  const int kpt = Cin >> 6;
  const int nit = (9 * kpt) / gridDim.z;
  const int it0 = blockIdx.z * nit;
  const size_t bstride = (size_t)Cout * Cin;

  auto stageAB = [&](int it, int sel) {
    int tap = it / kpt, kk = it - tap * kpt;
    int dy = tap / 3 - 1, dx = tap % 3 - 1;
    long offA = ((long)dy * Wp2 + dx) * Cin + (kk << 6);
    long offB = (long)tap * bstride + (kk << 6);
    f16* ab = Asm + sel * CH;
    f16* bb = Bsm + sel * CH;
#pragma unroll
    for (int e = 0; e < 4; ++e) {
      LLDS16(gA[e] + offA, ab + lOff[e]);
      LLDS16(gB[e] + offB, bb + lOff[e]);
    }
  };

  stageAB(it0, 0);
  int sel = 0;
  for (int ii = 0; ii < nit; ++ii) {
    __syncthreads();  // drains prefetch (vmcnt) + prior reads (lgkm)
    if (ii + 1 < nit) stageAB(it0 + ii + 1, sel ^ 1);  // overlaps compute below
    const f16* ab = Asm + sel * CH;
    const f16* bb = Bsm + sel * CH;
    f16x8 af[4][2], bf[4][2];
#pragma unroll
    for (int i = 0; i < 4; ++i)
#pragma unroll
      for (int kk = 0; kk < 2; ++kk) {
        af[i][kk] = *(const f16x8*)&ab[aoffs[i][kk]];
        bf[i][kk] = *(const f16x8*)&bb[boffs[i][kk]];
      }
#pragma unroll
    for (int kk = 0; kk < 2; ++kk)
#pragma unroll
      for (int i = 0; i < 4; ++i)
#pragma unroll
        for (int j = 0; j < 4; ++j)
          acc[i][j] = __builtin_amdgcn_mfma_f32_16x16x32_f16(af[i][kk], bf[j][kk], acc[i][j], 0, 0, 0);
    sel ^= 1;
  }

  const size_t pbase = (size_t)blockIdx.z * NB * Cout * HW;
#pragma unroll
  for (int i = 0; i < 4; ++i) {
    int mg = m0 + wm * 64 + i * 16 + quad * 4;
    int n = mg / HW, p = mg - n * HW;
#pragma unroll
    for (int j = 0; j < 4; ++j) {
      int co = co0 + wn * 64 + j * 16 + lr;
      f32x4 v = acc[i][j];
      f16x4 h;
#pragma unroll
      for (int r = 0; r < 4; ++r) h[r] = (f16)v[r];
      *(f16x4*)&part[pbase + ((size_t)n * Cout + co) * HW + p] = h;
    }
  }
}

// ---------------- reduce S partials + bias (+add)(+lrelu) + GN partials -----
__global__ __launch_bounds__(256) void reduceS_kernel(
    const f16* __restrict__ part, const float* __restrict__ bias,
    const float* __restrict__ add, float* __restrict__ out,
    int Cout, int HW, int S, int do_lrelu, int total4,
    float* __restrict__ gnp, int G, int Sg) {
  __shared__ float red[512];
  int idx = blockIdx.x * 256 + threadIdx.x;
  if (idx >= total4) return;
  size_t sstride = (size_t)NB * Cout * HW;
  int hw4 = HW >> 2;
  int p4 = idx % hw4; int t = idx / hw4;
  int c = t % Cout;
  size_t eoff = (size_t)t * HW + p4 * 4;
  float b = bias[c];
  f32x4 o = {b, b, b, b};
  for (int s = 0; s < S; ++s) {
    f16x4 a = *(const f16x4*)(part + s * sstride + eoff);
#pragma unroll
    for (int r = 0; r < 4; ++r) o[r] += (float)a[r];
  }
  if (add) {
    f32x4 av = *(const f32x4*)(add + eoff);
#pragma unroll
    for (int r = 0; r < 4; ++r) o[r] += av[r];
  }
  if (do_lrelu)
#pragma unroll
    for (int r = 0; r < 4; ++r) o[r] = o[r] > 0.f ? o[r] : 0.2f * o[r];
  *(f32x4*)(out + eoff) = o;
  if (gnp) {
    float ls = o[0] + o[1] + o[2] + o[3];
    float ls2 = o[0]*o[0] + o[1]*o[1] + o[2]*o[2] + o[3]*o[3];
    red[threadIdx.x] = ls; red[256 + threadIdx.x] = ls2;
    __syncthreads();
    for (int st = 128; st > 0; st >>= 1) {
      if (threadIdx.x < st) {
        red[threadIdx.x] += red[threadIdx.x + st];
        red[256 + threadIdx.x] += red[256 + threadIdx.x + st];
      }
      __syncthreads();
    }
    if (threadIdx.x == 0) {
      int flat0 = blockIdx.x * 1024;
      int chw = Cout * HW;
      int n = flat0 / chw;
      int rem = flat0 - n * chw;
      int L = (Cout / G) * HW;
      int g = rem / L;
      int s = (rem - g * L) >> 10;
      gnp[((n * G + g) * Sg + s) * 2] = red[0];
      gnp[((n * G + g) * Sg + s) * 2 + 1] = red[256];
    }
  }
}

// ---------------- conv_mfma3: 128x64x64, dbuf, 1 barrier/iter (Cout=64) -----
__global__ __launch_bounds__(256) void conv_mfma3_kernel(
    const f16* __restrict__ A, const f16* __restrict__ Wp,
    const float* __restrict__ bias, float* __restrict__ out,
    int Cin, int H, int W, int Cout, int HW, int do_lrelu) {
  constexpr int CHA = 128 * 64;  // f16 per A buffer
  constexpr int CHB = 64 * 64;   // f16 per B buffer
  __shared__ f16 Asm[2 * CHA];   // 32 KB
  __shared__ f16 Bsm[2 * CHB];   // 16 KB

  const int tid = threadIdx.x;
  const int w = tid >> 6, lane = tid & 63;
  const int m0 = blockIdx.x * 128;
  const int co0 = blockIdx.y * 64;
  const int Wp2 = W + 2;

  const f16* gA[4];
  int lAoff[4];
#pragma unroll
  for (int e = 0; e < 4; ++e) {
    int c = e * 256 + tid;
    int r = c >> 3, j = c & 7;
    int jx = j ^ (r & 7);
    int m = m0 + r; int n = m / HW; int p = m - n * HW;
    int y = p / W; int x = p - y * W;
    gA[e] = A + (((size_t)n * (H + 2) + y + 1) * Wp2 + (x + 1)) * Cin + jx * 8;
    lAoff[e] = (e * 256 + w * 64) * 8;
  }
  const f16* gB[2];
  int lBoff[2];
#pragma unroll
  for (int e = 0; e < 2; ++e) {
    int c = e * 256 + tid;
    int r = c >> 3, j = c & 7;
    int jx = j ^ (r & 7);
    gB[e] = Wp + (size_t)(co0 + r) * Cin + jx * 8;
    lBoff[e] = (e * 256 + w * 64) * 8;
  }

  const int wm = w & 1, wn = w >> 1;
  const int lr = lane & 15, quad = lane >> 4;
  int aoffs[4][2], boffs[2][2];
#pragma unroll
  for (int i = 0; i < 4; ++i)
#pragma unroll
    for (int kk = 0; kk < 2; ++kk) {
      int r = wm * 64 + i * 16 + lr;
      int cidx = kk * 4 + quad;
      aoffs[i][kk] = (r * 8 + (cidx ^ (r & 7))) * 8;
    }
#pragma unroll
  for (int jn = 0; jn < 2; ++jn)
#pragma unroll
    for (int kk = 0; kk < 2; ++kk) {
      int rb = wn * 32 + jn * 16 + lr;
      int cidx = kk * 4 + quad;
      boffs[jn][kk] = (rb * 8 + (cidx ^ (rb & 7))) * 8;
    }

  f32x4 acc[4][2];
#pragma unroll
  for (int i = 0; i < 4; ++i)
#pragma unroll
    for (int jn = 0; jn < 2; ++jn) acc[i][jn] = (f32x4){0.f, 0.f, 0.f, 0.f};

  const int kpt = Cin >> 6;
  const int nit = 9 * kpt;
  const size_t bstride = (size_t)Cout * Cin;

  auto stageAB = [&](int it, int sel) {
    int tap = it / kpt, kk = it - tap * kpt;
    int dy = tap / 3 - 1, dx = tap % 3 - 1;
    long offA = ((long)dy * Wp2 + dx) * Cin + (kk << 6);
    long offB = (long)tap * bstride + (kk << 6);
    f16* ab = Asm + sel * CHA;
    f16* bb = Bsm + sel * CHB;
#pragma unroll
    for (int e = 0; e < 4; ++e) LLDS16(gA[e] + offA, ab + lAoff[e]);
#pragma unroll
    for (int e = 0; e < 2; ++e) LLDS16(gB[e] + offB, bb + lBoff[e]);
  };

  stageAB(0, 0);
  int sel = 0;
  for (int ii = 0; ii < nit; ++ii) {
    __syncthreads();
    if (ii + 1 < nit) stageAB(ii + 1, sel ^ 1);
    const f16* ab = Asm + sel * CHA;
    const f16* bb = Bsm + sel * CHB;
    f16x8 af[4][2], bf[2][2];
#pragma unroll
    for (int i = 0; i < 4; ++i)
#pragma unroll
      for (int kk = 0; kk < 2; ++kk) af[i][kk] = *(const f16x8*)&ab[aoffs[i][kk]];
#pragma unroll
    for (int jn = 0; jn < 2; ++jn)
#pragma unroll
      for (int kk = 0; kk < 2; ++kk) bf[jn][kk] = *(const f16x8*)&bb[boffs[jn][kk]];
#pragma unroll
    for (int kk = 0; kk < 2; ++kk)
#pragma unroll
      for (int i = 0; i < 4; ++i)
#pragma unroll
        for (int jn = 0; jn < 2; ++jn)
          acc[i][jn] = __builtin_amdgcn_mfma_f32_16x16x32_f16(af[i][kk], bf[jn][kk], acc[i][jn], 0, 0, 0);
    sel ^= 1;
  }

#pragma unroll
  for (int i = 0; i < 4; ++i) {
    int mg = m0 + wm * 64 + i * 16 + quad * 4;
    int n = mg / HW, p = mg - n * HW;
#pragma unroll
    for (int jn = 0; jn < 2; ++jn) {
      int co = co0 + wn * 32 + jn * 16 + lr;
      float b = bias[co];
      f32x4 v = acc[i][jn];
#pragma unroll
      for (int r = 0; r < 4; ++r) {
        float u = v[r] + b;
        v[r] = (do_lrelu && u < 0.f) ? 0.2f * u : u;
      }
      *(f32x4*)&out[((size_t)n * Cout + co) * HW + p] = v;
    }
  }
}

// ---------------- direct 3x3 conv, CO per thread, optional gn1 partials -----
template <int CO, int CIC>
__global__ __launch_bounds__(256) void conv3x3_kernel(
    const float* __restrict__ in, const float* __restrict__ wgt,
    const float* __restrict__ bias, float* __restrict__ out,
    int Cin, int H, int W, int Cout, int do_lrelu, float* __restrict__ gnp) {
  __shared__ float sm[CIC][18][18];
  int tiles_x = W >> 4;
  int bt = blockIdx.x;
  int tx0 = (bt % tiles_x) << 4;
  int ty0 = (bt / tiles_x) << 4;
  int co0 = blockIdx.y * CO;
  int n = blockIdx.z;
  int tid = threadIdx.x;
  int lx = tid & 15, ly = tid >> 4;

  float acc[CO];
#pragma unroll
  for (int i = 0; i < CO; i++) acc[i] = 0.f;

  const float* inb = in + (size_t)n * Cin * H * W;

  for (int ci0 = 0; ci0 < Cin; ci0 += CIC) {
    __syncthreads();
    for (int idx = tid; idx < CIC * 324; idx += 256) {
      int ci = idx / 324;
      int r = idx - ci * 324;
      int gy = r / 18, gx = r - gy * 18;
      int iy = ty0 + gy - 1, ix = tx0 + gx - 1;
      float v = 0.f;
      if ((unsigned)iy < (unsigned)H && (unsigned)ix < (unsigned)W)
        v = inb[((size_t)(ci0 + ci)) * H * W + (size_t)iy * W + ix];
      sm[ci][gy][gx] = v;
    }
    __syncthreads();
#pragma unroll
    for (int ci = 0; ci < CIC; ci++) {
      float x00 = sm[ci][ly][lx],     x01 = sm[ci][ly][lx + 1],     x02 = sm[ci][ly][lx + 2];
      float x10 = sm[ci][ly + 1][lx], x11 = sm[ci][ly + 1][lx + 1], x12 = sm[ci][ly + 1][lx + 2];
      float x20 = sm[ci][ly + 2][lx], x21 = sm[ci][ly + 2][lx + 1], x22 = sm[ci][ly + 2][lx + 2];
      const float* wp = wgt + ((size_t)co0 * Cin + (ci0 + ci)) * 9;
#pragma unroll
      for (int co = 0; co < CO; co++) {
        const float* wc = wp + (size_t)co * Cin * 9;
        float a = acc[co];
        a = fmaf(wc[0], x00, a); a = fmaf(wc[1], x01, a); a = fmaf(wc[2], x02, a);
        a = fmaf(wc[3], x10, a); a = fmaf(wc[4], x11, a); a = fmaf(wc[5], x12, a);
        a = fmaf(wc[6], x20, a); a = fmaf(wc[7], x21, a); a = fmaf(wc[8], x22, a);
        acc[co] = a;
      }
    }
  }

  float vout[CO];
#pragma unroll
  for (int co = 0; co < CO; co++) {
    float v = acc[co] + bias[co0 + co];
    if (do_lrelu) v = v > 0.f ? v : 0.2f * v;
    vout[co] = v;
  }

  if (gnp) {
    float p0 = 0.f, q0 = 0.f, p1 = 0.f, q1 = 0.f;
#pragma unroll
    for (int co = 0; co < 8; ++co) { p0 += vout[co]; q0 += vout[co] * vout[co]; }
#pragma unroll
    for (int co = 8; co < CO; ++co) { p1 += vout[co]; q1 += vout[co] * vout[co]; }
    float* red = &sm[0][0][0];
    __syncthreads();
    red[tid] = p0; red[256 + tid] = q0; red[512 + tid] = p1; red[768 + tid] = q1;
    __syncthreads();
    for (int st = 128; st > 0; st >>= 1) {
      if (tid < st) {
        red[tid] += red[tid + st]; red[256 + tid] += red[256 + tid + st];
        red[512 + tid] += red[512 + tid + st]; red[768 + tid] += red[768 + tid + st];
      }
      __syncthreads();
    }
    if (tid == 0) {
      int S = gridDim.x;
      gnp[((n * 2 + 0) * S + blockIdx.x) * 2]     = red[0];
      gnp[((n * 2 + 0) * S + blockIdx.x) * 2 + 1] = red[256];
      gnp[((n * 2 + 1) * S + blockIdx.x) * 2]     = red[512];
      gnp[((n * 2 + 1) * S + blockIdx.x) * 2 + 1] = red[768];
    }
  }

  int oy = ty0 + ly, ox = tx0 + lx;
#pragma unroll
  for (int co = 0; co < CO; co++)
    out[(((size_t)n * Cout + co0 + co) * H + oy) * W + ox] = vout[co];
}

// ---- fused inline-GN(input) + conv3x3(lrelu) + iwt + final 1x1 ws-conv -----
template <int CO, int CIC>
__global__ __launch_bounds__(256) void conv3x3_iwt_kernel(
    const float* __restrict__ in, const float* __restrict__ wgt,
    const float* __restrict__ bias, const float* __restrict__ fw,
    const float* __restrict__ gnp, const float* __restrict__ gamma,
    const float* __restrict__ beta, int G, int Sg, int len,
    float* __restrict__ out, int Cin, int H, int W) {
  __shared__ float sm[CIC][18][18];
  __shared__ float csc[16], csh[16];
  int tiles_x = W >> 4;
  int bt = blockIdx.x;
  int tx0 = (bt % tiles_x) << 4;
  int ty0 = (bt / tiles_x) << 4;
  int n = blockIdx.z;
  int tid = threadIdx.x;
  int lx = tid & 15, ly = tid >> 4;

  if (tid < Cin) {
    int g = tid / (Cin / G);
    const float* pp = gnp + (size_t)((n * G + g) * Sg) * 2;
    float s = 0.f, s2 = 0.f;
    for (int i = 0; i < Sg; ++i) { s += pp[2 * i]; s2 += pp[2 * i + 1]; }
    float mean = s / (float)len;
    float var = s2 / (float)len - mean * mean;
    if (var < 0.f) var = 0.f;
    float inv = rsqrtf(var + 1e-5f);
    float ga = gamma[tid];
    csc[tid] = inv * ga;
    csh[tid] = beta[tid] - mean * inv * ga;
  }
  __syncthreads();

  float acc[CO];
#pragma unroll
  for (int i = 0; i < CO; i++) acc[i] = 0.f;

  const float* inb = in + (size_t)n * Cin * H * W;

  for (int ci0 = 0; ci0 < Cin; ci0 += CIC) {
    __syncthreads();
    for (int idx = tid; idx < CIC * 324; idx += 256) {
      int ci = idx / 324;
      int r = idx - ci * 324;
      int gy = r / 18, gx = r - gy * 18;
      int iy = ty0 + gy - 1, ix = tx0 + gx - 1;
      float v = 0.f;
      if ((unsigned)iy < (unsigned)H && (unsigned)ix < (unsigned)W)
        v = inb[((size_t)(ci0 + ci)) * H * W + (size_t)iy * W + ix] * csc[ci0 + ci] + csh[ci0 + ci];
      sm[ci][gy][gx] = v;
    }
    __syncthreads();
#pragma unroll
    for (int ci = 0; ci < CIC; ci++) {
      float x00 = sm[ci][ly][lx],     x01 = sm[ci][ly][lx + 1],     x02 = sm[ci][ly][lx + 2];
      float x10 = sm[ci][ly + 1][lx], x11 = sm[ci][ly + 1][lx + 1], x12 = sm[ci][ly + 1][lx + 2];
      float x20 = sm[ci][ly + 2][lx], x21 = sm[ci][ly + 2][lx + 1], x22 = sm[ci][ly + 2][lx + 2];
      const float* wp = wgt + (size_t)(ci0 + ci) * 9;
#pragma unroll
      for (int co = 0; co < CO; co++) {
        const float* wc = wp + (size_t)co * Cin * 9;
        float a = acc[co];
        a = fmaf(wc[0], x00, a); a = fmaf(wc[1], x01, a); a = fmaf(wc[2], x02, a);
        a = fmaf(wc[3], x10, a); a = fmaf(wc[4], x11, a); a = fmaf(wc[5], x12, a);
        a = fmaf(wc[6], x20, a); a = fmaf(wc[7], x21, a); a = fmaf(wc[8], x22, a);
        acc[co] = a;
      }
    }
  }

  float vout[CO];
#pragma unroll
  for (int co = 0; co < CO; co++) {
    float v = acc[co] + bias[co];
    vout[co] = v > 0.f ? v : 0.2f * v;
  }

  float y0[3], y1[3], y2[3], y3[3];
#pragma unroll
  for (int c = 0; c < 3; ++c) {
    float v0 = vout[4 * c];
    float v1 = 2.f * vout[4 * c + 1] - 1.f;
    float v2 = 2.f * vout[4 * c + 2] - 1.f;
    float v3 = 2.f * vout[4 * c + 3] - 1.f;
    y0[c] = v0 + 0.5f * ( v1 + v2 + v3);
    y1[c] = v0 + 0.5f * ( v1 - v2 - v3);
    y2[c] = v0 + 0.5f * (-v1 + v2 - v3);
    y3[c] = v0 + 0.5f * (-v1 - v2 + v3);
  }
  float w0 = fw[0], w1 = fw[1], w2 = fw[2], w3 = fw[3], w4 = fw[4], w5 = fw[5];
  int oy = ty0 + ly, ox = tx0 + lx;
  int OW = 2 * W;
  size_t ocs = (size_t)(2 * H) * OW;
  float* o0 = out + (size_t)n * 2 * ocs + (size_t)(2 * oy) * OW + 2 * ox;
  o0[0]      = w0 * y0[0] + w1 * y0[1] + w2 * y0[2];
  o0[1]      = w0 * y1[0] + w1 * y1[1] + w2 * y1[2];
  o0[OW]     = w0 * y2[0] + w1 * y2[1] + w2 * y2[2];
  o0[OW + 1] = w0 * y3[0] + w1 * y3[1] + w2 * y3[2];
  float* o1 = o0 + ocs;
  o1[0]      = w3 * y0[0] + w4 * y0[1] + w5 * y0[2];
  o1[1]      = w3 * y1[0] + w4 * y1[1] + w5 * y1[2];
  o1[OW]     = w3 * y2[0] + w4 * y2[1] + w5 * y2[2];
  o1[OW + 1] = w3 * y3[0] + w4 * y3[1] + w5 * y3[2];
}

// ---------------- group norm: stats (partials) ----------------
__global__ __launch_bounds__(256) void gn_stats_kernel(const float* __restrict__ x,
                                                       float* __restrict__ part,
                                                       int C, int HW, int G, int SPLIT) {
  __shared__ float red[512];
  int gs = blockIdx.x;
  int g = gs / SPLIT, s = gs - g * SPLIT;
  int n = blockIdx.y;
  int cpg = C / G;
  int len = cpg * HW;
  int chunk = len / SPLIT;
  size_t base = ((size_t)n * C + (size_t)g * cpg) * HW + (size_t)s * chunk;
  const f32x4* xp = (const f32x4*)(x + base);
  int chunk4 = chunk >> 2;
  float sm = 0.f, s2 = 0.f;
  for (int i = threadIdx.x; i < chunk4; i += 256) {
    f32x4 v = xp[i];
    sm += v.x + v.y + v.z + v.w;
    s2 += v.x * v.x + v.y * v.y + v.z * v.z + v.w * v.w;
  }
  red[threadIdx.x] = sm; red[256 + threadIdx.x] = s2;
  __syncthreads();
  for (int st = 128; st > 0; st >>= 1) {
    if (threadIdx.x < st) {
      red[threadIdx.x] += red[threadIdx.x + st];
      red[256 + threadIdx.x] += red[256 + threadIdx.x + st];
    }
    __syncthreads();
  }
  if (threadIdx.x == 0) {
    int o = ((n * G + g) * SPLIT + s) * 2;
    part[o] = red[0]; part[o + 1] = red[256];
  }
}

// ---------------------------------------------------------------------------

extern "C" void kernel_launch(void* const* d_in, const int* in_sizes, int n_in,
                              void* d_out, int out_size, void* d_ws, size_t ws_size,
                              hipStream_t stream) {
  const float* x        = (const float*)d_in[0];
  const float* conv1_w  = (const float*)d_in[1];
  const float* conv1_b  = (const float*)d_in[2];
  const float* conv2_w  = (const float*)d_in[3];
  const float* conv2_b  = (const float*)d_in[4];
  const float* conv3_w  = (const float*)d_in[5];
  const float* conv3_b  = (const float*)d_in[6];
  const float* conv4_w  = (const float*)d_in[7];
  const float* conv4_b  = (const float*)d_in[8];
  const float* convd1_w = (const float*)d_in[9];
  const float* convd1_b = (const float*)d_in[10];
  const float* convd2_w = (const float*)d_in[11];
  const float* convd2_b = (const float*)d_in[12];
  const float* convd3_w = (const float*)d_in[13];
  const float* convd3_b = (const float*)d_in[14];
  const float* convd4_w = (const float*)d_in[15];
  const float* convd4_b = (const float*)d_in[16];
  const float* final_w  = (const float*)d_in[17];
  const float* gn1_w = (const float*)d_in[18];
  const float* gn1_b = (const float*)d_in[19];
  const float* gn2_w = (const float*)d_in[20];
  const float* gn2_b = (const float*)d_in[21];
  const float* gn3_w = (const float*)d_in[22];
  const float* gn3_b = (const float*)d_in[23];
  const float* gn4_w = (const float*)d_in[24];
  const float* gn4_b = (const float*)d_in[25];

  char* base = (char*)d_ws;
  size_t off = 0;
  auto allocB = [&](size_t bytes) { size_t o = off; off = (off + bytes + 255) & ~(size_t)255; return o; };

  size_t o_sw1  = allocB(16 * 108 * 4);
  size_t o_swd1 = allocB(12 * 144 * 4);
  size_t o_swd2 = allocB(16 * 288 * 4);
  size_t o_swf  = allocB(6 * 4);
  size_t o_pw2  = allocB((size_t)9 * 64 * 64 * 2);
  size_t o_pw3  = allocB((size_t)9 * 256 * 256 * 2);
  size_t o_pw4  = allocB((size_t)9 * 1024 * 1024 * 2);
  size_t o_pwd3 = allocB((size_t)9 * 64 * 128 * 2);
  size_t o_pwd4 = allocB((size_t)9 * 256 * 512 * 2);
  size_t o_R1   = allocB((size_t)NB * 66 * 66 * 128 * 2);  // part | ah64 | ah128
  size_t o_R2   = allocB((size_t)NB * 34 * 34 * 512 * 2);  // ah256 | ah1k | ah512
  size_t o_gnp  = allocB(16384 * 4);                        // gn block partials
  size_t o_c1 = allocB((size_t)NB * 16 * 128 * 128 * 4);
  size_t o_c2 = allocB((size_t)NB * 64 * 64 * 64 * 4);
  size_t o_c3 = allocB((size_t)NB * 256 * 32 * 32 * 4);
  size_t o_w4 = allocB((size_t)NB * 1024 * 16 * 16 * 4);
  size_t o_t1 = allocB((size_t)NB * 1024 * 16 * 16 * 4);
  size_t o_t2 = allocB((size_t)NB * 512 * 32 * 32 * 4);

  if (off > ws_size) return;

  float* c1 = (float*)(base + o_c1);
  float* c2 = (float*)(base + o_c2);
  float* c3 = (float*)(base + o_c3);
  float* w4 = (float*)(base + o_w4);
  float* t1 = (float*)(base + o_t1);
  float* t2 = (float*)(base + o_t2);
  f16* part  = (f16*)(base + o_R1);
  f16* ah64  = (f16*)(base + o_R1);
  f16* ah128 = (f16*)(base + o_R1);
  f16* ah256 = (f16*)(base + o_R2);
  f16* ah1k  = (f16*)(base + o_R2);
  f16* ah512 = (f16*)(base + o_R2);
  f16* pw2 = (f16*)(base + o_pw2);
  f16* pw3 = (f16*)(base + o_pw3);
  f16* pw4 = (f16*)(base + o_pw4);
  f16* pwd3 = (f16*)(base + o_pwd3);
  f16* pwd4 = (f16*)(base + o_pwd4);
  float* gnp = (float*)(base + o_gnp);

  // ---- upfront ----
  {
    int n0 = NB * (2 * 66 + 2 * 64) * (64 / 8);
    int n1 = NB * (2 * 34 + 2 * 32) * (256 / 8);
    int tot = n0 + n1;
    halo2_kernel<<<(tot + 255) / 256, 256, 0, stream>>>(ah64, 64, 64, 64, n0,
                                                        ah256, 256, 32, 32, tot);
  }
  ws_all_kernel<<<46, 256, 0, stream>>>(conv1_w, (float*)(base + o_sw1),
                                        convd1_w, (float*)(base + o_swd1),
                                        convd2_w, (float*)(base + o_swd2),
                                        final_w, (float*)(base + o_swf));
  ws_f16_all_kernel<<<1664, 256, 0, stream>>>(conv2_w, pw2, conv3_w, pw3, conv4_w, pw4,
                                              convd3_w, pwd3, convd4_w, pwd4);

  auto prep_nhwc = [&](const float* in, f16* ah, int C, int H, int W, int zero) {
    if (zero) {
      int total8 = NB * (2 * (W + 2) + 2 * H) * (C / 8);
      zero_halo_kernel<<<(total8 + 255) / 256, 256, 0, stream>>>(ah, C, H, W, total8);
    }
    dim3 g((H * W) / 256, C / 32, NB);
    to_nhwc_pad_kernel<<<g, 256, 0, stream>>>(in, ah, C, H, W);
  };
  auto wt_nhwc_gn = [&](const float* in, f16* ah, float* haar32, float* wb,
                        const float* gg, const float* gb, int G, int Sg,
                        int C, int Ho, int Wo) {
    int len = (C / G) * (4 * Ho * Wo);
    dim3 g((Ho * Wo) / 256, C / 8, NB);
    wt_nhwc_gn_kernel<<<g, 256, 0, stream>>>(in, gnp, gg, gb, G, Sg, len,
                                             ah, haar32, wb, C, Ho, Wo);
  };
  auto cm6conv = [&](const f16* a, const f16* wt, int Cin, int Hs, int Ws, int Cout) {
    dim3 g((NB * Hs * Ws) / 128, Cout / 128, 2);
    conv_mfma6_kernel<<<g, 256, 0, stream>>>(a, wt, part, Cin, Hs, Ws, Cout, Hs * Ws);
  };
  auto cm6 = [&](const f16* a, const f16* wt, const float* b, float* dest, const float* add,
                 int Cin, int Hs, int Ws, int Cout, int lr, int G, int Sg) {
    cm6conv(a, wt, Cin, Hs, Ws, Cout);
    int total4 = (NB * Cout * Hs * Ws) >> 2;
    reduceS_kernel<<<(total4 + 255) / 256, 256, 0, stream>>>(
        part, b, add, dest, Cout, Hs * Ws, 2, lr, total4, G ? gnp : nullptr, G, Sg);
  };
  auto cm3 = [&](const f16* a, const f16* wt, const float* b, float* o,
                 int Cin, int Hs, int Ws, int Cout, int lr) {
    dim3 g((NB * Hs * Ws) / 128, Cout / 64);
    conv_mfma3_kernel<<<g, 256, 0, stream>>>(a, wt, b, o, Cin, Hs, Ws, Cout, Hs * Ws, lr);
  };
  auto stats = [&](const float* xb, int C, int HW, int G, int SPLIT) {
    dim3 gsd(G * SPLIT, NB);
    gn_stats_kernel<<<gsd, 256, 0, stream>>>(xb, gnp, C, HW, G, SPLIT);
  };

  // ==== encoder ====
  {
    int total = NB * 3 * 128 * 128;
    wt_kernel<<<(total + 255) / 256, 256, 0, stream>>>(x, t1, 3, 128, 128, total);  // w1
  }
  {
    dim3 g(64, 1, NB);
    conv3x3_kernel<16, 4><<<g, 256, 0, stream>>>(t1, (float*)(base + o_sw1), conv1_b,
                                                 c1, 12, 128, 128, 16, 1, gnp);
  }
  // gn1(c1) fused into wt_nhwc_gn (writeback -> c1 for skip use); w2 -> ah64
  wt_nhwc_gn(c1, ah64, nullptr, c1, gn1_w, gn1_b, 2, 64, 16, 64, 64);

  cm3(ah64, pw2, conv2_b, c2, 64, 64, 64, 64, 1);                   // c2
  stats(c2, 64, 4096, 8, 16);
  // gn2(c2) fused; w3 -> ah256
  wt_nhwc_gn(c2, ah256, nullptr, c2, gn2_w, gn2_b, 8, 16, 64, 32, 32);

  cm6(ah256, pw3, conv3_b, c3, nullptr, 256, 32, 32, 256, 1, 32, 8);  // c3 (+partials)
  {
    int total8 = NB * (2 * 18 + 2 * 16) * (1024 / 8);
    zero_halo_kernel<<<(total8 + 255) / 256, 256, 0, stream>>>(ah1k, 1024, 16, 16, total8);
  }
  // gn3(c3) fused; w4 -> ah1k + fp32 Haar copy (residual) + writeback -> c3
  wt_nhwc_gn(c3, ah1k, w4, c3, gn3_w, gn3_b, 32, 8, 256, 16, 16);

  cm6(ah1k, pw4, conv4_b, t1, nullptr, 1024, 16, 16, 1024, 1, 128, 2);  // c4 -> t1
  {
    dim3 g(1, 32, NB);
    gn_nhwc_kernel<<<g, 256, 0, stream>>>(t1, gnp, gn4_w, gn4_b, ah1k, 1024, 16, 16,
                                          128, 2, 2048);
  }
  cm6(ah1k, pw4, conv4_b, t2, nullptr, 1024, 16, 16, 1024, 1, 128, 2);  // c5 -> t2
  {
    dim3 g(1, 32, NB);
    gn_nhwc_kernel<<<g, 256, 0, stream>>>(t2, gnp, gn4_w, gn4_b, ah1k, 1024, 16, 16,
                                          128, 2, 2048);
  }
  // c6 partials only; split-K sum + bias + w4-add + lrelu folded into iw4 concat
  cm6conv(ah1k, pw4, 1024, 16, 16, 1024);

  // ==== decoder ====
  // iw4 = concat(c3, iwt(lrelu(part0+part1+bias+w4))) -> t2 (NCHW fp32)
  {
    int totalA = NB * 256 * 4 * 16 * 16;        // skip: NB*C*(2Hh*2Wh)
    int total = totalA + NB * 256 * 16 * 16;    // + v threads
    concat_iwt_kernel<<<(total + 255) / 256, 256, 0, stream>>>(
        c3, nullptr, part, conv4_b, w4, t2,
        nullptr, nullptr, nullptr, 0, 0, 0, 256, 16, 16, totalA, total);
  }
  prep_nhwc(t2, ah512, 512, 32, 32, 1);
  cm6(ah512, pwd4, convd4_b, t1, nullptr, 512, 32, 32, 256, 1, 32, 8);  // ic3 (+partials)
  // iw3 -> t2 (gn3 inline)
  {
    int totalA = NB * 64 * 4 * 32 * 32;
    int total = totalA + NB * 64 * 32 * 32;
    int len = (256 / 32) * 32 * 32;
    concat_iwt_kernel<<<(total + 255) / 256, 256, 0, stream>>>(
        c2, t1, nullptr, nullptr, nullptr, t2,
        gnp, gn3_w, gn3_b, 32, 8, len, 64, 32, 32, totalA, total);
  }
  prep_nhwc(t2, ah128, 128, 64, 64, 1);
  cm3(ah128, pwd3, convd3_b, t1, 128, 64, 64, 64, 1);               // ic2 -> t1
  stats(t1, 64, 4096, 8, 16);
  // iw2 -> t2 (gn2 inline)
  {
    int totalA = NB * 16 * 4 * 64 * 64;
    int total = totalA + NB * 16 * 64 * 64;
    int len = (64 / 8) * 64 * 64;
    concat_iwt_kernel<<<(total + 255) / 256, 256, 0, stream>>>(
        c1, t1, nullptr, nullptr, nullptr, t2,
        gnp, gn2_w, gn2_b, 8, 16, len, 16, 64, 64, totalA, total);
  }
  {
    dim3 g(64, 1, NB);
    conv3x3_kernel<16, 4><<<g, 256, 0, stream>>>(t2, (float*)(base + o_swd2), convd2_b,
                                                 t1, 32, 128, 128, 16, 1, gnp);
  }
  // gn1(ic1) fused into conv3x3_iwt's input read; final conv + iwt + 1x1
  {
    dim3 g(64, 1, NB);
    conv3x3_iwt_kernel<12, 4><<<g, 256, 0, stream>>>(
        t1, (float*)(base + o_swd1), convd1_b, (float*)(base + o_swf),
        gnp, gn1_w, gn1_b, 2, 64, 8 * 128 * 128, (float*)d_out, 16, 128, 128);
  }
}

// Round 11
// 877.496 us; speedup vs baseline: 1.0950x; 1.0167x over previous
//
#include <hip/hip_runtime.h>
#include <math.h>

// ---------------------------------------------------------------------------
// WaveletNet forward. conv_mfma6: 128x128x64 double-buffered (1 barrier/iter),
// split-K=2, 256 threads, 2 blocks/CU (cross-block overlap is the latency
// hiding mechanism - R4/R5/R7 ablations). GN-apply fused into consumers
// (wt_nhwc_gn / conv3x3_iwt). GN-stats fused into producer epilogues
// (reduceS for cm6 sites, conv_mfma3 epilogue via shfl butterfly, conv3x3).
// ic4 split-K reduce folded into the iw4 concat. NCHW concat keeps coalesced
// pattern (R9 lesson: NHWC-direct concat gather loses more than it saves).
// N=16 fixed.
// ---------------------------------------------------------------------------

#define NB 16  // batch

typedef _Float16 f16;
typedef _Float16 f16x8 __attribute__((ext_vector_type(8)));
typedef _Float16 f16x4 __attribute__((ext_vector_type(4)));
typedef float f32x4 __attribute__((ext_vector_type(4)));
typedef float f32x2 __attribute__((ext_vector_type(2)));
typedef unsigned int u32;

#define LLDS16(gp, lp)                                                          \
  __builtin_amdgcn_global_load_lds((const __attribute__((address_space(1))) u32*)(const void*)(gp), \
                                   (__attribute__((address_space(3))) u32*)(void*)(lp), 16, 0, 0)

// ---------------- weight standardization ----------------
__device__ __forceinline__ void ws_reduce(const float* wp, int fan, float* red,
                                          float& mean, float& inv) {
  float s = 0.f, s2 = 0.f;
  for (int i = threadIdx.x; i < fan; i += 256) { float v = wp[i]; s += v; s2 += v * v; }
  red[threadIdx.x] = s; red[256 + threadIdx.x] = s2;
  __syncthreads();
  for (int st = 128; st > 0; st >>= 1) {
    if (threadIdx.x < st) {
      red[threadIdx.x] += red[threadIdx.x + st];
      red[256 + threadIdx.x] += red[256 + threadIdx.x + st];
    }
    __syncthreads();
  }
  float sum = red[0], sumsq = red[256];
  mean = sum / (float)fan;
  float var = (sumsq - sum * mean) / (float)(fan - 1);
  if (var < 0.f) var = 0.f;
  inv = 1.0f / (sqrtf(var) + 1e-5f);
}

__global__ void ws_all_kernel(const float* w0, float* o0, const float* w1, float* o1,
                              const float* w2, float* o2, const float* w3, float* o3) {
  __shared__ float red[512];
  int b = blockIdx.x;
  const float* w; float* o; int fan, oi;
  if (b < 16)      { w = w0; o = o0; fan = 108; oi = b; }
  else if (b < 28) { w = w1; o = o1; fan = 144; oi = b - 16; }
  else if (b < 44) { w = w2; o = o2; fan = 288; oi = b - 28; }
  else             { w = w3; o = o3; fan = 3;   oi = b - 44; }
  const float* wp = w + (size_t)oi * fan;
  float mean, inv; ws_reduce(wp, fan, red, mean, inv);
  for (int i = threadIdx.x; i < fan; i += 256)
    o[(size_t)oi * fan + i] = (wp[i] - mean) * inv;
}

__global__ void ws_f16_all_kernel(const float* w0, f16* o0, const float* w1, f16* o1,
                                  const float* w2, f16* o2, const float* w3, f16* o3,
                                  const float* w4, f16* o4) {
  __shared__ float red[512];
  int b = blockIdx.x;
  const float* w; f16* o; int fan, Cin, Cout, oi;
  if (b < 64)        { w = w0; o = o0; fan = 576;  Cin = 64;   Cout = 64;   oi = b; }
  else if (b < 320)  { w = w1; o = o1; fan = 2304; Cin = 256;  Cout = 256;  oi = b - 64; }
  else if (b < 1344) { w = w2; o = o2; fan = 9216; Cin = 1024; Cout = 1024; oi = b - 320; }
  else if (b < 1408) { w = w3; o = o3; fan = 1152; Cin = 128;  Cout = 64;   oi = b - 1344; }
  else               { w = w4; o = o4; fan = 4608; Cin = 512;  Cout = 256;  oi = b - 1408; }
  const float* wp = w + (size_t)oi * fan;
  float mean, inv; ws_reduce(wp, fan, red, mean, inv);
  for (int i = threadIdx.x; i < fan; i += 256) {
    int ci = i / 9, tap = i - ci * 9;
    o[((size_t)tap * Cout + oi) * Cin + ci] = (f16)((wp[i] - mean) * inv);
  }
}

// ---------------- halo zero ----------------
__device__ __forceinline__ void halo_write(f16* buf, int C, int H, int W, int t) {
  int c8s = C >> 3;
  int c8 = t % c8s; int q = t / c8s;
  int P = 2 * (W + 2) + 2 * H;
  int b = q % P; int n = q / P;
  int y, x;
  if (b < W + 2) { y = 0; x = b; }
  else if (b < 2 * (W + 2)) { y = H + 1; x = b - (W + 2); }
  else { int bb = b - 2 * (W + 2); y = 1 + (bb >> 1); x = (bb & 1) ? (W + 1) : 0; }
  size_t a = (((size_t)n * (H + 2) + y) * (W + 2) + x) * C + c8 * 8;
  *(f16x8*)(buf + a) = (f16x8){0, 0, 0, 0, 0, 0, 0, 0};
}

__global__ void halo2_kernel(f16* b0, int c0, int h0, int w0, int n0,
                             f16* b1, int c1, int h1, int w1, int total) {
  int idx = blockIdx.x * 256 + threadIdx.x;
  if (idx >= total) return;
  if (idx < n0) halo_write(b0, c0, h0, w0, idx);
  else halo_write(b1, c1, h1, w1, idx - n0);
}

__global__ void zero_halo_kernel(f16* __restrict__ buf, int C, int H, int W, int total8) {
  int idx = blockIdx.x * 256 + threadIdx.x;
  if (idx >= total8) return;
  halo_write(buf, C, H, W, idx);
}

// ---------------- Haar forward (NCHW fp32) ----------------
__global__ void wt_kernel(const float* __restrict__ in, float* __restrict__ out,
                          int C, int Ho, int Wo, int total) {
  int idx = blockIdx.x * 256 + threadIdx.x;
  if (idx >= total) return;
  int w = idx % Wo; int t = idx / Wo;
  int h = t % Ho; t /= Ho;
  int c = t % C; int n = t / C;
  int Wi = 2 * Wo;
  const float* ip = in + (((size_t)n * C + c) * (2 * Ho) + 2 * h) * Wi + 2 * w;
  float a = ip[0], b = ip[1], cc = ip[Wi], d = ip[Wi + 1];
  size_t cs = (size_t)Ho * Wo;
  float* op = out + (((size_t)n * 4 * C + 4 * c) * Ho + h) * Wo + w;
  op[0]      = 0.25f * (a + b + cc + d);
  op[cs]     = 0.25f * (a + b - cc - d) + 0.5f;
  op[2 * cs] = 0.25f * (a - b + cc - d) + 0.5f;
  op[3 * cs] = 0.25f * (a - b - cc + d) + 0.5f;
}

// ---------------- fused GN-apply + Haar + NCHW->padded NHWC f16 -------------
__global__ __launch_bounds__(256) void wt_nhwc_gn_kernel(
    const float* __restrict__ in, const float* __restrict__ gnp,
    const float* __restrict__ gamma, const float* __restrict__ beta,
    int G, int Sg, int len,
    f16* __restrict__ out, float* __restrict__ out32, float* __restrict__ gnwb,
    int C, int Ho, int Wo) {
  __shared__ f16 sm[32][264];
  __shared__ float scs[8], shs[8];
  int HWo = Ho * Wo;
  int p0 = blockIdx.x * 256, c0 = blockIdx.y * 8, n = blockIdx.z;
  int t = threadIdx.x;
  if (t < 8) {
    int c = c0 + t;
    int g = c / (C / G);
    const float* pp = gnp + (size_t)((n * G + g) * Sg) * 2;
    float s = 0.f, s2 = 0.f;
    for (int i = 0; i < Sg; ++i) { s += pp[2 * i]; s2 += pp[2 * i + 1]; }
    float mean = s / (float)len;
    float var = s2 / (float)len - mean * mean;
    if (var < 0.f) var = 0.f;
    float inv = rsqrtf(var + 1e-5f);
    float ga = gamma[c];
    scs[t] = inv * ga;
    shs[t] = beta[c] - mean * inv * ga;
  }
  __syncthreads();
  int p = p0 + t; int h = p / Wo; int ww = p - h * Wo;
  int Wi = 2 * Wo;
  int C4 = 4 * C;
#pragma unroll
  for (int r = 0; r < 8; ++r) {
    size_t ioff = (((size_t)n * C + c0 + r) * (2 * Ho) + 2 * h) * Wi + 2 * ww;
    const float* ip = in + ioff;
    f32x2 u0 = *(const f32x2*)ip;
    f32x2 u1 = *(const f32x2*)(ip + Wi);
    float sc = scs[r], sh = shs[r];
    float a = u0.x * sc + sh, b = u0.y * sc + sh;
    float cc = u1.x * sc + sh, d = u1.y * sc + sh;
    if (gnwb) {
      float* wp = gnwb + ioff;
      *(f32x2*)wp = (f32x2){a, b};
      *(f32x2*)(wp + Wi) = (f32x2){cc, d};
    }
    float v0 = 0.25f * (a + b + cc + d);
    float v1 = 0.25f * (a + b - cc - d) + 0.5f;
    float v2 = 0.25f * (a - b + cc - d) + 0.5f;
    float v3 = 0.25f * (a - b - cc + d) + 0.5f;
    sm[4 * r][t]     = (f16)v0;
    sm[4 * r + 1][t] = (f16)v1;
    sm[4 * r + 2][t] = (f16)v2;
    sm[4 * r + 3][t] = (f16)v3;
    if (out32) {
      float* op = out32 + (((size_t)n * C4 + 4 * (c0 + r)) * Ho + h) * Wo + ww;
      size_t cs = (size_t)HWo;
      op[0] = v0; op[cs] = v1; op[2 * cs] = v2; op[3 * cs] = v3;
    }
  }
  __syncthreads();
#pragma unroll
  for (int i = 0; i < 4; ++i) {
    int c = t + i * 256;
    int pl = c >> 2, cio = (c & 3) * 8;
    f16x8 v;
#pragma unroll
    for (int u = 0; u < 8; ++u) v[u] = sm[cio + u][pl];
    int pp = p0 + pl; int y = pp / Wo; int x = pp - y * Wo;
    *(f16x8*)(out + (((size_t)n * (Ho + 2) + y + 1) * (Wo + 2) + x + 1) * C4 + c0 * 4 + cio) = v;
  }
}

// ---------------- fused concat + iwt (+optional inline GN / part-reduce) ----
__global__ void concat_iwt_kernel(const float* __restrict__ skip, const float* __restrict__ v,
                                  const f16* __restrict__ part, const float* __restrict__ bias,
                                  const float* __restrict__ add,
                                  float* __restrict__ out, const float* __restrict__ gnp,
                                  const float* __restrict__ gamma, const float* __restrict__ beta,
                                  int G, int Sg, int len, int C, int Hh, int Wh,
                                  int totalA, int total) {
  int idx = blockIdx.x * 256 + threadIdx.x;
  if (idx >= total) return;
  int W = 2 * Wh, H = 2 * Hh; int HWs = H * W;
  if (idx < totalA) {
    int p = idx % HWs; int t = idx / HWs; int c = t % C; int n = t / C;
    out[((size_t)n * 2 * C + c) * HWs + p] = skip[idx];
    return;
  }
  int i2 = idx - totalA;
  int w = i2 % Wh; int t = i2 / Wh; int h = t % Hh; t /= Hh;
  int c = t % C; int n = t / C;
  size_t cs = (size_t)Hh * Wh;
  float v0, v1, v2, v3;
  if (part) {
    size_t base_off = (((size_t)n * 4 * C + 4 * c) * Hh + h) * Wh + w;
    size_t sstr = (size_t)NB * 4 * C * cs;
    float vv[4];
#pragma unroll
    for (int k = 0; k < 4; ++k) {
      size_t off = base_off + (size_t)k * cs;
      float val = (float)part[off] + (float)part[sstr + off] + bias[4 * c + k];
      if (add) val += add[off];
      vv[k] = val > 0.f ? val : 0.2f * val;
    }
    v0 = vv[0]; v1 = vv[1]; v2 = vv[2]; v3 = vv[3];
  } else {
    const float* vp = v + (((size_t)n * 4 * C + 4 * c) * Hh + h) * Wh + w;
    v0 = vp[0]; v1 = vp[cs]; v2 = vp[2 * cs]; v3 = vp[3 * cs];
  }
  if (gnp) {
    int cpg = (4 * C) / G;
    int g = (4 * c) / cpg;
    const float* pp = gnp + (size_t)((n * G + g) * Sg) * 2;
    float s = 0.f, s2 = 0.f;
    for (int i = 0; i < Sg; ++i) { s += pp[2 * i]; s2 += pp[2 * i + 1]; }
    float mean = s / (float)len;
    float var = s2 / (float)len - mean * mean;
    if (var < 0.f) var = 0.f;
    float inv = rsqrtf(var + 1e-5f);
    v0 = (v0 - mean) * inv * gamma[4 * c]     + beta[4 * c];
    v1 = (v1 - mean) * inv * gamma[4 * c + 1] + beta[4 * c + 1];
    v2 = (v2 - mean) * inv * gamma[4 * c + 2] + beta[4 * c + 2];
    v3 = (v3 - mean) * inv * gamma[4 * c + 3] + beta[4 * c + 3];
  }
  v1 = 2.f * v1 - 1.f; v2 = 2.f * v2 - 1.f; v3 = 2.f * v3 - 1.f;
  float* op = out + (((size_t)n * 2 * C + C + c) * H + 2 * h) * (size_t)W + 2 * w;
  op[0]     = v0 + 0.5f * ( v1 + v2 + v3);
  op[1]     = v0 + 0.5f * ( v1 - v2 - v3);
  op[W]     = v0 + 0.5f * (-v1 + v2 - v3);
  op[W + 1] = v0 + 0.5f * (-v1 - v2 + v3);
}

// ---------------- NCHW fp32 -> padded NHWC f16 (LDS transpose) --------------
__global__ __launch_bounds__(256) void to_nhwc_pad_kernel(const float* __restrict__ in,
                                                          f16* __restrict__ out,
                                                          int C, int H, int W) {
  __shared__ f16 sm[32][264];
  int HW = H * W;
  int p0 = blockIdx.x * 256, c0 = blockIdx.y * 32, n = blockIdx.z;
  int t = threadIdx.x;
  const float* ip = in + ((size_t)n * C + c0) * HW + p0;
#pragma unroll 8
  for (int r = 0; r < 32; ++r) sm[r][t] = (f16)ip[(size_t)r * HW + t];
  __syncthreads();
#pragma unroll
  for (int i = 0; i < 4; ++i) {
    int c = t + i * 256;
    int pl = c >> 2, cio = (c & 3) * 8;
    f16x8 v;
#pragma unroll
    for (int u = 0; u < 8; ++u) v[u] = sm[cio + u][pl];
    int p = p0 + pl; int y = p / W; int x = p - y * W;
    *(f16x8*)(out + (((size_t)n * (H + 2) + y + 1) * (W + 2) + x + 1) * C + c0 + cio) = v;
  }
}

// ---------------- GN-apply (partial-based) + NCHW->padded NHWC f16 ----------
__global__ __launch_bounds__(256) void gn_nhwc_kernel(
    const float* __restrict__ in, const float* __restrict__ gnp,
    const float* __restrict__ gamma, const float* __restrict__ beta,
    f16* __restrict__ out, int C, int H, int W, int G, int Sg, int len) {
  __shared__ f16 sm[32][264];
  int HW = H * W;
  int p0 = blockIdx.x * 256, c0 = blockIdx.y * 32, n = blockIdx.z;
  int t = threadIdx.x;
  int cpg = C / G;
  const float* ip = in + ((size_t)n * C + c0) * HW + p0;
#pragma unroll 8
  for (int r = 0; r < 32; ++r) {
    int c = c0 + r; int g = c / cpg;
    const float* pp = gnp + (size_t)((n * G + g) * Sg) * 2;
    float s = 0.f, s2 = 0.f;
    for (int i = 0; i < Sg; ++i) { s += pp[2 * i]; s2 += pp[2 * i + 1]; }
    float mean = s / (float)len;
    float var = s2 / (float)len - mean * mean;
    if (var < 0.f) var = 0.f;
    float inv = rsqrtf(var + 1e-5f);
    float ga = gamma[c], be = beta[c];
    sm[r][t] = (f16)((ip[(size_t)r * HW + t] - mean) * inv * ga + be);
  }
  __syncthreads();
#pragma unroll
  for (int i = 0; i < 4; ++i) {
    int c = t + i * 256;
    int pl = c >> 2, cio = (c & 3) * 8;
    f16x8 v;
#pragma unroll
    for (int u = 0; u < 8; ++u) v[u] = sm[cio + u][pl];
    int p = p0 + pl; int y = p / W; int x = p - y * W;
    *(f16x8*)(out + (((size_t)n * (H + 2) + y + 1) * (W + 2) + x + 1) * C + c0 + cio) = v;
  }
}

// ---------------- conv_mfma6: 128x128x64, dbuf, 1 barrier/iter, split-K -----
__global__ __launch_bounds__(256) void conv_mfma6_kernel(
    const f16* __restrict__ A, const f16* __restrict__ Wp,
    f16* __restrict__ part, int Cin, int H, int W, int Cout, int HW) {
  constexpr int CH = 128 * 64;  // f16 per buffer
  __shared__ f16 Asm[2 * CH];   // 32 KB
  __shared__ f16 Bsm[2 * CH];   // 32 KB

  const int tid = threadIdx.x;
  const int w = tid >> 6, lane = tid & 63;
  const int m0 = blockIdx.x * 128;
  const int co0 = blockIdx.y * 128;
  const int Wp2 = W + 2;

  const f16* gA[4]; const f16* gB[4];
  int lOff[4];
#pragma unroll
  for (int e = 0; e < 4; ++e) {
    int c = e * 256 + tid;
    int r = c >> 3, j = c & 7;
    int jx = j ^ (r & 7);
    int m = m0 + r; int n = m / HW; int p = m - n * HW;
    int y = p / W; int x = p - y * W;
    gA[e] = A + (((size_t)n * (H + 2) + y + 1) * Wp2 + (x + 1)) * Cin + jx * 8;
    gB[e] = Wp + (size_t)(co0 + r) * Cin + jx * 8;
    lOff[e] = (e * 256 + w * 64) * 8;  // wave-uniform
  }

  const int wm = w & 1, wn = w >> 1;
  const int lr = lane & 15, quad = lane >> 4;
  int aoffs[4][2], boffs[4][2];
#pragma unroll
  for (int i = 0; i < 4; ++i)
#pragma unroll
    for (int kk = 0; kk < 2; ++kk) {
      int r = wm * 64 + i * 16 + lr;
      int cidx = kk * 4 + quad;
      aoffs[i][kk] = (r * 8 + (cidx ^ (r & 7))) * 8;
      int rb = wn * 64 + i * 16 + lr;
      boffs[i][kk] = (rb * 8 + (cidx ^ (rb & 7))) * 8;
    }

  f32x4 acc[4][4];
#pragma unroll
  for (int i = 0; i < 4; ++i)
#pragma unroll
    for (int j = 0; j < 4; ++j) acc[i][j] = (f32x4){0.f, 0.f, 0.f, 0.f};

  const int kpt = Cin >> 6;
  const int nit = (9 * kpt) / gridDim.z;
  const int it0 = blockIdx.z * nit;
  const size_t bstride = (size_t)Cout * Cin;

  auto stageAB = [&](int it, int sel) {
    int tap = it / kpt, kk = it - tap * kpt;
    int dy = tap / 3 - 1, dx = tap % 3 - 1;
    long offA = ((long)dy * Wp2 + dx) * Cin + (kk << 6);
    long offB = (long)tap * bstride + (kk << 6);
    f16* ab = Asm + sel * CH;
    f16* bb = Bsm + sel * CH;
#pragma unroll
    for (int e = 0; e < 4; ++e) {
      LLDS16(gA[e] + offA, ab + lOff[e]);
      LLDS16(gB[e] + offB, bb + lOff[e]);
    }
  };

  stageAB(it0, 0);
  int sel = 0;
  for (int ii = 0; ii < nit; ++ii) {
    __syncthreads();  // drains prefetch (vmcnt) + prior reads (lgkm)
    if (ii + 1 < nit) stageAB(it0 + ii + 1, sel ^ 1);  // overlaps compute below
    const f16* ab = Asm + sel * CH;
    const f16* bb = Bsm + sel * CH;
    f16x8 af[4][2], bf[4][2];
#pragma unroll
    for (int i = 0; i < 4; ++i)
#pragma unroll
      for (int kk = 0; kk < 2; ++kk) {
        af[i][kk] = *(const f16x8*)&ab[aoffs[i][kk]];
        bf[i][kk] = *(const f16x8*)&bb[boffs[i][kk]];
      }
#pragma unroll
    for (int kk = 0; kk < 2; ++kk)
#pragma unroll
      for (int i = 0; i < 4; ++i)
#pragma unroll
        for (int j = 0; j < 4; ++j)
          acc[i][j] = __builtin_amdgcn_mfma_f32_16x16x32_f16(af[i][kk], bf[j][kk], acc[i][j], 0, 0, 0);
    sel ^= 1;
  }

  const size_t pbase = (size_t)blockIdx.z * NB * Cout * HW;
#pragma unroll
  for (int i = 0; i < 4; ++i) {
    int mg = m0 + wm * 64 + i * 16 + quad * 4;
    int n = mg / HW, p = mg - n * HW;
#pragma unroll
    for (int j = 0; j < 4; ++j) {
      int co = co0 + wn * 64 + j * 16 + lr;
      f32x4 v = acc[i][j];
      f16x4 h;
#pragma unroll
      for (int r = 0; r < 4; ++r) h[r] = (f16)v[r];
      *(f16x4*)&part[pbase + ((size_t)n * Cout + co) * HW + p] = h;
    }
  }
}

// ---------------- reduce S partials + bias (+add)(+lrelu) + GN partials -----
__global__ __launch_bounds__(256) void reduceS_kernel(
    const f16* __restrict__ part, const float* __restrict__ bias,
    const float* __restrict__ add, float* __restrict__ out,
    int Cout, int HW, int S, int do_lrelu, int total4,
    float* __restrict__ gnp, int G, int Sg) {
  __shared__ float red[512];
  int idx = blockIdx.x * 256 + threadIdx.x;
  if (idx >= total4) return;
  size_t sstride = (size_t)NB * Cout * HW;
  int hw4 = HW >> 2;
  int p4 = idx % hw4; int t = idx / hw4;
  int c = t % Cout;
  size_t eoff = (size_t)t * HW + p4 * 4;
  float b = bias[c];
  f32x4 o = {b, b, b, b};
  for (int s = 0; s < S; ++s) {
    f16x4 a = *(const f16x4*)(part + s * sstride + eoff);
#pragma unroll
    for (int r = 0; r < 4; ++r) o[r] += (float)a[r];
  }
  if (add) {
    f32x4 av = *(const f32x4*)(add + eoff);
#pragma unroll
    for (int r = 0; r < 4; ++r) o[r] += av[r];
  }
  if (do_lrelu)
#pragma unroll
    for (int r = 0; r < 4; ++r) o[r] = o[r] > 0.f ? o[r] : 0.2f * o[r];
  *(f32x4*)(out + eoff) = o;
  if (gnp) {
    float ls = o[0] + o[1] + o[2] + o[3];
    float ls2 = o[0]*o[0] + o[1]*o[1] + o[2]*o[2] + o[3]*o[3];
    red[threadIdx.x] = ls; red[256 + threadIdx.x] = ls2;
    __syncthreads();
    for (int st = 128; st > 0; st >>= 1) {
      if (threadIdx.x < st) {
        red[threadIdx.x] += red[threadIdx.x + st];
        red[256 + threadIdx.x] += red[256 + threadIdx.x + st];
      }
      __syncthreads();
    }
    if (threadIdx.x == 0) {
      int flat0 = blockIdx.x * 1024;
      int chw = Cout * HW;
      int n = flat0 / chw;
      int rem = flat0 - n * chw;
      int L = (Cout / G) * HW;
      int g = rem / L;
      int s = (rem - g * L) >> 10;
      gnp[((n * G + g) * Sg + s) * 2] = red[0];
      gnp[((n * G + g) * Sg + s) * 2 + 1] = red[256];
    }
  }
}

// ---------------- conv_mfma3: 128x64x64, dbuf, fused GN-partial epilogue ----
// Cout==64, grid.y==1. Writes post-lrelu GN partials for 8 groups of 8 ch,
// one slice per 128-pixel M-block (Sg = HW/128). Butterfly over lane bits
// {0,1,2,4,5}; bit 3 separates the two 8-ch groups within 16 lanes (lr).
__global__ __launch_bounds__(256) void conv_mfma3_kernel(
    const f16* __restrict__ A, const f16* __restrict__ Wp,
    const float* __restrict__ bias, float* __restrict__ out,
    int Cin, int H, int W, int Cout, int HW, int do_lrelu,
    float* __restrict__ gnp) {
  constexpr int CHA = 128 * 64;  // f16 per A buffer
  constexpr int CHB = 64 * 64;   // f16 per B buffer
  __shared__ f16 Asm[2 * CHA];   // 32 KB
  __shared__ f16 Bsm[2 * CHB];   // 16 KB
  __shared__ float redg[32];     // 8 groups x 2 wm x {s,s2}

  const int tid = threadIdx.x;
  const int w = tid >> 6, lane = tid & 63;
  const int m0 = blockIdx.x * 128;
  const int co0 = blockIdx.y * 64;
  const int Wp2 = W + 2;

  const f16* gA[4];
  int lAoff[4];
#pragma unroll
  for (int e = 0; e < 4; ++e) {
    int c = e * 256 + tid;
    int r = c >> 3, j = c & 7;
    int jx = j ^ (r & 7);
    int m = m0 + r; int n = m / HW; int p = m - n * HW;
    int y = p / W; int x = p - y * W;
    gA[e] = A + (((size_t)n * (H + 2) + y + 1) * Wp2 + (x + 1)) * Cin + jx * 8;
    lAoff[e] = (e * 256 + w * 64) * 8;
  }
  const f16* gB[2];
  int lBoff[2];
#pragma unroll
  for (int e = 0; e < 2; ++e) {
    int c = e * 256 + tid;
    int r = c >> 3, j = c & 7;
    int jx = j ^ (r & 7);
    gB[e] = Wp + (size_t)(co0 + r) * Cin + jx * 8;
    lBoff[e] = (e * 256 + w * 64) * 8;
  }

  const int wm = w & 1, wn = w >> 1;
  const int lr = lane & 15, quad = lane >> 4;
  int aoffs[4][2], boffs[2][2];
#pragma unroll
  for (int i = 0; i < 4; ++i)
#pragma unroll
    for (int kk = 0; kk < 2; ++kk) {
      int r = wm * 64 + i * 16 + lr;
      int cidx = kk * 4 + quad;
      aoffs[i][kk] = (r * 8 + (cidx ^ (r & 7))) * 8;
    }
#pragma unroll
  for (int jn = 0; jn < 2; ++jn)
#pragma unroll
    for (int kk = 0; kk < 2; ++kk) {
      int rb = wn * 32 + jn * 16 + lr;
      int cidx = kk * 4 + quad;
      boffs[jn][kk] = (rb * 8 + (cidx ^ (rb & 7))) * 8;
    }

  f32x4 acc[4][2];
#pragma unroll
  for (int i = 0; i < 4; ++i)
#pragma unroll
    for (int jn = 0; jn < 2; ++jn) acc[i][jn] = (f32x4){0.f, 0.f, 0.f, 0.f};

  const int kpt = Cin >> 6;
  const int nit = 9 * kpt;
  const size_t bstride = (size_t)Cout * Cin;

  auto stageAB = [&](int it, int sel) {
    int tap = it / kpt, kk = it - tap * kpt;
    int dy = tap / 3 - 1, dx = tap % 3 - 1;
    long offA = ((long)dy * Wp2 + dx) * Cin + (kk << 6);
    long offB = (long)tap * bstride + (kk << 6);
    f16* ab = Asm + sel * CHA;
    f16* bb = Bsm + sel * CHB;
#pragma unroll
    for (int e = 0; e < 4; ++e) LLDS16(gA[e] + offA, ab + lAoff[e]);
#pragma unroll
    for (int e = 0; e < 2; ++e) LLDS16(gB[e] + offB, bb + lBoff[e]);
  };

  stageAB(0, 0);
  int sel = 0;
  for (int ii = 0; ii < nit; ++ii) {
    __syncthreads();
    if (ii + 1 < nit) stageAB(ii + 1, sel ^ 1);
    const f16* ab = Asm + sel * CHA;
    const f16* bb = Bsm + sel * CHB;
    f16x8 af[4][2], bf[2][2];
#pragma unroll
    for (int i = 0; i < 4; ++i)
#pragma unroll
      for (int kk = 0; kk < 2; ++kk) af[i][kk] = *(const f16x8*)&ab[aoffs[i][kk]];
#pragma unroll
    for (int jn = 0; jn < 2; ++jn)
#pragma unroll
      for (int kk = 0; kk < 2; ++kk) bf[jn][kk] = *(const f16x8*)&bb[boffs[jn][kk]];
#pragma unroll
    for (int kk = 0; kk < 2; ++kk)
#pragma unroll
      for (int i = 0; i < 4; ++i)
#pragma unroll
        for (int jn = 0; jn < 2; ++jn)
          acc[i][jn] = __builtin_amdgcn_mfma_f32_16x16x32_f16(af[i][kk], bf[jn][kk], acc[i][jn], 0, 0, 0);
    sel ^= 1;
  }

  float lsj[2] = {0.f, 0.f}, ls2j[2] = {0.f, 0.f};
#pragma unroll
  for (int i = 0; i < 4; ++i) {
    int mg = m0 + wm * 64 + i * 16 + quad * 4;
    int n = mg / HW, p = mg - n * HW;
#pragma unroll
    for (int jn = 0; jn < 2; ++jn) {
      int co = co0 + wn * 32 + jn * 16 + lr;
      float b = bias[co];
      f32x4 v = acc[i][jn];
#pragma unroll
      for (int r = 0; r < 4; ++r) {
        float u = v[r] + b;
        u = (do_lrelu && u < 0.f) ? 0.2f * u : u;
        v[r] = u;
        lsj[jn] += u; ls2j[jn] += u * u;
      }
      *(f32x4*)&out[((size_t)n * Cout + co) * HW + p] = v;
    }
  }

  if (gnp) {
    __syncthreads();  // main-loop LDS traffic retired before redg reuse phase
#pragma unroll
    for (int jn = 0; jn < 2; ++jn) {
      float s = lsj[jn], s2 = ls2j[jn];
      s += __shfl_xor(s, 1);  s2 += __shfl_xor(s2, 1);
      s += __shfl_xor(s, 2);  s2 += __shfl_xor(s2, 2);
      s += __shfl_xor(s, 4);  s2 += __shfl_xor(s2, 4);
      s += __shfl_xor(s, 16); s2 += __shfl_xor(s2, 16);
      s += __shfl_xor(s, 32); s2 += __shfl_xor(s2, 32);
      if ((lane & 55) == 0) {  // lanes 0 (hi=0) and 8 (hi=1)
        int hi = (lane >> 3) & 1;
        int g = wn * 4 + jn * 2 + hi;   // local 8-ch group in [0,8)
        redg[(g * 2 + wm) * 2]     = s;
        redg[(g * 2 + wm) * 2 + 1] = s2;
      }
    }
    __syncthreads();
    if (tid < 8) {
      float s  = redg[(tid * 2) * 2]     + redg[(tid * 2 + 1) * 2];
      float s2 = redg[(tid * 2) * 2 + 1] + redg[(tid * 2 + 1) * 2 + 1];
      int n = m0 / HW;
      int sIdx = (m0 - n * HW) >> 7;   // 128-pixel slice within image
      int Sg = HW >> 7;
      int G = Cout >> 3;               // 8 groups (Cout=64, grid.y=1)
      gnp[((n * G + tid) * Sg + sIdx) * 2]     = s;
      gnp[((n * G + tid) * Sg + sIdx) * 2 + 1] = s2;
    }
  }
}

// ---------------- direct 3x3 conv, CO per thread, optional gn1 partials -----
template <int CO, int CIC>
__global__ __launch_bounds__(256) void conv3x3_kernel(
    const float* __restrict__ in, const float* __restrict__ wgt,
    const float* __restrict__ bias, float* __restrict__ out,
    int Cin, int H, int W, int Cout, int do_lrelu, float* __restrict__ gnp) {
  __shared__ float sm[CIC][18][18];
  int tiles_x = W >> 4;
  int bt = blockIdx.x;
  int tx0 = (bt % tiles_x) << 4;
  int ty0 = (bt / tiles_x) << 4;
  int co0 = blockIdx.y * CO;
  int n = blockIdx.z;
  int tid = threadIdx.x;
  int lx = tid & 15, ly = tid >> 4;

  float acc[CO];
#pragma unroll
  for (int i = 0; i < CO; i++) acc[i] = 0.f;

  const float* inb = in + (size_t)n * Cin * H * W;

  for (int ci0 = 0; ci0 < Cin; ci0 += CIC) {
    __syncthreads();
    for (int idx = tid; idx < CIC * 324; idx += 256) {
      int ci = idx / 324;
      int r = idx - ci * 324;
      int gy = r / 18, gx = r - gy * 18;
      int iy = ty0 + gy - 1, ix = tx0 + gx - 1;
      float v = 0.f;
      if ((unsigned)iy < (unsigned)H && (unsigned)ix < (unsigned)W)
        v = inb[((size_t)(ci0 + ci)) * H * W + (size_t)iy * W + ix];
      sm[ci][gy][gx] = v;
    }
    __syncthreads();
#pragma unroll
    for (int ci = 0; ci < CIC; ci++) {
      float x00 = sm[ci][ly][lx],     x01 = sm[ci][ly][lx + 1],     x02 = sm[ci][ly][lx + 2];
      float x10 = sm[ci][ly + 1][lx], x11 = sm[ci][ly + 1][lx + 1], x12 = sm[ci][ly + 1][lx + 2];
      float x20 = sm[ci][ly + 2][lx], x21 = sm[ci][ly + 2][lx + 1], x22 = sm[ci][ly + 2][lx + 2];
      const float* wp = wgt + ((size_t)co0 * Cin + (ci0 + ci)) * 9;
#pragma unroll
      for (int co = 0; co < CO; co++) {
        const float* wc = wp + (size_t)co * Cin * 9;
        float a = acc[co];
        a = fmaf(wc[0], x00, a); a = fmaf(wc[1], x01, a); a = fmaf(wc[2], x02, a);
        a = fmaf(wc[3], x10, a); a = fmaf(wc[4], x11, a); a = fmaf(wc[5], x12, a);
        a = fmaf(wc[6], x20, a); a = fmaf(wc[7], x21, a); a = fmaf(wc[8], x22, a);
        acc[co] = a;
      }
    }
  }

  float vout[CO];
#pragma unroll
  for (int co = 0; co < CO; co++) {
    float v = acc[co] + bias[co0 + co];
    if (do_lrelu) v = v > 0.f ? v : 0.2f * v;
    vout[co] = v;
  }

  if (gnp) {
    float p0 = 0.f, q0 = 0.f, p1 = 0.f, q1 = 0.f;
#pragma unroll
    for (int co = 0; co < 8; ++co) { p0 += vout[co]; q0 += vout[co] * vout[co]; }
#pragma unroll
    for (int co = 8; co < CO; ++co) { p1 += vout[co]; q1 += vout[co] * vout[co]; }
    float* red = &sm[0][0][0];
    __syncthreads();
    red[tid] = p0; red[256 + tid] = q0; red[512 + tid] = p1; red[768 + tid] = q1;
    __syncthreads();
    for (int st = 128; st > 0; st >>= 1) {
      if (tid < st) {
        red[tid] += red[tid + st]; red[256 + tid] += red[256 + tid + st];
        red[512 + tid] += red[512 + tid + st]; red[768 + tid] += red[768 + tid + st];
      }
      __syncthreads();
    }
    if (tid == 0) {
      int S = gridDim.x;
      gnp[((n * 2 + 0) * S + blockIdx.x) * 2]     = red[0];
      gnp[((n * 2 + 0) * S + blockIdx.x) * 2 + 1] = red[256];
      gnp[((n * 2 + 1) * S + blockIdx.x) * 2]     = red[512];
      gnp[((n * 2 + 1) * S + blockIdx.x) * 2 + 1] = red[768];
    }
  }

  int oy = ty0 + ly, ox = tx0 + lx;
#pragma unroll
  for (int co = 0; co < CO; co++)
    out[(((size_t)n * Cout + co0 + co) * H + oy) * W + ox] = vout[co];
}

// ---- fused inline-GN(input) + conv3x3(lrelu) + iwt + final 1x1 ws-conv -----
template <int CO, int CIC>
__global__ __launch_bounds__(256) void conv3x3_iwt_kernel(
    const float* __restrict__ in, const float* __restrict__ wgt,
    const float* __restrict__ bias, const float* __restrict__ fw,
    const float* __restrict__ gnp, const float* __restrict__ gamma,
    const float* __restrict__ beta, int G, int Sg, int len,
    float* __restrict__ out, int Cin, int H, int W) {
  __shared__ float sm[CIC][18][18];
  __shared__ float csc[16], csh[16];
  int tiles_x = W >> 4;
  int bt = blockIdx.x;
  int tx0 = (bt % tiles_x) << 4;
  int ty0 = (bt / tiles_x) << 4;
  int n = blockIdx.z;
  int tid = threadIdx.x;
  int lx = tid & 15, ly = tid >> 4;

  if (tid < Cin) {
    int g = tid / (Cin / G);
    const float* pp = gnp + (size_t)((n * G + g) * Sg) * 2;
    float s = 0.f, s2 = 0.f;
    for (int i = 0; i < Sg; ++i) { s += pp[2 * i]; s2 += pp[2 * i + 1]; }
    float mean = s / (float)len;
    float var = s2 / (float)len - mean * mean;
    if (var < 0.f) var = 0.f;
    float inv = rsqrtf(var + 1e-5f);
    float ga = gamma[tid];
    csc[tid] = inv * ga;
    csh[tid] = beta[tid] - mean * inv * ga;
  }
  __syncthreads();

  float acc[CO];
#pragma unroll
  for (int i = 0; i < CO; i++) acc[i] = 0.f;

  const float* inb = in + (size_t)n * Cin * H * W;

  for (int ci0 = 0; ci0 < Cin; ci0 += CIC) {
    __syncthreads();
    for (int idx = tid; idx < CIC * 324; idx += 256) {
      int ci = idx / 324;
      int r = idx - ci * 324;
      int gy = r / 18, gx = r - gy * 18;
      int iy = ty0 + gy - 1, ix = tx0 + gx - 1;
      float v = 0.f;
      if ((unsigned)iy < (unsigned)H && (unsigned)ix < (unsigned)W)
        v = inb[((size_t)(ci0 + ci)) * H * W + (size_t)iy * W + ix] * csc[ci0 + ci] + csh[ci0 + ci];
      sm[ci][gy][gx] = v;
    }
    __syncthreads();
#pragma unroll
    for (int ci = 0; ci < CIC; ci++) {
      float x00 = sm[ci][ly][lx],     x01 = sm[ci][ly][lx + 1],     x02 = sm[ci][ly][lx + 2];
      float x10 = sm[ci][ly + 1][lx], x11 = sm[ci][ly + 1][lx + 1], x12 = sm[ci][ly + 1][lx + 2];
      float x20 = sm[ci][ly + 2][lx], x21 = sm[ci][ly + 2][lx + 1], x22 = sm[ci][ly + 2][lx + 2];
      const float* wp = wgt + (size_t)(ci0 + ci) * 9;
#pragma unroll
      for (int co = 0; co < CO; co++) {
        const float* wc = wp + (size_t)co * Cin * 9;
        float a = acc[co];
        a = fmaf(wc[0], x00, a); a = fmaf(wc[1], x01, a); a = fmaf(wc[2], x02, a);
        a = fmaf(wc[3], x10, a); a = fmaf(wc[4], x11, a); a = fmaf(wc[5], x12, a);
        a = fmaf(wc[6], x20, a); a = fmaf(wc[7], x21, a); a = fmaf(wc[8], x22, a);
        acc[co] = a;
      }
    }
  }

  float vout[CO];
#pragma unroll
  for (int co = 0; co < CO; co++) {
    float v = acc[co] + bias[co];
    vout[co] = v > 0.f ? v : 0.2f * v;
  }

  float y0[3], y1[3], y2[3], y3[3];
#pragma unroll
  for (int c = 0; c < 3; ++c) {
    float v0 = vout[4 * c];
    float v1 = 2.f * vout[4 * c + 1] - 1.f;
    float v2 = 2.f * vout[4 * c + 2] - 1.f;
    float v3 = 2.f * vout[4 * c + 3] - 1.f;
    y0[c] = v0 + 0.5f * ( v1 + v2 + v3);
    y1[c] = v0 + 0.5f * ( v1 - v2 - v3);
    y2[c] = v0 + 0.5f * (-v1 + v2 - v3);
    y3[c] = v0 + 0.5f * (-v1 - v2 + v3);
  }
  float w0 = fw[0], w1 = fw[1], w2 = fw[2], w3 = fw[3], w4 = fw[4], w5 = fw[5];
  int oy = ty0 + ly, ox = tx0 + lx;
  int OW = 2 * W;
  size_t ocs = (size_t)(2 * H) * OW;
  float* o0 = out + (size_t)n * 2 * ocs + (size_t)(2 * oy) * OW + 2 * ox;
  o0[0]      = w0 * y0[0] + w1 * y0[1] + w2 * y0[2];
  o0[1]      = w0 * y1[0] + w1 * y1[1] + w2 * y1[2];
  o0[OW]     = w0 * y2[0] + w1 * y2[1] + w2 * y2[2];
  o0[OW + 1] = w0 * y3[0] + w1 * y3[1] + w2 * y3[2];
  float* o1 = o0 + ocs;
  o1[0]      = w3 * y0[0] + w4 * y0[1] + w5 * y0[2];
  o1[1]      = w3 * y1[0] + w4 * y1[1] + w5 * y1[2];
  o1[OW]     = w3 * y2[0] + w4 * y2[1] + w5 * y2[2];
  o1[OW + 1] = w3 * y3[0] + w4 * y3[1] + w5 * y3[2];
}

// ---------------------------------------------------------------------------

extern "C" void kernel_launch(void* const* d_in, const int* in_sizes, int n_in,
                              void* d_out, int out_size, void* d_ws, size_t ws_size,
                              hipStream_t stream) {
  const float* x        = (const float*)d_in[0];
  const float* conv1_w  = (const float*)d_in[1];
  const float* conv1_b  = (const float*)d_in[2];
  const float* conv2_w  = (const float*)d_in[3];
  const float* conv2_b  = (const float*)d_in[4];
  const float* conv3_w  = (const float*)d_in[5];
  const float* conv3_b  = (const float*)d_in[6];
  const float* conv4_w  = (const float*)d_in[7];
  const float* conv4_b  = (const float*)d_in[8];
  const float* convd1_w = (const float*)d_in[9];
  const float* convd1_b = (const float*)d_in[10];
  const float* convd2_w = (const float*)d_in[11];
  const float* convd2_b = (const float*)d_in[12];
  const float* convd3_w = (const float*)d_in[13];
  const float* convd3_b = (const float*)d_in[14];
  const float* convd4_w = (const float*)d_in[15];
  const float* convd4_b = (const float*)d_in[16];
  const float* final_w  = (const float*)d_in[17];
  const float* gn1_w = (const float*)d_in[18];
  const float* gn1_b = (const float*)d_in[19];
  const float* gn2_w = (const float*)d_in[20];
  const float* gn2_b = (const float*)d_in[21];
  const float* gn3_w = (const float*)d_in[22];
  const float* gn3_b = (const float*)d_in[23];
  const float* gn4_w = (const float*)d_in[24];
  const float* gn4_b = (const float*)d_in[25];

  char* base = (char*)d_ws;
  size_t off = 0;
  auto allocB = [&](size_t bytes) { size_t o = off; off = (off + bytes + 255) & ~(size_t)255; return o; };

  size_t o_sw1  = allocB(16 * 108 * 4);
  size_t o_swd1 = allocB(12 * 144 * 4);
  size_t o_swd2 = allocB(16 * 288 * 4);
  size_t o_swf  = allocB(6 * 4);
  size_t o_pw2  = allocB((size_t)9 * 64 * 64 * 2);
  size_t o_pw3  = allocB((size_t)9 * 256 * 256 * 2);
  size_t o_pw4  = allocB((size_t)9 * 1024 * 1024 * 2);
  size_t o_pwd3 = allocB((size_t)9 * 64 * 128 * 2);
  size_t o_pwd4 = allocB((size_t)9 * 256 * 512 * 2);
  size_t o_R1   = allocB((size_t)NB * 66 * 66 * 128 * 2);  // part | ah64 | ah128
  size_t o_R2   = allocB((size_t)NB * 34 * 34 * 512 * 2);  // ah256 | ah1k | ah512
  size_t o_gnp  = allocB(16384 * 4);                        // gn block partials
  size_t o_c1 = allocB((size_t)NB * 16 * 128 * 128 * 4);
  size_t o_c2 = allocB((size_t)NB * 64 * 64 * 64 * 4);
  size_t o_c3 = allocB((size_t)NB * 256 * 32 * 32 * 4);
  size_t o_w4 = allocB((size_t)NB * 1024 * 16 * 16 * 4);
  size_t o_t1 = allocB((size_t)NB * 1024 * 16 * 16 * 4);
  size_t o_t2 = allocB((size_t)NB * 512 * 32 * 32 * 4);

  if (off > ws_size) return;

  float* c1 = (float*)(base + o_c1);
  float* c2 = (float*)(base + o_c2);
  float* c3 = (float*)(base + o_c3);
  float* w4 = (float*)(base + o_w4);
  float* t1 = (float*)(base + o_t1);
  float* t2 = (float*)(base + o_t2);
  f16* part  = (f16*)(base + o_R1);
  f16* ah64  = (f16*)(base + o_R1);
  f16* ah128 = (f16*)(base + o_R1);
  f16* ah256 = (f16*)(base + o_R2);
  f16* ah1k  = (f16*)(base + o_R2);
  f16* ah512 = (f16*)(base + o_R2);
  f16* pw2 = (f16*)(base + o_pw2);
  f16* pw3 = (f16*)(base + o_pw3);
  f16* pw4 = (f16*)(base + o_pw4);
  f16* pwd3 = (f16*)(base + o_pwd3);
  f16* pwd4 = (f16*)(base + o_pwd4);
  float* gnp = (float*)(base + o_gnp);

  // ---- upfront ----
  {
    int n0 = NB * (2 * 66 + 2 * 64) * (64 / 8);
    int n1 = NB * (2 * 34 + 2 * 32) * (256 / 8);
    int tot = n0 + n1;
    halo2_kernel<<<(tot + 255) / 256, 256, 0, stream>>>(ah64, 64, 64, 64, n0,
                                                        ah256, 256, 32, 32, tot);
  }
  ws_all_kernel<<<46, 256, 0, stream>>>(conv1_w, (float*)(base + o_sw1),
                                        convd1_w, (float*)(base + o_swd1),
                                        convd2_w, (float*)(base + o_swd2),
                                        final_w, (float*)(base + o_swf));
  ws_f16_all_kernel<<<1664, 256, 0, stream>>>(conv2_w, pw2, conv3_w, pw3, conv4_w, pw4,
                                              convd3_w, pwd3, convd4_w, pwd4);

  auto prep_nhwc = [&](const float* in, f16* ah, int C, int H, int W, int zero) {
    if (zero) {
      int total8 = NB * (2 * (W + 2) + 2 * H) * (C / 8);
      zero_halo_kernel<<<(total8 + 255) / 256, 256, 0, stream>>>(ah, C, H, W, total8);
    }
    dim3 g((H * W) / 256, C / 32, NB);
    to_nhwc_pad_kernel<<<g, 256, 0, stream>>>(in, ah, C, H, W);
  };
  auto wt_nhwc_gn = [&](const float* in, f16* ah, float* haar32, float* wb,
                        const float* gg, const float* gb, int G, int Sg,
                        int C, int Ho, int Wo) {
    int len = (C / G) * (4 * Ho * Wo);
    dim3 g((Ho * Wo) / 256, C / 8, NB);
    wt_nhwc_gn_kernel<<<g, 256, 0, stream>>>(in, gnp, gg, gb, G, Sg, len,
                                             ah, haar32, wb, C, Ho, Wo);
  };
  auto cm6conv = [&](const f16* a, const f16* wt, int Cin, int Hs, int Ws, int Cout) {
    dim3 g((NB * Hs * Ws) / 128, Cout / 128, 2);
    conv_mfma6_kernel<<<g, 256, 0, stream>>>(a, wt, part, Cin, Hs, Ws, Cout, Hs * Ws);
  };
  auto cm6 = [&](const f16* a, const f16* wt, const float* b, float* dest, const float* add,
                 int Cin, int Hs, int Ws, int Cout, int lr, int G, int Sg) {
    cm6conv(a, wt, Cin, Hs, Ws, Cout);
    int total4 = (NB * Cout * Hs * Ws) >> 2;
    reduceS_kernel<<<(total4 + 255) / 256, 256, 0, stream>>>(
        part, b, add, dest, Cout, Hs * Ws, 2, lr, total4, G ? gnp : nullptr, G, Sg);
  };
  // cm3: Cout=64 conv with fused GN-partial epilogue (8 groups, Sg = HW/128)
  auto cm3 = [&](const f16* a, const f16* wt, const float* b, float* o,
                 int Cin, int Hs, int Ws, int lr) {
    dim3 g((NB * Hs * Ws) / 128, 1);
    conv_mfma3_kernel<<<g, 256, 0, stream>>>(a, wt, b, o, Cin, Hs, Ws, 64, Hs * Ws, lr, gnp);
  };

  // ==== encoder ====
  {
    int total = NB * 3 * 128 * 128;
    wt_kernel<<<(total + 255) / 256, 256, 0, stream>>>(x, t1, 3, 128, 128, total);  // w1
  }
  {
    dim3 g(64, 1, NB);
    conv3x3_kernel<16, 4><<<g, 256, 0, stream>>>(t1, (float*)(base + o_sw1), conv1_b,
                                                 c1, 12, 128, 128, 16, 1, gnp);
  }
  // gn1(c1) fused into wt_nhwc_gn (writeback -> c1 for skip use); w2 -> ah64
  wt_nhwc_gn(c1, ah64, nullptr, c1, gn1_w, gn1_b, 2, 64, 16, 64, 64);

  cm3(ah64, pw2, conv2_b, c2, 64, 64, 64, 1);                       // c2 (+partials Sg=32)
  // gn2(c2) fused; w3 -> ah256
  wt_nhwc_gn(c2, ah256, nullptr, c2, gn2_w, gn2_b, 8, 32, 64, 32, 32);

  cm6(ah256, pw3, conv3_b, c3, nullptr, 256, 32, 32, 256, 1, 32, 8);  // c3 (+partials)
  {
    int total8 = NB * (2 * 18 + 2 * 16) * (1024 / 8);
    zero_halo_kernel<<<(total8 + 255) / 256, 256, 0, stream>>>(ah1k, 1024, 16, 16, total8);
  }
  // gn3(c3) fused; w4 -> ah1k + fp32 Haar copy (residual) + writeback -> c3
  wt_nhwc_gn(c3, ah1k, w4, c3, gn3_w, gn3_b, 32, 8, 256, 16, 16);

  cm6(ah1k, pw4, conv4_b, t1, nullptr, 1024, 16, 16, 1024, 1, 128, 2);  // c4 -> t1
  {
    dim3 g(1, 32, NB);
    gn_nhwc_kernel<<<g, 256, 0, stream>>>(t1, gnp, gn4_w, gn4_b, ah1k, 1024, 16, 16,
                                          128, 2, 2048);
  }
  cm6(ah1k, pw4, conv4_b, t2, nullptr, 1024, 16, 16, 1024, 1, 128, 2);  // c5 -> t2
  {
    dim3 g(1, 32, NB);
    gn_nhwc_kernel<<<g, 256, 0, stream>>>(t2, gnp, gn4_w, gn4_b, ah1k, 1024, 16, 16,
                                          128, 2, 2048);
  }
  // c6 partials only; split-K sum + bias + w4-add + lrelu folded into iw4 concat
  cm6conv(ah1k, pw4, 1024, 16, 16, 1024);

  // ==== decoder ====
  // iw4 = concat(c3, iwt(lrelu(part0+part1+bias+w4))) -> t2 (NCHW fp32)
  {
    int totalA = NB * 256 * 4 * 16 * 16;
    int total = totalA + NB * 256 * 16 * 16;
    concat_iwt_kernel<<<(total + 255) / 256, 256, 0, stream>>>(
        c3, nullptr, part, conv4_b, w4, t2,
        nullptr, nullptr, nullptr, 0, 0, 0, 256, 16, 16, totalA, total);
  }
  prep_nhwc(t2, ah512, 512, 32, 32, 1);
  cm6(ah512, pwd4, convd4_b, t1, nullptr, 512, 32, 32, 256, 1, 32, 8);  // ic3 (+partials)
  // iw3 -> t2 (gn3 inline)
  {
    int totalA = NB * 64 * 4 * 32 * 32;
    int total = totalA + NB * 64 * 32 * 32;
    int len = (256 / 32) * 32 * 32;
    concat_iwt_kernel<<<(total + 255) / 256, 256, 0, stream>>>(
        c2, t1, nullptr, nullptr, nullptr, t2,
        gnp, gn3_w, gn3_b, 32, 8, len, 64, 32, 32, totalA, total);
  }
  prep_nhwc(t2, ah128, 128, 64, 64, 1);
  cm3(ah128, pwd3, convd3_b, t1, 128, 64, 64, 1);                   // ic2 (+partials Sg=32)
  // iw2 -> t2 (gn2 inline, partials from ic2 epilogue)
  {
    int totalA = NB * 16 * 4 * 64 * 64;
    int total = totalA + NB * 16 * 64 * 64;
    int len = (64 / 8) * 64 * 64;
    concat_iwt_kernel<<<(total + 255) / 256, 256, 0, stream>>>(
        c1, t1, nullptr, nullptr, nullptr, t2,
        gnp, gn2_w, gn2_b, 8, 32, len, 16, 64, 64, totalA, total);
  }
  {
    dim3 g(64, 1, NB);
    conv3x3_kernel<16, 4><<<g, 256, 0, stream>>>(t2, (float*)(base + o_swd2), convd2_b,
                                                 t1, 32, 128, 128, 16, 1, gnp);
  }
  // gn1(ic1) fused into conv3x3_iwt's input read; final conv + iwt + 1x1
  {
    dim3 g(64, 1, NB);
    conv3x3_iwt_kernel<12, 4><<<g, 256, 0, stream>>>(
        t1, (float*)(base + o_swd1), convd1_b, (float*)(base + o_swf),
        gnp, gn1_w, gn1_b, 2, 64, 8 * 128 * 128, (float*)d_out, 16, 128, 128);
  }
}

// Round 13
// 848.202 us; speedup vs baseline: 1.1328x; 1.0345x over previous
//
#include <hip/hip_runtime.h>
#include <math.h>

// ---------------------------------------------------------------------------
// WaveletNet forward. conv_mfma6: 128x128x64 double-buffered (1 barrier/iter),
// split-K=2, 256 threads, 2 blocks/CU (cross-block overlap is the latency
// hiding mechanism - R4/R5/R7 ablations). GN-apply fused into consumers
// (wt_nhwc_gn / conv3x3_iwt / gn_nhwc_part). GN-stats fused into producer
// epilogues (reduceS, conv_mfma3 shfl-butterfly, conv3x3, gn_nhwc_part
// in-block: at 16x16 spatial one block holds 4 complete groups).
// ic4 split-K reduce folded into the iw4 concat. N=16 fixed.
// ---------------------------------------------------------------------------

#define NB 16  // batch

typedef _Float16 f16;
typedef _Float16 f16x8 __attribute__((ext_vector_type(8)));
typedef _Float16 f16x4 __attribute__((ext_vector_type(4)));
typedef float f32x4 __attribute__((ext_vector_type(4)));
typedef float f32x2 __attribute__((ext_vector_type(2)));
typedef unsigned int u32;

#define LLDS16(gp, lp)                                                          \
  __builtin_amdgcn_global_load_lds((const __attribute__((address_space(1))) u32*)(const void*)(gp), \
                                   (__attribute__((address_space(3))) u32*)(void*)(lp), 16, 0, 0)

// ---------------- weight standardization ----------------
__device__ __forceinline__ void ws_reduce(const float* wp, int fan, float* red,
                                          float& mean, float& inv) {
  float s = 0.f, s2 = 0.f;
  for (int i = threadIdx.x; i < fan; i += 256) { float v = wp[i]; s += v; s2 += v * v; }
  red[threadIdx.x] = s; red[256 + threadIdx.x] = s2;
  __syncthreads();
  for (int st = 128; st > 0; st >>= 1) {
    if (threadIdx.x < st) {
      red[threadIdx.x] += red[threadIdx.x + st];
      red[256 + threadIdx.x] += red[256 + threadIdx.x + st];
    }
    __syncthreads();
  }
  float sum = red[0], sumsq = red[256];
  mean = sum / (float)fan;
  float var = (sumsq - sum * mean) / (float)(fan - 1);
  if (var < 0.f) var = 0.f;
  inv = 1.0f / (sqrtf(var) + 1e-5f);
}

__global__ void ws_all_kernel(const float* w0, float* o0, const float* w1, float* o1,
                              const float* w2, float* o2, const float* w3, float* o3) {
  __shared__ float red[512];
  int b = blockIdx.x;
  const float* w; float* o; int fan, oi;
  if (b < 16)      { w = w0; o = o0; fan = 108; oi = b; }
  else if (b < 28) { w = w1; o = o1; fan = 144; oi = b - 16; }
  else if (b < 44) { w = w2; o = o2; fan = 288; oi = b - 28; }
  else             { w = w3; o = o3; fan = 3;   oi = b - 44; }
  const float* wp = w + (size_t)oi * fan;
  float mean, inv; ws_reduce(wp, fan, red, mean, inv);
  for (int i = threadIdx.x; i < fan; i += 256)
    o[(size_t)oi * fan + i] = (wp[i] - mean) * inv;
}

__global__ void ws_f16_all_kernel(const float* w0, f16* o0, const float* w1, f16* o1,
                                  const float* w2, f16* o2, const float* w3, f16* o3,
                                  const float* w4, f16* o4) {
  __shared__ float red[512];
  int b = blockIdx.x;
  const float* w; f16* o; int fan, Cin, Cout, oi;
  if (b < 64)        { w = w0; o = o0; fan = 576;  Cin = 64;   Cout = 64;   oi = b; }
  else if (b < 320)  { w = w1; o = o1; fan = 2304; Cin = 256;  Cout = 256;  oi = b - 64; }
  else if (b < 1344) { w = w2; o = o2; fan = 9216; Cin = 1024; Cout = 1024; oi = b - 320; }
  else if (b < 1408) { w = w3; o = o3; fan = 1152; Cin = 128;  Cout = 64;   oi = b - 1344; }
  else               { w = w4; o = o4; fan = 4608; Cin = 512;  Cout = 256;  oi = b - 1408; }
  const float* wp = w + (size_t)oi * fan;
  float mean, inv; ws_reduce(wp, fan, red, mean, inv);
  for (int i = threadIdx.x; i < fan; i += 256) {
    int ci = i / 9, tap = i - ci * 9;
    o[((size_t)tap * Cout + oi) * Cin + ci] = (f16)((wp[i] - mean) * inv);
  }
}

// ---------------- halo zero ----------------
__device__ __forceinline__ void halo_write(f16* buf, int C, int H, int W, int t) {
  int c8s = C >> 3;
  int c8 = t % c8s; int q = t / c8s;
  int P = 2 * (W + 2) + 2 * H;
  int b = q % P; int n = q / P;
  int y, x;
  if (b < W + 2) { y = 0; x = b; }
  else if (b < 2 * (W + 2)) { y = H + 1; x = b - (W + 2); }
  else { int bb = b - 2 * (W + 2); y = 1 + (bb >> 1); x = (bb & 1) ? (W + 1) : 0; }
  size_t a = (((size_t)n * (H + 2) + y) * (W + 2) + x) * C + c8 * 8;
  *(f16x8*)(buf + a) = (f16x8){0, 0, 0, 0, 0, 0, 0, 0};
}

__global__ void halo2_kernel(f16* b0, int c0, int h0, int w0, int n0,
                             f16* b1, int c1, int h1, int w1, int total) {
  int idx = blockIdx.x * 256 + threadIdx.x;
  if (idx >= total) return;
  if (idx < n0) halo_write(b0, c0, h0, w0, idx);
  else halo_write(b1, c1, h1, w1, idx - n0);
}

__global__ void zero_halo_kernel(f16* __restrict__ buf, int C, int H, int W, int total8) {
  int idx = blockIdx.x * 256 + threadIdx.x;
  if (idx >= total8) return;
  halo_write(buf, C, H, W, idx);
}

// ---------------- Haar forward (NCHW fp32) ----------------
__global__ void wt_kernel(const float* __restrict__ in, float* __restrict__ out,
                          int C, int Ho, int Wo, int total) {
  int idx = blockIdx.x * 256 + threadIdx.x;
  if (idx >= total) return;
  int w = idx % Wo; int t = idx / Wo;
  int h = t % Ho; t /= Ho;
  int c = t % C; int n = t / C;
  int Wi = 2 * Wo;
  const float* ip = in + (((size_t)n * C + c) * (2 * Ho) + 2 * h) * Wi + 2 * w;
  float a = ip[0], b = ip[1], cc = ip[Wi], d = ip[Wi + 1];
  size_t cs = (size_t)Ho * Wo;
  float* op = out + (((size_t)n * 4 * C + 4 * c) * Ho + h) * Wo + w;
  op[0]      = 0.25f * (a + b + cc + d);
  op[cs]     = 0.25f * (a + b - cc - d) + 0.5f;
  op[2 * cs] = 0.25f * (a - b + cc - d) + 0.5f;
  op[3 * cs] = 0.25f * (a - b - cc + d) + 0.5f;
}

// ---------------- fused GN-apply + Haar + NCHW->padded NHWC f16 -------------
__global__ __launch_bounds__(256) void wt_nhwc_gn_kernel(
    const float* __restrict__ in, const float* __restrict__ gnp,
    const float* __restrict__ gamma, const float* __restrict__ beta,
    int G, int Sg, int len,
    f16* __restrict__ out, float* __restrict__ out32, float* __restrict__ gnwb,
    int C, int Ho, int Wo) {
  __shared__ f16 sm[32][264];
  __shared__ float scs[8], shs[8];
  int HWo = Ho * Wo;
  int p0 = blockIdx.x * 256, c0 = blockIdx.y * 8, n = blockIdx.z;
  int t = threadIdx.x;
  if (t < 8) {
    int c = c0 + t;
    int g = c / (C / G);
    const float* pp = gnp + (size_t)((n * G + g) * Sg) * 2;
    float s = 0.f, s2 = 0.f;
    for (int i = 0; i < Sg; ++i) { s += pp[2 * i]; s2 += pp[2 * i + 1]; }
    float mean = s / (float)len;
    float var = s2 / (float)len - mean * mean;
    if (var < 0.f) var = 0.f;
    float inv = rsqrtf(var + 1e-5f);
    float ga = gamma[c];
    scs[t] = inv * ga;
    shs[t] = beta[c] - mean * inv * ga;
  }
  __syncthreads();
  int p = p0 + t; int h = p / Wo; int ww = p - h * Wo;
  int Wi = 2 * Wo;
  int C4 = 4 * C;
#pragma unroll
  for (int r = 0; r < 8; ++r) {
    size_t ioff = (((size_t)n * C + c0 + r) * (2 * Ho) + 2 * h) * Wi + 2 * ww;
    const float* ip = in + ioff;
    f32x2 u0 = *(const f32x2*)ip;
    f32x2 u1 = *(const f32x2*)(ip + Wi);
    float sc = scs[r], sh = shs[r];
    float a = u0.x * sc + sh, b = u0.y * sc + sh;
    float cc = u1.x * sc + sh, d = u1.y * sc + sh;
    if (gnwb) {
      float* wp = gnwb + ioff;
      *(f32x2*)wp = (f32x2){a, b};
      *(f32x2*)(wp + Wi) = (f32x2){cc, d};
    }
    float v0 = 0.25f * (a + b + cc + d);
    float v1 = 0.25f * (a + b - cc - d) + 0.5f;
    float v2 = 0.25f * (a - b + cc - d) + 0.5f;
    float v3 = 0.25f * (a - b - cc + d) + 0.5f;
    sm[4 * r][t]     = (f16)v0;
    sm[4 * r + 1][t] = (f16)v1;
    sm[4 * r + 2][t] = (f16)v2;
    sm[4 * r + 3][t] = (f16)v3;
    if (out32) {
      float* op = out32 + (((size_t)n * C4 + 4 * (c0 + r)) * Ho + h) * Wo + ww;
      size_t cs = (size_t)HWo;
      op[0] = v0; op[cs] = v1; op[2 * cs] = v2; op[3 * cs] = v3;
    }
  }
  __syncthreads();
#pragma unroll
  for (int i = 0; i < 4; ++i) {
    int c = t + i * 256;
    int pl = c >> 2, cio = (c & 3) * 8;
    f16x8 v;
#pragma unroll
    for (int u = 0; u < 8; ++u) v[u] = sm[cio + u][pl];
    int pp = p0 + pl; int y = pp / Wo; int x = pp - y * Wo;
    *(f16x8*)(out + (((size_t)n * (Ho + 2) + y + 1) * (Wo + 2) + x + 1) * C4 + c0 * 4 + cio) = v;
  }
}

// ---------------- fused concat + iwt (+optional inline GN / part-reduce) ----
__global__ void concat_iwt_kernel(const float* __restrict__ skip, const float* __restrict__ v,
                                  const f16* __restrict__ part, const float* __restrict__ bias,
                                  const float* __restrict__ add,
                                  float* __restrict__ out, const float* __restrict__ gnp,
                                  const float* __restrict__ gamma, const float* __restrict__ beta,
                                  int G, int Sg, int len, int C, int Hh, int Wh,
                                  int totalA, int total) {
  int idx = blockIdx.x * 256 + threadIdx.x;
  if (idx >= total) return;
  int W = 2 * Wh, H = 2 * Hh; int HWs = H * W;
  if (idx < totalA) {
    int p = idx % HWs; int t = idx / HWs; int c = t % C; int n = t / C;
    out[((size_t)n * 2 * C + c) * HWs + p] = skip[idx];
    return;
  }
  int i2 = idx - totalA;
  int w = i2 % Wh; int t = i2 / Wh; int h = t % Hh; t /= Hh;
  int c = t % C; int n = t / C;
  size_t cs = (size_t)Hh * Wh;
  float v0, v1, v2, v3;
  if (part) {
    size_t base_off = (((size_t)n * 4 * C + 4 * c) * Hh + h) * Wh + w;
    size_t sstr = (size_t)NB * 4 * C * cs;
    float vv[4];
#pragma unroll
    for (int k = 0; k < 4; ++k) {
      size_t off = base_off + (size_t)k * cs;
      float val = (float)part[off] + (float)part[sstr + off] + bias[4 * c + k];
      if (add) val += add[off];
      vv[k] = val > 0.f ? val : 0.2f * val;
    }
    v0 = vv[0]; v1 = vv[1]; v2 = vv[2]; v3 = vv[3];
  } else {
    const float* vp = v + (((size_t)n * 4 * C + 4 * c) * Hh + h) * Wh + w;
    v0 = vp[0]; v1 = vp[cs]; v2 = vp[2 * cs]; v3 = vp[3 * cs];
  }
  if (gnp) {
    int cpg = (4 * C) / G;
    int g = (4 * c) / cpg;
    const float* pp = gnp + (size_t)((n * G + g) * Sg) * 2;
    float s = 0.f, s2 = 0.f;
    for (int i = 0; i < Sg; ++i) { s += pp[2 * i]; s2 += pp[2 * i + 1]; }
    float mean = s / (float)len;
    float var = s2 / (float)len - mean * mean;
    if (var < 0.f) var = 0.f;
    float inv = rsqrtf(var + 1e-5f);
    v0 = (v0 - mean) * inv * gamma[4 * c]     + beta[4 * c];
    v1 = (v1 - mean) * inv * gamma[4 * c + 1] + beta[4 * c + 1];
    v2 = (v2 - mean) * inv * gamma[4 * c + 2] + beta[4 * c + 2];
    v3 = (v3 - mean) * inv * gamma[4 * c + 3] + beta[4 * c + 3];
  }
  v1 = 2.f * v1 - 1.f; v2 = 2.f * v2 - 1.f; v3 = 2.f * v3 - 1.f;
  float* op = out + (((size_t)n * 2 * C + C + c) * H + 2 * h) * (size_t)W + 2 * w;
  op[0]     = v0 + 0.5f * ( v1 + v2 + v3);
  op[1]     = v0 + 0.5f * ( v1 - v2 - v3);
  op[W]     = v0 + 0.5f * (-v1 + v2 - v3);
  op[W + 1] = v0 + 0.5f * (-v1 - v2 + v3);
}

// ---------------- NCHW fp32 -> padded NHWC f16 (LDS transpose) --------------
__global__ __launch_bounds__(256) void to_nhwc_pad_kernel(const float* __restrict__ in,
                                                          f16* __restrict__ out,
                                                          int C, int H, int W) {
  __shared__ f16 sm[32][264];
  int HW = H * W;
  int p0 = blockIdx.x * 256, c0 = blockIdx.y * 32, n = blockIdx.z;
  int t = threadIdx.x;
  const float* ip = in + ((size_t)n * C + c0) * HW + p0;
#pragma unroll 8
  for (int r = 0; r < 32; ++r) sm[r][t] = (f16)ip[(size_t)r * HW + t];
  __syncthreads();
#pragma unroll
  for (int i = 0; i < 4; ++i) {
    int c = t + i * 256;
    int pl = c >> 2, cio = (c & 3) * 8;
    f16x8 v;
#pragma unroll
    for (int u = 0; u < 8; ++u) v[u] = sm[cio + u][pl];
    int p = p0 + pl; int y = p / W; int x = p - y * W;
    *(f16x8*)(out + (((size_t)n * (H + 2) + y + 1) * (W + 2) + x + 1) * C + c0 + cio) = v;
  }
}

// ---- fused split-K reduce + bias + lrelu + in-block GN + NHWC f16 pack -----
// Specialized for HW == 256 (grid.x == 1): each block covers 32 channels x
// all 256 pixels = 4 COMPLETE GN groups (cpg=8) -> stats computed in-block.
__global__ __launch_bounds__(256) void gn_nhwc_part_kernel(
    const f16* __restrict__ part, const float* __restrict__ bias,
    const float* __restrict__ gamma, const float* __restrict__ beta,
    f16* __restrict__ out, int C, int H, int W) {
  __shared__ f16 sm[32][264];
  __shared__ float redg[32];   // 4 groups x 4 waves x {s,s2}
  const int HW = H * W;  // 256
  const int c0 = blockIdx.y * 32, n = blockIdx.z;
  const int t = threadIdx.x;
  const int w = t >> 6, lane = t & 63;
  const size_t sstr = (size_t)NB * C * HW;
  float val[32];
  float s[4] = {0.f, 0.f, 0.f, 0.f}, s2[4] = {0.f, 0.f, 0.f, 0.f};
#pragma unroll
  for (int r = 0; r < 32; ++r) {
    int c = c0 + r;
    size_t off = ((size_t)n * C + c) * HW + t;
    float v = (float)part[off] + (float)part[sstr + off] + bias[c];
    v = v > 0.f ? v : 0.2f * v;
    val[r] = v;
    s[r >> 3] += v; s2[r >> 3] += v * v;
  }
#pragma unroll
  for (int g = 0; g < 4; ++g) {
    float a = s[g], b = s2[g];
    a += __shfl_xor(a, 1);  b += __shfl_xor(b, 1);
    a += __shfl_xor(a, 2);  b += __shfl_xor(b, 2);
    a += __shfl_xor(a, 4);  b += __shfl_xor(b, 4);
    a += __shfl_xor(a, 8);  b += __shfl_xor(b, 8);
    a += __shfl_xor(a, 16); b += __shfl_xor(b, 16);
    a += __shfl_xor(a, 32); b += __shfl_xor(b, 32);
    if (lane == 0) { redg[(g * 4 + w) * 2] = a; redg[(g * 4 + w) * 2 + 1] = b; }
  }
  __syncthreads();
  float mean[4], inv[4];
#pragma unroll
  for (int g = 0; g < 4; ++g) {
    float a = redg[(g * 4 + 0) * 2]     + redg[(g * 4 + 1) * 2]
            + redg[(g * 4 + 2) * 2]     + redg[(g * 4 + 3) * 2];
    float b = redg[(g * 4 + 0) * 2 + 1] + redg[(g * 4 + 1) * 2 + 1]
            + redg[(g * 4 + 2) * 2 + 1] + redg[(g * 4 + 3) * 2 + 1];
    float len = 8.f * (float)HW;  // 2048
    float m = a / len;
    float var = b / len - m * m;
    if (var < 0.f) var = 0.f;
    mean[g] = m; inv[g] = rsqrtf(var + 1e-5f);
  }
#pragma unroll
  for (int r = 0; r < 32; ++r) {
    int c = c0 + r;
    int g = r >> 3;
    sm[r][t] = (f16)((val[r] - mean[g]) * inv[g] * gamma[c] + beta[c]);
  }
  __syncthreads();
#pragma unroll
  for (int i = 0; i < 4; ++i) {
    int c = t + i * 256;
    int pl = c >> 2, cio = (c & 3) * 8;
    f16x8 v;
#pragma unroll
    for (int u = 0; u < 8; ++u) v[u] = sm[cio + u][pl];
    int y = pl / W; int x = pl - y * W;
    *(f16x8*)(out + (((size_t)n * (H + 2) + y + 1) * (W + 2) + x + 1) * C + c0 + cio) = v;
  }
}

// ---------------- conv_mfma6: 128x128x64, dbuf, 1 barrier/iter, split-K -----
__global__ __launch_bounds__(256) void conv_mfma6_kernel(
    const f16* __restrict__ A, const f16* __restrict__ Wp,
    f16* __restrict__ part, int Cin, int H, int W, int Cout, int HW) {
  constexpr int CH = 128 * 64;  // f16 per buffer
  __shared__ f16 Asm[2 * CH];   // 32 KB
  __shared__ f16 Bsm[2 * CH];   // 32 KB

  const int tid = threadIdx.x;
  const int w = tid >> 6, lane = tid & 63;
  const int m0 = blockIdx.x * 128;
  const int co0 = blockIdx.y * 128;
  const int Wp2 = W + 2;

  const f16* gA[4]; const f16* gB[4];
  int lOff[4];
#pragma unroll
  for (int e = 0; e < 4; ++e) {
    int c = e * 256 + tid;
    int r = c >> 3, j = c & 7;
    int jx = j ^ (r & 7);
    int m = m0 + r; int n = m / HW; int p = m - n * HW;
    int y = p / W; int x = p - y * W;
    gA[e] = A + (((size_t)n * (H + 2) + y + 1) * Wp2 + (x + 1)) * Cin + jx * 8;
    gB[e] = Wp + (size_t)(co0 + r) * Cin + jx * 8;
    lOff[e] = (e * 256 + w * 64) * 8;  // wave-uniform
  }

  const int wm = w & 1, wn = w >> 1;
  const int lr = lane & 15, quad = lane >> 4;
  int aoffs[4][2], boffs[4][2];
#pragma unroll
  for (int i = 0; i < 4; ++i)
#pragma unroll
    for (int kk = 0; kk < 2; ++kk) {
      int r = wm * 64 + i * 16 + lr;
      int cidx = kk * 4 + quad;
      aoffs[i][kk] = (r * 8 + (cidx ^ (r & 7))) * 8;
      int rb = wn * 64 + i * 16 + lr;
      boffs[i][kk] = (rb * 8 + (cidx ^ (rb & 7))) * 8;
    }

  f32x4 acc[4][4];
#pragma unroll
  for (int i = 0; i < 4; ++i)
#pragma unroll
    for (int j = 0; j < 4; ++j) acc[i][j] = (f32x4){0.f, 0.f, 0.f, 0.f};

  const int kpt = Cin >> 6;
  const int nit = (9 * kpt) / gridDim.z;
  const int it0 = blockIdx.z * nit;
  const size_t bstride = (size_t)Cout * Cin;

  auto stageAB = [&](int it, int sel) {
    int tap = it / kpt, kk = it - tap * kpt;
    int dy = tap / 3 - 1, dx = tap % 3 - 1;
    long offA = ((long)dy * Wp2 + dx) * Cin + (kk << 6);
    long offB = (long)tap * bstride + (kk << 6);
    f16* ab = Asm + sel * CH;
    f16* bb = Bsm + sel * CH;
#pragma unroll
    for (int e = 0; e < 4; ++e) {
      LLDS16(gA[e] + offA, ab + lOff[e]);
      LLDS16(gB[e] + offB, bb + lOff[e]);
    }
  };

  stageAB(it0, 0);
  int sel = 0;
  for (int ii = 0; ii < nit; ++ii) {
    __syncthreads();  // drains prefetch (vmcnt) + prior reads (lgkm)
    if (ii + 1 < nit) stageAB(it0 + ii + 1, sel ^ 1);  // overlaps compute below
    const f16* ab = Asm + sel * CH;
    const f16* bb = Bsm + sel * CH;
    f16x8 af[4][2], bf[4][2];
#pragma unroll
    for (int i = 0; i < 4; ++i)
#pragma unroll
      for (int kk = 0; kk < 2; ++kk) {
        af[i][kk] = *(const f16x8*)&ab[aoffs[i][kk]];
        bf[i][kk] = *(const f16x8*)&bb[boffs[i][kk]];
      }
#pragma unroll
    for (int kk = 0; kk < 2; ++kk)
#pragma unroll
      for (int i = 0; i < 4; ++i)
#pragma unroll
        for (int j = 0; j < 4; ++j)
          acc[i][j] = __builtin_amdgcn_mfma_f32_16x16x32_f16(af[i][kk], bf[j][kk], acc[i][j], 0, 0, 0);
    sel ^= 1;
  }

  const size_t pbase = (size_t)blockIdx.z * NB * Cout * HW;
#pragma unroll
  for (int i = 0; i < 4; ++i) {
    int mg = m0 + wm * 64 + i * 16 + quad * 4;
    int n = mg / HW, p = mg - n * HW;
#pragma unroll
    for (int j = 0; j < 4; ++j) {
      int co = co0 + wn * 64 + j * 16 + lr;
      f32x4 v = acc[i][j];
      f16x4 h;
#pragma unroll
      for (int r = 0; r < 4; ++r) h[r] = (f16)v[r];
      *(f16x4*)&part[pbase + ((size_t)n * Cout + co) * HW + p] = h;
    }
  }
}

// ---------------- reduce S partials + bias (+add)(+lrelu) + GN partials -----
__global__ __launch_bounds__(256) void reduceS_kernel(
    const f16* __restrict__ part, const float* __restrict__ bias,
    const float* __restrict__ add, float* __restrict__ out,
    int Cout, int HW, int S, int do_lrelu, int total4,
    float* __restrict__ gnp, int G, int Sg) {
  __shared__ float red[512];
  int idx = blockIdx.x * 256 + threadIdx.x;
  if (idx >= total4) return;
  size_t sstride = (size_t)NB * Cout * HW;
  int hw4 = HW >> 2;
  int p4 = idx % hw4; int t = idx / hw4;
  int c = t % Cout;
  size_t eoff = (size_t)t * HW + p4 * 4;
  float b = bias[c];
  f32x4 o = {b, b, b, b};
  for (int s = 0; s < S; ++s) {
    f16x4 a = *(const f16x4*)(part + s * sstride + eoff);
#pragma unroll
    for (int r = 0; r < 4; ++r) o[r] += (float)a[r];
  }
  if (add) {
    f32x4 av = *(const f32x4*)(add + eoff);
#pragma unroll
    for (int r = 0; r < 4; ++r) o[r] += av[r];
  }
  if (do_lrelu)
#pragma unroll
    for (int r = 0; r < 4; ++r) o[r] = o[r] > 0.f ? o[r] : 0.2f * o[r];
  *(f32x4*)(out + eoff) = o;
  if (gnp) {
    float ls = o[0] + o[1] + o[2] + o[3];
    float ls2 = o[0]*o[0] + o[1]*o[1] + o[2]*o[2] + o[3]*o[3];
    red[threadIdx.x] = ls; red[256 + threadIdx.x] = ls2;
    __syncthreads();
    for (int st = 128; st > 0; st >>= 1) {
      if (threadIdx.x < st) {
        red[threadIdx.x] += red[threadIdx.x + st];
        red[256 + threadIdx.x] += red[256 + threadIdx.x + st];
      }
      __syncthreads();
    }
    if (threadIdx.x == 0) {
      int flat0 = blockIdx.x * 1024;
      int chw = Cout * HW;
      int n = flat0 / chw;
      int rem = flat0 - n * chw;
      int L = (Cout / G) * HW;
      int g = rem / L;
      int s = (rem - g * L) >> 10;
      gnp[((n * G + g) * Sg + s) * 2] = red[0];
      gnp[((n * G + g) * Sg + s) * 2 + 1] = red[256];
    }
  }
}

// ---------------- conv_mfma3: 128x64x64, dbuf, fused GN-partial epilogue ----
__global__ __launch_bounds__(256) void conv_mfma3_kernel(
    const f16* __restrict__ A, const f16* __restrict__ Wp,
    const float* __restrict__ bias, float* __restrict__ out,
    int Cin, int H, int W, int Cout, int HW, int do_lrelu,
    float* __restrict__ gnp) {
  constexpr int CHA = 128 * 64;  // f16 per A buffer
  constexpr int CHB = 64 * 64;   // f16 per B buffer
  __shared__ f16 Asm[2 * CHA];   // 32 KB
  __shared__ f16 Bsm[2 * CHB];   // 16 KB
  __shared__ float redg[32];     // 8 groups x 2 wm x {s,s2}

  const int tid = threadIdx.x;
  const int w = tid >> 6, lane = tid & 63;
  const int m0 = blockIdx.x * 128;
  const int co0 = blockIdx.y * 64;
  const int Wp2 = W + 2;

  const f16* gA[4];
  int lAoff[4];
#pragma unroll
  for (int e = 0; e < 4; ++e) {
    int c = e * 256 + tid;
    int r = c >> 3, j = c & 7;
    int jx = j ^ (r & 7);
    int m = m0 + r; int n = m / HW; int p = m - n * HW;
    int y = p / W; int x = p - y * W;
    gA[e] = A + (((size_t)n * (H + 2) + y + 1) * Wp2 + (x + 1)) * Cin + jx * 8;
    lAoff[e] = (e * 256 + w * 64) * 8;
  }
  const f16* gB[2];
  int lBoff[2];
#pragma unroll
  for (int e = 0; e < 2; ++e) {
    int c = e * 256 + tid;
    int r = c >> 3, j = c & 7;
    int jx = j ^ (r & 7);
    gB[e] = Wp + (size_t)(co0 + r) * Cin + jx * 8;
    lBoff[e] = (e * 256 + w * 64) * 8;
  }

  const int wm = w & 1, wn = w >> 1;
  const int lr = lane & 15, quad = lane >> 4;
  int aoffs[4][2], boffs[2][2];
#pragma unroll
  for (int i = 0; i < 4; ++i)
#pragma unroll
    for (int kk = 0; kk < 2; ++kk) {
      int r = wm * 64 + i * 16 + lr;
      int cidx = kk * 4 + quad;
      aoffs[i][kk] = (r * 8 + (cidx ^ (r & 7))) * 8;
    }
#pragma unroll
  for (int jn = 0; jn < 2; ++jn)
#pragma unroll
    for (int kk = 0; kk < 2; ++kk) {
      int rb = wn * 32 + jn * 16 + lr;
      int cidx = kk * 4 + quad;
      boffs[jn][kk] = (rb * 8 + (cidx ^ (rb & 7))) * 8;
    }

  f32x4 acc[4][2];
#pragma unroll
  for (int i = 0; i < 4; ++i)
#pragma unroll
    for (int jn = 0; jn < 2; ++jn) acc[i][jn] = (f32x4){0.f, 0.f, 0.f, 0.f};

  const int kpt = Cin >> 6;
  const int nit = 9 * kpt;
  const size_t bstride = (size_t)Cout * Cin;

  auto stageAB = [&](int it, int sel) {
    int tap = it / kpt, kk = it - tap * kpt;
    int dy = tap / 3 - 1, dx = tap % 3 - 1;
    long offA = ((long)dy * Wp2 + dx) * Cin + (kk << 6);
    long offB = (long)tap * bstride + (kk << 6);
    f16* ab = Asm + sel * CHA;
    f16* bb = Bsm + sel * CHB;
#pragma unroll
    for (int e = 0; e < 4; ++e) LLDS16(gA[e] + offA, ab + lAoff[e]);
#pragma unroll
    for (int e = 0; e < 2; ++e) LLDS16(gB[e] + offB, bb + lBoff[e]);
  };

  stageAB(0, 0);
  int sel = 0;
  for (int ii = 0; ii < nit; ++ii) {
    __syncthreads();
    if (ii + 1 < nit) stageAB(ii + 1, sel ^ 1);
    const f16* ab = Asm + sel * CHA;
    const f16* bb = Bsm + sel * CHB;
    f16x8 af[4][2], bf[2][2];
#pragma unroll
    for (int i = 0; i < 4; ++i)
#pragma unroll
      for (int kk = 0; kk < 2; ++kk) af[i][kk] = *(const f16x8*)&ab[aoffs[i][kk]];
#pragma unroll
    for (int jn = 0; jn < 2; ++jn)
#pragma unroll
      for (int kk = 0; kk < 2; ++kk) bf[jn][kk] = *(const f16x8*)&bb[boffs[jn][kk]];
#pragma unroll
    for (int kk = 0; kk < 2; ++kk)
#pragma unroll
      for (int i = 0; i < 4; ++i)
#pragma unroll
        for (int jn = 0; jn < 2; ++jn)
          acc[i][jn] = __builtin_amdgcn_mfma_f32_16x16x32_f16(af[i][kk], bf[jn][kk], acc[i][jn], 0, 0, 0);
    sel ^= 1;
  }

  float lsj[2] = {0.f, 0.f}, ls2j[2] = {0.f, 0.f};
#pragma unroll
  for (int i = 0; i < 4; ++i) {
    int mg = m0 + wm * 64 + i * 16 + quad * 4;
    int n = mg / HW, p = mg - n * HW;
#pragma unroll
    for (int jn = 0; jn < 2; ++jn) {
      int co = co0 + wn * 32 + jn * 16 + lr;
      float b = bias[co];
      f32x4 v = acc[i][jn];
#pragma unroll
      for (int r = 0; r < 4; ++r) {
        float u = v[r] + b;
        u = (do_lrelu && u < 0.f) ? 0.2f * u : u;
        v[r] = u;
        lsj[jn] += u; ls2j[jn] += u * u;
      }
      *(f32x4*)&out[((size_t)n * Cout + co) * HW + p] = v;
    }
  }

  if (gnp) {
    __syncthreads();  // main-loop LDS traffic retired before redg reuse phase
#pragma unroll
    for (int jn = 0; jn < 2; ++jn) {
      float s = lsj[jn], s2 = ls2j[jn];
      s += __shfl_xor(s, 1);  s2 += __shfl_xor(s2, 1);
      s += __shfl_xor(s, 2);  s2 += __shfl_xor(s2, 2);
      s += __shfl_xor(s, 4);  s2 += __shfl_xor(s2, 4);
      s += __shfl_xor(s, 16); s2 += __shfl_xor(s2, 16);
      s += __shfl_xor(s, 32); s2 += __shfl_xor(s2, 32);
      if ((lane & 55) == 0) {  // lanes 0 (hi=0) and 8 (hi=1)
        int hi = (lane >> 3) & 1;
        int g = wn * 4 + jn * 2 + hi;   // local 8-ch group in [0,8)
        redg[(g * 2 + wm) * 2]     = s;
        redg[(g * 2 + wm) * 2 + 1] = s2;
      }
    }
    __syncthreads();
    if (tid < 8) {
      float s  = redg[(tid * 2) * 2]     + redg[(tid * 2 + 1) * 2];
      float s2 = redg[(tid * 2) * 2 + 1] + redg[(tid * 2 + 1) * 2 + 1];
      int n = m0 / HW;
      int sIdx = (m0 - n * HW) >> 7;   // 128-pixel slice within image
      int Sg = HW >> 7;
      int G = Cout >> 3;               // 8 groups (Cout=64, grid.y=1)
      gnp[((n * G + tid) * Sg + sIdx) * 2]     = s;
      gnp[((n * G + tid) * Sg + sIdx) * 2 + 1] = s2;
    }
  }
}

// ---------------- direct 3x3 conv, CO per thread, optional gn1 partials -----
template <int CO, int CIC>
__global__ __launch_bounds__(256) void conv3x3_kernel(
    const float* __restrict__ in, const float* __restrict__ wgt,
    const float* __restrict__ bias, float* __restrict__ out,
    int Cin, int H, int W, int Cout, int do_lrelu, float* __restrict__ gnp) {
  __shared__ float sm[CIC][18][18];
  int tiles_x = W >> 4;
  int bt = blockIdx.x;
  int tx0 = (bt % tiles_x) << 4;
  int ty0 = (bt / tiles_x) << 4;
  int co0 = blockIdx.y * CO;
  int n = blockIdx.z;
  int tid = threadIdx.x;
  int lx = tid & 15, ly = tid >> 4;

  float acc[CO];
#pragma unroll
  for (int i = 0; i < CO; i++) acc[i] = 0.f;

  const float* inb = in + (size_t)n * Cin * H * W;

  for (int ci0 = 0; ci0 < Cin; ci0 += CIC) {
    __syncthreads();
    for (int idx = tid; idx < CIC * 324; idx += 256) {
      int ci = idx / 324;
      int r = idx - ci * 324;
      int gy = r / 18, gx = r - gy * 18;
      int iy = ty0 + gy - 1, ix = tx0 + gx - 1;
      float v = 0.f;
      if ((unsigned)iy < (unsigned)H && (unsigned)ix < (unsigned)W)
        v = inb[((size_t)(ci0 + ci)) * H * W + (size_t)iy * W + ix];
      sm[ci][gy][gx] = v;
    }
    __syncthreads();
#pragma unroll
    for (int ci = 0; ci < CIC; ci++) {
      float x00 = sm[ci][ly][lx],     x01 = sm[ci][ly][lx + 1],     x02 = sm[ci][ly][lx + 2];
      float x10 = sm[ci][ly + 1][lx], x11 = sm[ci][ly + 1][lx + 1], x12 = sm[ci][ly + 1][lx + 2];
      float x20 = sm[ci][ly + 2][lx], x21 = sm[ci][ly + 2][lx + 1], x22 = sm[ci][ly + 2][lx + 2];
      const float* wp = wgt + ((size_t)co0 * Cin + (ci0 + ci)) * 9;
#pragma unroll
      for (int co = 0; co < CO; co++) {
        const float* wc = wp + (size_t)co * Cin * 9;
        float a = acc[co];
        a = fmaf(wc[0], x00, a); a = fmaf(wc[1], x01, a); a = fmaf(wc[2], x02, a);
        a = fmaf(wc[3], x10, a); a = fmaf(wc[4], x11, a); a = fmaf(wc[5], x12, a);
        a = fmaf(wc[6], x20, a); a = fmaf(wc[7], x21, a); a = fmaf(wc[8], x22, a);
        acc[co] = a;
      }
    }
  }

  float vout[CO];
#pragma unroll
  for (int co = 0; co < CO; co++) {
    float v = acc[co] + bias[co0 + co];
    if (do_lrelu) v = v > 0.f ? v : 0.2f * v;
    vout[co] = v;
  }

  if (gnp) {
    float p0 = 0.f, q0 = 0.f, p1 = 0.f, q1 = 0.f;
#pragma unroll
    for (int co = 0; co < 8; ++co) { p0 += vout[co]; q0 += vout[co] * vout[co]; }
#pragma unroll
    for (int co = 8; co < CO; ++co) { p1 += vout[co]; q1 += vout[co] * vout[co]; }
    float* red = &sm[0][0][0];
    __syncthreads();
    red[tid] = p0; red[256 + tid] = q0; red[512 + tid] = p1; red[768 + tid] = q1;
    __syncthreads();
    for (int st = 128; st > 0; st >>= 1) {
      if (tid < st) {
        red[tid] += red[tid + st]; red[256 + tid] += red[256 + tid + st];
        red[512 + tid] += red[512 + tid + st]; red[768 + tid] += red[768 + tid + st];
      }
      __syncthreads();
    }
    if (tid == 0) {
      int S = gridDim.x;
      gnp[((n * 2 + 0) * S + blockIdx.x) * 2]     = red[0];
      gnp[((n * 2 + 0) * S + blockIdx.x) * 2 + 1] = red[256];
      gnp[((n * 2 + 1) * S + blockIdx.x) * 2]     = red[512];
      gnp[((n * 2 + 1) * S + blockIdx.x) * 2 + 1] = red[768];
    }
  }

  int oy = ty0 + ly, ox = tx0 + lx;
#pragma unroll
  for (int co = 0; co < CO; co++)
    out[(((size_t)n * Cout + co0 + co) * H + oy) * W + ox] = vout[co];
}

// ---- fused inline-GN(input) + conv3x3(lrelu) + iwt + final 1x1 ws-conv -----
template <int CO, int CIC>
__global__ __launch_bounds__(256) void conv3x3_iwt_kernel(
    const float* __restrict__ in, const float* __restrict__ wgt,
    const float* __restrict__ bias, const float* __restrict__ fw,
    const float* __restrict__ gnp, const float* __restrict__ gamma,
    const float* __restrict__ beta, int G, int Sg, int len,
    float* __restrict__ out, int Cin, int H, int W) {
  __shared__ float sm[CIC][18][18];
  __shared__ float csc[16], csh[16];
  int tiles_x = W >> 4;
  int bt = blockIdx.x;
  int tx0 = (bt % tiles_x) << 4;
  int ty0 = (bt / tiles_x) << 4;
  int n = blockIdx.z;
  int tid = threadIdx.x;
  int lx = tid & 15, ly = tid >> 4;

  if (tid < Cin) {
    int g = tid / (Cin / G);
    const float* pp = gnp + (size_t)((n * G + g) * Sg) * 2;
    float s = 0.f, s2 = 0.f;
    for (int i = 0; i < Sg; ++i) { s += pp[2 * i]; s2 += pp[2 * i + 1]; }
    float mean = s / (float)len;
    float var = s2 / (float)len - mean * mean;
    if (var < 0.f) var = 0.f;
    float inv = rsqrtf(var + 1e-5f);
    float ga = gamma[tid];
    csc[tid] = inv * ga;
    csh[tid] = beta[tid] - mean * inv * ga;
  }
  __syncthreads();

  float acc[CO];
#pragma unroll
  for (int i = 0; i < CO; i++) acc[i] = 0.f;

  const float* inb = in + (size_t)n * Cin * H * W;

  for (int ci0 = 0; ci0 < Cin; ci0 += CIC) {
    __syncthreads();
    for (int idx = tid; idx < CIC * 324; idx += 256) {
      int ci = idx / 324;
      int r = idx - ci * 324;
      int gy = r / 18, gx = r - gy * 18;
      int iy = ty0 + gy - 1, ix = tx0 + gx - 1;
      float v = 0.f;
      if ((unsigned)iy < (unsigned)H && (unsigned)ix < (unsigned)W)
        v = inb[((size_t)(ci0 + ci)) * H * W + (size_t)iy * W + ix] * csc[ci0 + ci] + csh[ci0 + ci];
      sm[ci][gy][gx] = v;
    }
    __syncthreads();
#pragma unroll
    for (int ci = 0; ci < CIC; ci++) {
      float x00 = sm[ci][ly][lx],     x01 = sm[ci][ly][lx + 1],     x02 = sm[ci][ly][lx + 2];
      float x10 = sm[ci][ly + 1][lx], x11 = sm[ci][ly + 1][lx + 1], x12 = sm[ci][ly + 1][lx + 2];
      float x20 = sm[ci][ly + 2][lx], x21 = sm[ci][ly + 2][lx + 1], x22 = sm[ci][ly + 2][lx + 2];
      const float* wp = wgt + (size_t)(ci0 + ci) * 9;
#pragma unroll
      for (int co = 0; co < CO; co++) {
        const float* wc = wp + (size_t)co * Cin * 9;
        float a = acc[co];
        a = fmaf(wc[0], x00, a); a = fmaf(wc[1], x01, a); a = fmaf(wc[2], x02, a);
        a = fmaf(wc[3], x10, a); a = fmaf(wc[4], x11, a); a = fmaf(wc[5], x12, a);
        a = fmaf(wc[6], x20, a); a = fmaf(wc[7], x21, a); a = fmaf(wc[8], x22, a);
        acc[co] = a;
      }
    }
  }

  float vout[CO];
#pragma unroll
  for (int co = 0; co < CO; co++) {
    float v = acc[co] + bias[co];
    vout[co] = v > 0.f ? v : 0.2f * v;
  }

  float y0[3], y1[3], y2[3], y3[3];
#pragma unroll
  for (int c = 0; c < 3; ++c) {
    float v0 = vout[4 * c];
    float v1 = 2.f * vout[4 * c + 1] - 1.f;
    float v2 = 2.f * vout[4 * c + 2] - 1.f;
    float v3 = 2.f * vout[4 * c + 3] - 1.f;
    y0[c] = v0 + 0.5f * ( v1 + v2 + v3);
    y1[c] = v0 + 0.5f * ( v1 - v2 - v3);
    y2[c] = v0 + 0.5f * (-v1 + v2 - v3);
    y3[c] = v0 + 0.5f * (-v1 - v2 + v3);
  }
  float w0 = fw[0], w1 = fw[1], w2 = fw[2], w3 = fw[3], w4 = fw[4], w5 = fw[5];
  int oy = ty0 + ly, ox = tx0 + lx;
  int OW = 2 * W;
  size_t ocs = (size_t)(2 * H) * OW;
  float* o0 = out + (size_t)n * 2 * ocs + (size_t)(2 * oy) * OW + 2 * ox;
  o0[0]      = w0 * y0[0] + w1 * y0[1] + w2 * y0[2];
  o0[1]      = w0 * y1[0] + w1 * y1[1] + w2 * y1[2];
  o0[OW]     = w0 * y2[0] + w1 * y2[1] + w2 * y2[2];
  o0[OW + 1] = w0 * y3[0] + w1 * y3[1] + w2 * y3[2];
  float* o1 = o0 + ocs;
  o1[0]      = w3 * y0[0] + w4 * y0[1] + w5 * y0[2];
  o1[1]      = w3 * y1[0] + w4 * y1[1] + w5 * y1[2];
  o1[OW]     = w3 * y2[0] + w4 * y2[1] + w5 * y2[2];
  o1[OW + 1] = w3 * y3[0] + w4 * y3[1] + w5 * y3[2];
}

// ---------------------------------------------------------------------------

extern "C" void kernel_launch(void* const* d_in, const int* in_sizes, int n_in,
                              void* d_out, int out_size, void* d_ws, size_t ws_size,
                              hipStream_t stream) {
  const float* x        = (const float*)d_in[0];
  const float* conv1_w  = (const float*)d_in[1];
  const float* conv1_b  = (const float*)d_in[2];
  const float* conv2_w  = (const float*)d_in[3];
  const float* conv2_b  = (const float*)d_in[4];
  const float* conv3_w  = (const float*)d_in[5];
  const float* conv3_b  = (const float*)d_in[6];
  const float* conv4_w  = (const float*)d_in[7];
  const float* conv4_b  = (const float*)d_in[8];
  const float* convd1_w = (const float*)d_in[9];
  const float* convd1_b = (const float*)d_in[10];
  const float* convd2_w = (const float*)d_in[11];
  const float* convd2_b = (const float*)d_in[12];
  const float* convd3_w = (const float*)d_in[13];
  const float* convd3_b = (const float*)d_in[14];
  const float* convd4_w = (const float*)d_in[15];
  const float* convd4_b = (const float*)d_in[16];
  const float* final_w  = (const float*)d_in[17];
  const float* gn1_w = (const float*)d_in[18];
  const float* gn1_b = (const float*)d_in[19];
  const float* gn2_w = (const float*)d_in[20];
  const float* gn2_b = (const float*)d_in[21];
  const float* gn3_w = (const float*)d_in[22];
  const float* gn3_b = (const float*)d_in[23];
  const float* gn4_w = (const float*)d_in[24];
  const float* gn4_b = (const float*)d_in[25];

  char* base = (char*)d_ws;
  size_t off = 0;
  auto allocB = [&](size_t bytes) { size_t o = off; off = (off + bytes + 255) & ~(size_t)255; return o; };

  size_t o_sw1  = allocB(16 * 108 * 4);
  size_t o_swd1 = allocB(12 * 144 * 4);
  size_t o_swd2 = allocB(16 * 288 * 4);
  size_t o_swf  = allocB(6 * 4);
  size_t o_pw2  = allocB((size_t)9 * 64 * 64 * 2);
  size_t o_pw3  = allocB((size_t)9 * 256 * 256 * 2);
  size_t o_pw4  = allocB((size_t)9 * 1024 * 1024 * 2);
  size_t o_pwd3 = allocB((size_t)9 * 64 * 128 * 2);
  size_t o_pwd4 = allocB((size_t)9 * 256 * 512 * 2);
  size_t o_R1   = allocB((size_t)NB * 66 * 66 * 128 * 2);  // part | ah64 | ah128
  size_t o_R2   = allocB((size_t)NB * 34 * 34 * 512 * 2);  // ah256 | ah1k | ah512
  size_t o_gnp  = allocB(16384 * 4);                        // gn block partials
  size_t o_c1 = allocB((size_t)NB * 16 * 128 * 128 * 4);
  size_t o_c2 = allocB((size_t)NB * 64 * 64 * 64 * 4);
  size_t o_c3 = allocB((size_t)NB * 256 * 32 * 32 * 4);
  size_t o_w4 = allocB((size_t)NB * 1024 * 16 * 16 * 4);
  size_t o_t1 = allocB((size_t)NB * 1024 * 16 * 16 * 4);
  size_t o_t2 = allocB((size_t)NB * 512 * 32 * 32 * 4);

  if (off > ws_size) return;

  float* c1 = (float*)(base + o_c1);
  float* c2 = (float*)(base + o_c2);
  float* c3 = (float*)(base + o_c3);
  float* w4 = (float*)(base + o_w4);
  float* t1 = (float*)(base + o_t1);
  float* t2 = (float*)(base + o_t2);
  f16* part  = (f16*)(base + o_R1);
  f16* ah64  = (f16*)(base + o_R1);
  f16* ah128 = (f16*)(base + o_R1);
  f16* ah256 = (f16*)(base + o_R2);
  f16* ah1k  = (f16*)(base + o_R2);
  f16* ah512 = (f16*)(base + o_R2);
  f16* pw2 = (f16*)(base + o_pw2);
  f16* pw3 = (f16*)(base + o_pw3);
  f16* pw4 = (f16*)(base + o_pw4);
  f16* pwd3 = (f16*)(base + o_pwd3);
  f16* pwd4 = (f16*)(base + o_pwd4);
  float* gnp = (float*)(base + o_gnp);

  // ---- upfront ----
  {
    int n0 = NB * (2 * 66 + 2 * 64) * (64 / 8);
    int n1 = NB * (2 * 34 + 2 * 32) * (256 / 8);
    int tot = n0 + n1;
    halo2_kernel<<<(tot + 255) / 256, 256, 0, stream>>>(ah64, 64, 64, 64, n0,
                                                        ah256, 256, 32, 32, tot);
  }
  ws_all_kernel<<<46, 256, 0, stream>>>(conv1_w, (float*)(base + o_sw1),
                                        convd1_w, (float*)(base + o_swd1),
                                        convd2_w, (float*)(base + o_swd2),
                                        final_w, (float*)(base + o_swf));
  ws_f16_all_kernel<<<1664, 256, 0, stream>>>(conv2_w, pw2, conv3_w, pw3, conv4_w, pw4,
                                              convd3_w, pwd3, convd4_w, pwd4);

  auto prep_nhwc = [&](const float* in, f16* ah, int C, int H, int W, int zero) {
    if (zero) {
      int total8 = NB * (2 * (W + 2) + 2 * H) * (C / 8);
      zero_halo_kernel<<<(total8 + 255) / 256, 256, 0, stream>>>(ah, C, H, W, total8);
    }
    dim3 g((H * W) / 256, C / 32, NB);
    to_nhwc_pad_kernel<<<g, 256, 0, stream>>>(in, ah, C, H, W);
  };
  auto wt_nhwc_gn = [&](const float* in, f16* ah, float* haar32, float* wb,
                        const float* gg, const float* gb, int G, int Sg,
                        int C, int Ho, int Wo) {
    int len = (C / G) * (4 * Ho * Wo);
    dim3 g((Ho * Wo) / 256, C / 8, NB);
    wt_nhwc_gn_kernel<<<g, 256, 0, stream>>>(in, gnp, gg, gb, G, Sg, len,
                                             ah, haar32, wb, C, Ho, Wo);
  };
  auto cm6conv = [&](const f16* a, const f16* wt, int Cin, int Hs, int Ws, int Cout) {
    dim3 g((NB * Hs * Ws) / 128, Cout / 128, 2);
    conv_mfma6_kernel<<<g, 256, 0, stream>>>(a, wt, part, Cin, Hs, Ws, Cout, Hs * Ws);
  };
  auto cm6 = [&](const f16* a, const f16* wt, const float* b, float* dest, const float* add,
                 int Cin, int Hs, int Ws, int Cout, int lr, int G, int Sg) {
    cm6conv(a, wt, Cin, Hs, Ws, Cout);
    int total4 = (NB * Cout * Hs * Ws) >> 2;
    reduceS_kernel<<<(total4 + 255) / 256, 256, 0, stream>>>(
        part, b, add, dest, Cout, Hs * Ws, 2, lr, total4, G ? gnp : nullptr, G, Sg);
  };
  // cm3: Cout=64 conv with fused GN-partial epilogue (8 groups, Sg = HW/128)
  auto cm3 = [&](const f16* a, const f16* wt, const float* b, float* o,
                 int Cin, int Hs, int Ws, int lr) {
    dim3 g((NB * Hs * Ws) / 128, 1);
    conv_mfma3_kernel<<<g, 256, 0, stream>>>(a, wt, b, o, Cin, Hs, Ws, 64, Hs * Ws, lr, gnp);
  };
  // fused split-K reduce + bias + lrelu + in-block GN + NHWC pack (16x16 sites)
  auto gnp_nhwc = [&](const float* b, const float* gg, const float* gb, f16* ah) {
    dim3 g(1, 32, NB);
    gn_nhwc_part_kernel<<<g, 256, 0, stream>>>(part, b, gg, gb, ah, 1024, 16, 16);
  };

  // ==== encoder ====
  {
    int total = NB * 3 * 128 * 128;
    wt_kernel<<<(total + 255) / 256, 256, 0, stream>>>(x, t1, 3, 128, 128, total);  // w1
  }
  {
    dim3 g(64, 1, NB);
    conv3x3_kernel<16, 4><<<g, 256, 0, stream>>>(t1, (float*)(base + o_sw1), conv1_b,
                                                 c1, 12, 128, 128, 16, 1, gnp);
  }
  // gn1(c1) fused into wt_nhwc_gn (writeback -> c1 for skip use); w2 -> ah64
  wt_nhwc_gn(c1, ah64, nullptr, c1, gn1_w, gn1_b, 2, 64, 16, 64, 64);

  cm3(ah64, pw2, conv2_b, c2, 64, 64, 64, 1);                       // c2 (+partials Sg=32)
  // gn2(c2) fused; w3 -> ah256
  wt_nhwc_gn(c2, ah256, nullptr, c2, gn2_w, gn2_b, 8, 32, 64, 32, 32);

  cm6(ah256, pw3, conv3_b, c3, nullptr, 256, 32, 32, 256, 1, 32, 8);  // c3 (+partials)
  {
    int total8 = NB * (2 * 18 + 2 * 16) * (1024 / 8);
    zero_halo_kernel<<<(total8 + 255) / 256, 256, 0, stream>>>(ah1k, 1024, 16, 16, total8);
  }
  // gn3(c3) fused; w4 -> ah1k + fp32 Haar copy (residual) + writeback -> c3
  wt_nhwc_gn(c3, ah1k, w4, c3, gn3_w, gn3_b, 32, 8, 256, 16, 16);

  // c4: conv -> part; split-K reduce + bias + lrelu + in-block GN -> ah1k
  cm6conv(ah1k, pw4, 1024, 16, 16, 1024);
  gnp_nhwc(conv4_b, gn4_w, gn4_b, ah1k);
  // c5: same
  cm6conv(ah1k, pw4, 1024, 16, 16, 1024);
  gnp_nhwc(conv4_b, gn4_w, gn4_b, ah1k);
  // c6 partials only; split-K sum + bias + w4-add + lrelu folded into iw4 concat
  cm6conv(ah1k, pw4, 1024, 16, 16, 1024);

  // ==== decoder ====
  // iw4 = concat(c3, iwt(lrelu(part0+part1+bias+w4))) -> t2 (NCHW fp32)
  {
    int totalA = NB * 256 * 4 * 16 * 16;
    int total = totalA + NB * 256 * 16 * 16;
    concat_iwt_kernel<<<(total + 255) / 256, 256, 0, stream>>>(
        c3, nullptr, part, conv4_b, w4, t2,
        nullptr, nullptr, nullptr, 0, 0, 0, 256, 16, 16, totalA, total);
  }
  prep_nhwc(t2, ah512, 512, 32, 32, 1);
  cm6(ah512, pwd4, convd4_b, t1, nullptr, 512, 32, 32, 256, 1, 32, 8);  // ic3 (+partials)
  // iw3 -> t2 (gn3 inline)
  {
    int totalA = NB * 64 * 4 * 32 * 32;
    int total = totalA + NB * 64 * 32 * 32;
    int len = (256 / 32) * 32 * 32;
    concat_iwt_kernel<<<(total + 255) / 256, 256, 0, stream>>>(
        c2, t1, nullptr, nullptr, nullptr, t2,
        gnp, gn3_w, gn3_b, 32, 8, len, 64, 32, 32, totalA, total);
  }
  prep_nhwc(t2, ah128, 128, 64, 64, 1);
  cm3(ah128, pwd3, convd3_b, t1, 128, 64, 64, 1);                   // ic2 (+partials Sg=32)
  // iw2 -> t2 (gn2 inline, partials from ic2 epilogue)
  {
    int totalA = NB * 16 * 4 * 64 * 64;
    int total = totalA + NB * 16 * 64 * 64;
    int len = (64 / 8) * 64 * 64;
    concat_iwt_kernel<<<(total + 255) / 256, 256, 0, stream>>>(
        c1, t1, nullptr, nullptr, nullptr, t2,
        gnp, gn2_w, gn2_b, 8, 32, len, 16, 64, 64, totalA, total);
  }
  {
    dim3 g(64, 1, NB);
    conv3x3_kernel<16, 4><<<g, 256, 0, stream>>>(t2, (float*)(base + o_swd2), convd2_b,
                                                 t1, 32, 128, 128, 16, 1, gnp);
  }
  // gn1(ic1) fused into conv3x3_iwt's input read; final conv + iwt + 1x1
  {
    dim3 g(64, 1, NB);
    conv3x3_iwt_kernel<12, 4><<<g, 256, 0, stream>>>(
        t1, (float*)(base + o_swd1), convd1_b, (float*)(base + o_swf),
        gnp, gn1_w, gn1_b, 2, 64, 8 * 128 * 128, (float*)d_out, 16, 128, 128);
  }
}